// Round 21
// baseline (754.795 us; speedup 1.0000x reference)
//
#include <hip/hip_runtime.h>
#include <hip/hip_bf16.h>
#include <math.h>

typedef __hip_bfloat16 bf16;
typedef __attribute__((ext_vector_type(8))) short bf16x8;
typedef __attribute__((ext_vector_type(4))) float f32x4;

#define N_TOK 1024
#define DIM 2048
#define NHEADS 16
#define KVH 2
#define DH 128
#define GQ 8
#define NWIN 64
#define CMP_BLK 32
#define NCMP 65        // MEM_KV + NWIN
#define NFINE 16
#define SEL_BLK 64
#define T_TOT 320
#define CDIM 4096      // CMP_BLK*DH
#define SCALE 0.08838834764831845f

static __device__ __forceinline__ float b2f(bf16 v){ return __bfloat162float(v); }
static __device__ __forceinline__ float bfbits2f(unsigned int u){
  union { unsigned int i; float f; } x; x.i = u << 16; return x.f;
}
// RNE float->bf16 bits (matches __float2bfloat16 for normal values)
static __device__ __forceinline__ unsigned short f2bf(float f){
  union { float f; unsigned u; } x; x.f = f;
  unsigned r = x.u + 0x7fffu + ((x.u >> 16) & 1u);
  return (unsigned short)(r >> 16);
}

// ---------------- RMSNorm: x fp32 [N,DIM] -> xn fp32 + xnh/xnl bf16 hi/lo SLAB-TILED ----------------
__global__ __launch_bounds__(256) void rmsnorm_kernel(const float* __restrict__ x,
                                                      const float* __restrict__ g,
                                                      float* __restrict__ xn,
                                                      unsigned short* __restrict__ xnh,
                                                      unsigned short* __restrict__ xnl){
  int n = blockIdx.x, tid = threadIdx.x;
  __shared__ float red[256];
  const float* row = x + (size_t)n*DIM;
  float vals[8];
  float s = 0.f;
  #pragma unroll
  for (int i = 0; i < 8; ++i){ float v = row[tid + i*256]; vals[i] = v; s += v*v; }
  red[tid] = s; __syncthreads();
  for (int st = 128; st > 0; st >>= 1){ if (tid < st) red[tid] += red[tid+st]; __syncthreads(); }
  float scale = 1.0f / sqrtf(red[0]/(float)DIM + 1e-6f);
  #pragma unroll
  for (int i = 0; i < 8; ++i){
    int c = tid + i*256;
    float v = vals[i]*scale*g[c];
    xn[(size_t)n*DIM + c] = v;
    unsigned short h = f2bf(v);
    int sl = c >> 5, kk = c & 31;
    size_t o = (size_t)sl*(N_TOK*32) + (size_t)n*32 + kk;
    xnh[o] = h;
    xnl[o] = f2bf(v - bfbits2f(h));
  }
}

// ---------------- Transpose + hi/lo split into SLAB-TILED layout --------------------------------
__global__ __launch_bounds__(256) void transpose_split_kernel(const float* __restrict__ W, int ldw,
                                                              int ncols,
                                                              unsigned short* __restrict__ Th,
                                                              unsigned short* __restrict__ Tl){
  __shared__ float t[64][65];
  int bx = blockIdx.x;   // n tile
  int by = blockIdx.y;   // k tile
  int tid = threadIdx.x;
  #pragma unroll
  for (int i = 0; i < 16; ++i){
    int idx = tid + i*256;
    int r = idx >> 6, c = idx & 63;            // r=k_local, c=n_local (coalesced read)
    t[r][c] = W[(size_t)(by*64 + r)*ldw + bx*64 + c];
  }
  __syncthreads();
  #pragma unroll
  for (int i = 0; i < 16; ++i){
    int idx = tid + i*256;
    int nl = idx >> 6, kl = idx & 63;          // kl consecutive -> kk contiguous (coalesced)
    float v = t[kl][nl];
    unsigned short h = f2bf(v);
    unsigned short l = f2bf(v - bfbits2f(h));
    int s = by*2 + (kl >> 5), kk = kl & 31;
    size_t o = (size_t)s*((size_t)ncols*32) + (size_t)(bx*64 + nl)*32 + kk;
    Th[o] = h;
    Tl[o] = l;
  }
}

// ---------------- Split-K GEMM (64x64 tile) — kept for gates -----------------------------------
__global__ __launch_bounds__(256) void gemm_splitk_kernel(const void* __restrict__ Av, int a_is_bf16,
                                                          const float* __restrict__ afold,
                                                          const float* __restrict__ B, int ldb,
                                                          float* __restrict__ C,
                                                          int M, int N, int K, int kchunk){
  __shared__ __align__(16) float As[16*68];
  __shared__ __align__(16) float Bs[16*68];
  int tid = threadIdx.x;
  int tx = tid & 15, ty = tid >> 4;
  int m0 = blockIdx.y * 64, n0 = blockIdx.x * 64;
  int kz = blockIdx.z * kchunk;
  const float* Af = (const float*)Av;
  const bf16*  Ab = (const bf16*)Av;
  float c[4][4] = {};
  for (int k0 = kz; k0 < kz + kchunk; k0 += 16){
    #pragma unroll
    for (int i = 0; i < 4; ++i){
      int idx = tid + i*256;
      int kk = idx & 15, m = idx >> 4;
      size_t aidx = (size_t)(m0+m)*K + k0 + kk;
      float av = a_is_bf16 ? b2f(Ab[aidx]) : Af[aidx];
      if (afold) av = fmaxf(av + afold[k0+kk], 0.f);
      As[kk*68 + m] = av;
    }
    #pragma unroll
    for (int i = 0; i < 4; ++i){
      int idx = tid + i*256;
      int nn = idx & 63, kk = idx >> 6;
      int col = n0 + nn;
      Bs[kk*68 + nn] = (col < N) ? B[(size_t)(k0+kk)*ldb + col] : 0.f;
    }
    __syncthreads();
    #pragma unroll
    for (int kk = 0; kk < 16; ++kk){
      float a[4], b[4];
      *(float4*)a = *(const float4*)&As[kk*68 + ty*4];
      *(float4*)b = *(const float4*)&Bs[kk*68 + tx*4];
      #pragma unroll
      for (int i = 0; i < 4; ++i)
        #pragma unroll
        for (int j = 0; j < 4; ++j)
          c[i][j] += a[i]*b[j];
    }
    __syncthreads();
  }
  #pragma unroll
  for (int i = 0; i < 4; ++i){
    int row = m0 + ty*4 + i;
    #pragma unroll
    for (int j = 0; j < 4; ++j){
      int col = n0 + tx*4 + j;
      if (col < N) atomicAdd(&C[(size_t)row*N + col], c[i][j]);
    }
  }
}

// ---------------- MLP2 GEMM, k/v FUSED into one dispatch (round-14, passing) ------------------------
__global__ __launch_bounds__(256) void gemm_mlp2_fused_kernel(const float* __restrict__ hbuf2,
    const float* __restrict__ bk1, const float* __restrict__ bv1,
    const float* __restrict__ Wk2, const float* __restrict__ Wv2,
    float* __restrict__ ckb, float* __restrict__ cvb){
  const int kvsel = blockIdx.z >> 5;
  const int kz = (blockIdx.z & 31) * 128;
  const float* Af    = hbuf2 + (size_t)kvsel*128*CDIM;
  const float* afold = kvsel ? bv1 : bk1;
  const float* B     = kvsel ? Wv2 : Wk2;
  float* C           = kvsel ? cvb : ckb;
  __shared__ __align__(16) float As[16*68];
  __shared__ __align__(16) float Bs[16*68];
  int tid = threadIdx.x;
  int tx = tid & 15, ty = tid >> 4;
  int m0 = blockIdx.y * 64, n0 = blockIdx.x * 64;
  float c[4][4] = {};
  for (int k0 = kz; k0 < kz + 128; k0 += 16){
    #pragma unroll
    for (int i = 0; i < 4; ++i){
      int idx = tid + i*256;
      int kk = idx & 15, m = idx >> 4;
      float av = Af[(size_t)(m0+m)*CDIM + k0 + kk];
      av = fmaxf(av + afold[k0+kk], 0.f);
      As[kk*68 + m] = av;
    }
    #pragma unroll
    for (int i = 0; i < 4; ++i){
      int idx = tid + i*256;
      int nn = idx & 63, kk = idx >> 6;
      Bs[kk*68 + nn] = B[(size_t)(k0+kk)*DH + n0 + nn];
    }
    __syncthreads();
    #pragma unroll
    for (int kk = 0; kk < 16; ++kk){
      float a[4], b[4];
      *(float4*)a = *(const float4*)&As[kk*68 + ty*4];
      *(float4*)b = *(const float4*)&Bs[kk*68 + tx*4];
      #pragma unroll
      for (int i = 0; i < 4; ++i)
        #pragma unroll
        for (int j = 0; j < 4; ++j)
          c[i][j] += a[i]*b[j];
    }
    __syncthreads();
  }
  #pragma unroll
  for (int i = 0; i < 4; ++i){
    int row = m0 + ty*4 + i;
    #pragma unroll
    for (int j = 0; j < 4; ++j){
      int col = n0 + tx*4 + j;
      atomicAdd(&C[(size_t)row*DH + col], c[i][j]);
    }
  }
}

// ---------------- MLP1 GEMM via MFMA: B f32 LDS-staged + in-reg hi/lo, A SLAB-TILED -----------------
// Round-16/17 passing values. grid (64, 4, 16): z>>3 = k/v, z&7 = 16-slab chunk.
__global__ __launch_bounds__(256) void gemm_mfma_mlp1_kernel(const unsigned short* __restrict__ fh,
                                                             const unsigned short* __restrict__ fl,
                                                             const float* __restrict__ Wk1,
                                                             const float* __restrict__ Wv1,
                                                             float* __restrict__ hbuf2){
  const int kvsel = blockIdx.z >> 3;
  const int slab0 = (blockIdx.z & 7) * 16;     // 16 slabs = 512 k
  const int kz = slab0 * 32;
  const unsigned short* Ah = fh + (size_t)kvsel*524288 + (size_t)slab0*4096;
  const unsigned short* Al = fl + (size_t)kvsel*524288 + (size_t)slab0*4096;
  const float* B = kvsel ? Wv1 : Wk1;
  float* C = hbuf2 + (size_t)kvsel*524288;
  const int n0 = blockIdx.x * 64;
  const int m0 = blockIdx.y * 32;
  const int tid = threadIdx.x;
  const int wid = tid >> 6, lane = tid & 63;
  const int l15 = lane & 15, lg = lane >> 4;
  const int colL = wid*16 + l15;
  __shared__ __align__(16) float Bs[2][32][68];   // 17.4 KB

  f32x4 acc[2];
  #pragma unroll
  for (int m = 0; m < 2; ++m) acc[m] = (f32x4){0.f,0.f,0.f,0.f};

  const unsigned short* ahp[2];
  const unsigned short* alp[2];
  #pragma unroll
  for (int m = 0; m < 2; ++m){
    size_t ro = (size_t)(m0 + m*16 + l15)*32 + lg*8;
    ahp[m] = Ah + ro;
    alp[m] = Al + ro;
  }
  const int sr = tid >> 3, sc = (tid & 7) * 8;   // stage: row sr (of 32), 8 cols from sc

  float4 rb0, rb1;
  int4 rah[2], ral[2];
  {
    const float* bp = B + (size_t)(kz + sr)*CDIM + n0 + sc;
    rb0 = *(const float4*)(bp);
    rb1 = *(const float4*)(bp + 4);
    #pragma unroll
    for (int m = 0; m < 2; ++m){
      rah[m] = *(const int4*)(ahp[m]);
      ral[m] = *(const int4*)(alp[m]);
    }
  }

  #pragma unroll 1
  for (int s = 0; s < 16; ++s){
    const int buf = s & 1;                        // runtime index OK: LDS, not registers
    *(float4*)&Bs[buf][sr][sc]     = rb0;
    *(float4*)&Bs[buf][sr][sc + 4] = rb1;
    int4 cah[2], cal[2];
    #pragma unroll
    for (int m = 0; m < 2; ++m){ cah[m] = rah[m]; cal[m] = ral[m]; }
    __syncthreads();
    if (s + 1 < 16){
      const int kr = kz + (s+1)*32;
      const float* bp = B + (size_t)(kr + sr)*CDIM + n0 + sc;
      rb0 = *(const float4*)(bp);
      rb1 = *(const float4*)(bp + 4);
      #pragma unroll
      for (int m = 0; m < 2; ++m){
        rah[m] = *(const int4*)(ahp[m] + (size_t)(s+1)*4096);
        ral[m] = *(const int4*)(alp[m] + (size_t)(s+1)*4096);
      }
    }
    float bv[8];
    #pragma unroll
    for (int j = 0; j < 8; ++j) bv[j] = Bs[buf][lg*8 + j][colL];
    bf16x8 bh, bl;
    #pragma unroll
    for (int j = 0; j < 8; ++j){
      unsigned short h = f2bf(bv[j]);
      bh[j] = (short)h;
      bl[j] = (short)f2bf(bv[j] - bfbits2f(h));
    }
    #pragma unroll
    for (int m = 0; m < 2; ++m){
      union { int4 i; bf16x8 v; } uah, ual;
      uah.i = cah[m]; ual.i = cal[m];
      acc[m] = __builtin_amdgcn_mfma_f32_16x16x32_bf16(uah.v, bh, acc[m], 0, 0, 0);
      acc[m] = __builtin_amdgcn_mfma_f32_16x16x32_bf16(ual.v, bh, acc[m], 0, 0, 0);
      acc[m] = __builtin_amdgcn_mfma_f32_16x16x32_bf16(uah.v, bl, acc[m], 0, 0, 0);
    }
  }
  const int col = n0 + colL;
  #pragma unroll
  for (int m = 0; m < 2; ++m)
    #pragma unroll
    for (int r = 0; r < 4; ++r){
      const int row = m0 + m*16 + lg*4 + r;
      atomicAdd(&C[(size_t)row*CDIM + col], acc[m][r]);
    }
}

// ---------------- q+kv GEMM: LDS-FREE MFMA, slab-tiled A/B — ROUND-21: K-SPLIT z=2 -----------------
// Latency-bound at 5 blk/CU (MfmaUtil 11%, occupancy 44%). grid (40, 32, 2): z = 32-slab chunk ->
// 2560 WGs = 10 blk/CU. Outputs atomicAdd into pre-zeroed q/kv; exactly 2 commutative fp32
// partials -> deterministic. Within-chunk slab order + MFMA term order unchanged (regroup-only,
// accepted ~1e-7 class, rounds 14/15 precedent).
__global__ __launch_bounds__(256) void gemm_mfma_qkvT_kernel(const unsigned short* __restrict__ Ah,
                                                             const unsigned short* __restrict__ Al,
                                                             const unsigned short* __restrict__ BhT,
                                                             const unsigned short* __restrict__ BlT,
                                                             float* __restrict__ Cq,
                                                             float* __restrict__ Ckv){
  const int n0 = blockIdx.x * 64;
  const int m0 = blockIdx.y * 32;
  const int kz = blockIdx.z * 32;           // slab chunk base
  const int ke = kz + 32;
  const int tid = threadIdx.x;
  const int wid = tid >> 6, lane = tid & 63;
  const int l15 = lane & 15, lg = lane >> 4;
  const int col = n0 + wid*16 + l15;
  const size_t ASTR = (size_t)N_TOK*32;     // 32768
  const size_t BSTR = (size_t)2560*32;      // 81920

  f32x4 acc[2];
  #pragma unroll
  for (int m = 0; m < 2; ++m) acc[m] = (f32x4){0.f,0.f,0.f,0.f};

  const unsigned short* aph[2];
  const unsigned short* apl[2];
  #pragma unroll
  for (int m = 0; m < 2; ++m){
    size_t ro = (size_t)(m0 + m*16 + l15)*32 + lg*8;
    aph[m] = Ah + ro;
    apl[m] = Al + ro;
  }
  const unsigned short* bph = BhT + (size_t)col*32 + lg*8;
  const unsigned short* bpl = BlT + (size_t)col*32 + lg*8;

  int4 rah0[2], ral0[2], rah1[2], ral1[2];
  int4 rbh0, rbl0, rbh1, rbl1;
  #pragma unroll
  for (int m = 0; m < 2; ++m){
    rah0[m] = *(const int4*)(aph[m] + (size_t)kz*ASTR);
    ral0[m] = *(const int4*)(apl[m] + (size_t)kz*ASTR);
    rah1[m] = *(const int4*)(aph[m] + (size_t)(kz+1)*ASTR);
    ral1[m] = *(const int4*)(apl[m] + (size_t)(kz+1)*ASTR);
  }
  rbh0 = *(const int4*)(bph + (size_t)kz*BSTR);
  rbl0 = *(const int4*)(bpl + (size_t)kz*BSTR);
  rbh1 = *(const int4*)(bph + (size_t)(kz+1)*BSTR);
  rbl1 = *(const int4*)(bpl + (size_t)(kz+1)*BSTR);

  #pragma unroll 1
  for (int s = kz; s < ke; s += 2){
    {
      union { int4 i; bf16x8 v; } ubh, ubl;
      ubh.i = rbh0; ubl.i = rbl0;
      #pragma unroll
      for (int m = 0; m < 2; ++m){
        union { int4 i; bf16x8 v; } uah, ual;
        uah.i = rah0[m]; ual.i = ral0[m];
        acc[m] = __builtin_amdgcn_mfma_f32_16x16x32_bf16(uah.v, ubh.v, acc[m], 0, 0, 0);
        acc[m] = __builtin_amdgcn_mfma_f32_16x16x32_bf16(ual.v, ubh.v, acc[m], 0, 0, 0);
        acc[m] = __builtin_amdgcn_mfma_f32_16x16x32_bf16(uah.v, ubl.v, acc[m], 0, 0, 0);
      }
    }
    if (s + 2 < ke){
      #pragma unroll
      for (int m = 0; m < 2; ++m){
        rah0[m] = *(const int4*)(aph[m] + (size_t)(s+2)*ASTR);
        ral0[m] = *(const int4*)(apl[m] + (size_t)(s+2)*ASTR);
      }
      rbh0 = *(const int4*)(bph + (size_t)(s+2)*BSTR);
      rbl0 = *(const int4*)(bpl + (size_t)(s+2)*BSTR);
    }
    {
      union { int4 i; bf16x8 v; } ubh, ubl;
      ubh.i = rbh1; ubl.i = rbl1;
      #pragma unroll
      for (int m = 0; m < 2; ++m){
        union { int4 i; bf16x8 v; } uah, ual;
        uah.i = rah1[m]; ual.i = ral1[m];
        acc[m] = __builtin_amdgcn_mfma_f32_16x16x32_bf16(uah.v, ubh.v, acc[m], 0, 0, 0);
        acc[m] = __builtin_amdgcn_mfma_f32_16x16x32_bf16(ual.v, ubh.v, acc[m], 0, 0, 0);
        acc[m] = __builtin_amdgcn_mfma_f32_16x16x32_bf16(uah.v, ubl.v, acc[m], 0, 0, 0);
      }
    }
    if (s + 3 < ke){
      #pragma unroll
      for (int m = 0; m < 2; ++m){
        rah1[m] = *(const int4*)(aph[m] + (size_t)(s+3)*ASTR);
        ral1[m] = *(const int4*)(apl[m] + (size_t)(s+3)*ASTR);
      }
      rbh1 = *(const int4*)(bph + (size_t)(s+3)*BSTR);
      rbl1 = *(const int4*)(bpl + (size_t)(s+3)*BSTR);
    }
  }
  #pragma unroll
  for (int m = 0; m < 2; ++m)
    #pragma unroll
    for (int r = 0; r < 4; ++r){
      const int row = m0 + m*16 + lg*4 + r;
      if (col < 2048) atomicAdd(&Cq[(size_t)row*DIM + col], acc[m][r]);
      else            atomicAdd(&Ckv[(size_t)row*512 + (col - 2048)], acc[m][r]);
    }
}

// ---------------- out-GEMM: LDS-FREE MFMA — ROUND-21: K-SPLIT z=2 (same rationale as qkvT) ---------
__global__ __launch_bounds__(256) void gemm_mfma_outT_kernel(const unsigned short* __restrict__ AT,
                                                             const unsigned short* __restrict__ BhT,
                                                             const unsigned short* __restrict__ BlT,
                                                             float* __restrict__ C){
  const int n0 = blockIdx.x * 64;
  const int m0 = blockIdx.y * 32;
  const int kz = blockIdx.z * 32;
  const int ke = kz + 32;
  const int tid = threadIdx.x;
  const int wid = tid >> 6, lane = tid & 63;
  const int l15 = lane & 15, lg = lane >> 4;
  const int col = n0 + wid*16 + l15;
  const size_t ASTR = (size_t)N_TOK*32;     // 32768
  const size_t BSTR = (size_t)2048*32;      // 65536

  f32x4 acc[2];
  #pragma unroll
  for (int m = 0; m < 2; ++m) acc[m] = (f32x4){0.f,0.f,0.f,0.f};

  const unsigned short* ap[2];
  #pragma unroll
  for (int m = 0; m < 2; ++m)
    ap[m] = AT + (size_t)(m0 + m*16 + l15)*32 + lg*8;
  const unsigned short* bph = BhT + (size_t)col*32 + lg*8;
  const unsigned short* bpl = BlT + (size_t)col*32 + lg*8;

  int4 ra0[2], ra1[2], rbh0, rbl0, rbh1, rbl1;
  #pragma unroll
  for (int m = 0; m < 2; ++m){
    ra0[m] = *(const int4*)(ap[m] + (size_t)kz*ASTR);
    ra1[m] = *(const int4*)(ap[m] + (size_t)(kz+1)*ASTR);
  }
  rbh0 = *(const int4*)(bph + (size_t)kz*BSTR);
  rbl0 = *(const int4*)(bpl + (size_t)kz*BSTR);
  rbh1 = *(const int4*)(bph + (size_t)(kz+1)*BSTR);
  rbl1 = *(const int4*)(bpl + (size_t)(kz+1)*BSTR);

  #pragma unroll 1
  for (int s = kz; s < ke; s += 2){
    {
      union { int4 i; bf16x8 v; } ubh, ubl;
      ubh.i = rbh0; ubl.i = rbl0;
      #pragma unroll
      for (int m = 0; m < 2; ++m){
        union { int4 i; bf16x8 v; } ua; ua.i = ra0[m];
        acc[m] = __builtin_amdgcn_mfma_f32_16x16x32_bf16(ua.v, ubh.v, acc[m], 0, 0, 0);
        acc[m] = __builtin_amdgcn_mfma_f32_16x16x32_bf16(ua.v, ubl.v, acc[m], 0, 0, 0);
      }
    }
    if (s + 2 < ke){
      #pragma unroll
      for (int m = 0; m < 2; ++m)
        ra0[m] = *(const int4*)(ap[m] + (size_t)(s+2)*ASTR);
      rbh0 = *(const int4*)(bph + (size_t)(s+2)*BSTR);
      rbl0 = *(const int4*)(bpl + (size_t)(s+2)*BSTR);
    }
    {
      union { int4 i; bf16x8 v; } ubh, ubl;
      ubh.i = rbh1; ubl.i = rbl1;
      #pragma unroll
      for (int m = 0; m < 2; ++m){
        union { int4 i; bf16x8 v; } ua; ua.i = ra1[m];
        acc[m] = __builtin_amdgcn_mfma_f32_16x16x32_bf16(ua.v, ubh.v, acc[m], 0, 0, 0);
        acc[m] = __builtin_amdgcn_mfma_f32_16x16x32_bf16(ua.v, ubl.v, acc[m], 0, 0, 0);
      }
    }
    if (s + 3 < ke){
      #pragma unroll
      for (int m = 0; m < 2; ++m)
        ra1[m] = *(const int4*)(ap[m] + (size_t)(s+3)*ASTR);
      rbh1 = *(const int4*)(bph + (size_t)(s+3)*BSTR);
      rbl1 = *(const int4*)(bpl + (size_t)(s+3)*BSTR);
    }
  }
  #pragma unroll
  for (int m = 0; m < 2; ++m)
    #pragma unroll
    for (int r = 0; r < 4; ++r){
      const int row = m0 + m*16 + lg*4 + r;
      atomicAdd(&C[(size_t)row*DIM + col], acc[m][r]);
    }
}

// ---------------- RoPE: q fp32 [n][2048], kv fp32 [n][512] -> qr bf16 [n][2048], kr bf16 [n][256] ----
__global__ __launch_bounds__(256) void rope_kernel(const float* __restrict__ q,
    const float* __restrict__ kv, bf16* __restrict__ qr, bf16* __restrict__ kr){
  int n = blockIdx.x, tid = threadIdx.x;
  const float* qrow = q + (size_t)n*DIM;
  bf16* qrrow = qr + (size_t)n*DIM;
  #pragma unroll
  for (int i = 0; i < 4; ++i){
    int p = tid + i*256;
    int hd = p >> 6, ii = p & 63;
    float inv = powf(10000.f, -(float)ii/64.f);
    float ang = (float)n * inv;
    float cs = cosf(ang), sn = sinf(ang);
    float x1 = qrow[hd*DH + 2*ii], x2 = qrow[hd*DH + 2*ii + 1];
    qrrow[hd*DH + 2*ii]     = __float2bfloat16(x1*cs - x2*sn);
    qrrow[hd*DH + 2*ii + 1] = __float2bfloat16(x1*sn + x2*cs);
  }
  if (tid < 128){
    int h = tid >> 6, ii = tid & 63;
    float inv = powf(10000.f, -(float)ii/64.f);
    float ang = (float)n * inv;
    float cs = cosf(ang), sn = sinf(ang);
    const float* kvrow = kv + (size_t)n*512;
    float x1 = kvrow[h*DH + 2*ii], x2 = kvrow[h*DH + 2*ii + 1];
    bf16* krrow = kr + (size_t)n*256;
    krrow[h*DH + 2*ii]     = __float2bfloat16(x1*cs - x2*sn);
    krrow[h*DH + 2*ii + 1] = __float2bfloat16(x1*sn + x2*cs);
  }
}

// ---------------- Build compression-MLP input, k/v fused, SLAB-TILED bf16 hi/lo ---------------------
// fh/fl layout: [kv][128 slabs][128 rows][32] (slab = k/32 within CDIM).
__global__ __launch_bounds__(256) void build_f_kernel(const float* __restrict__ kv,
    const float* __restrict__ k_pos, const float* __restrict__ v_pos,
    unsigned short* __restrict__ fh, unsigned short* __restrict__ fl){
  int bw2 = blockIdx.x;          // 0..255: kvsel*128 + h*NWIN + w
  int kvsel = bw2 >> 7, bw = bw2 & 127;
  int voff = kvsel * 256;
  const float* pos = kvsel ? v_pos : k_pos;
  int h = bw >> 6, w = bw & 63;
  int tid = threadIdx.x;
  for (int idx = tid; idx < CMP_BLK*DH; idx += 256){
    int j = idx >> 7, d = idx & 127;
    int t = w*16 + j - 16;       // padded window index
    float kvv = (t >= 0) ? kv[(size_t)t*512 + voff + h*DH + d] : 0.f;
    float v = kvv + pos[(h*CMP_BLK + j)*DH + d];
    unsigned short hh = f2bf(v);
    int sl = idx >> 5, kk = idx & 31;
    size_t o = (size_t)kvsel*524288 + (size_t)sl*4096 + (size_t)bw*32 + kk;
    fh[o] = hh;
    fl[o] = f2bf(v - bfbits2f(hh));
  }
}

// ---------------- Assemble ck/cv [KVH][NCMP][DH]; MLP second bias folded here ----------------
__global__ __launch_bounds__(256) void assemble_kernel(const float* __restrict__ ckb,
    const float* __restrict__ cvb, const float* __restrict__ mem_kv,
    const float* __restrict__ bk2, const float* __restrict__ bv2,
    float* __restrict__ ck, float* __restrict__ cv){
  int j = blockIdx.x;            // 0..64
  int tid = threadIdx.x;         // 256 = KVH*DH
  int h = tid >> 7, d = tid & 127;
  float kvx, vvx;
  if (j == 0){
    kvx = mem_kv[(0*KVH + h)*DH + d];
    vvx = mem_kv[(1*KVH + h)*DH + d];
  } else {
    kvx = ckb[((size_t)h*NWIN + (j-1))*DH + d] + bk2[d];
    vvx = cvb[((size_t)h*NWIN + (j-1))*DH + d] + bv2[d];
  }
  ck[((size_t)h*NCMP + j)*DH + d] = kvx;
  cv[((size_t)h*NCMP + j)*DH + d] = vvx;
}

// ---------------- Compressed attention (pre-rope q, fp32) + importance + top-4 selection ----------------
__global__ __launch_bounds__(256) void cmp_attn_kernel(const float* __restrict__ q,
    const float* __restrict__ ck, const float* __restrict__ cv,
    bf16* __restrict__ cmp_o, int* __restrict__ sel){
  int bx = blockIdx.x;
  int h = bx >> 10, n = bx & 1023;
  int tid = threadIdx.x;
  __shared__ float cks[NCMP*129];
  __shared__ float qs[GQ*DH];
  __shared__ float sims[GQ*66];
  __shared__ float red[GQ*32];
  __shared__ float impb[NFINE];
  for (int idx = tid; idx < NCMP*DH; idx += 256){
    int j = idx >> 7, d = idx & 127;
    cks[j*129 + d] = ck[((size_t)h*NCMP + j)*DH + d];
  }
  for (int idx = tid; idx < GQ*DH; idx += 256)
    qs[idx] = q[(size_t)n*DIM + h*(GQ*DH) + idx];
  __syncthreads();
  for (int p = tid; p < GQ*NCMP; p += 256){
    int g = p / NCMP, j = p % NCMP;
    float acc = 0.f;
    const float* qp = &qs[g*DH];
    const float* kp = &cks[j*129];
    #pragma unroll 4
    for (int d = 0; d < DH; ++d) acc += qp[d]*kp[d];
    sims[g*66 + j] = acc * SCALE;
  }
  __syncthreads();
  if (tid < NFINE){
    float s = 0.f;
    for (int g = 0; g < GQ; ++g)
      #pragma unroll
      for (int c = 0; c < 4; ++c)
        s += sims[g*66 + 1 + tid*4 + c];
    impb[tid] = s;
  }
  __syncthreads();
  if (tid == 0){
    int own = n >> 6;
    impb[own] = -1e30f;
    int selbuf[5];
    #pragma unroll
    for (int r = 0; r < 4; ++r){
      float best = -1e38f; int bi = 0;
      for (int f = 0; f < NFINE; ++f)
        if (impb[f] > best){ best = impb[f]; bi = f; }   // strict > : lowest index on ties
      selbuf[r] = bi; impb[bi] = -1e38f;
    }
    selbuf[4] = own;
    for (int r = 0; r < 5; ++r) sel[(size_t)(h*N_TOK + n)*8 + r] = selbuf[r];
  }
  int g = tid >> 5, lane = tid & 31;
  float m = -1e38f;
  for (int j = lane; j < NCMP; j += 32) m = fmaxf(m, sims[g*66 + j]);
  red[g*32 + lane] = m; __syncthreads();
  for (int st = 16; st > 0; st >>= 1){ if (lane < st) red[g*32+lane] = fmaxf(red[g*32+lane], red[g*32+lane+st]); __syncthreads(); }
  float gm = red[g*32]; __syncthreads();
  float ps = 0.f;
  for (int j = lane; j < NCMP; j += 32){ float e = expf(sims[g*66+j] - gm); sims[g*66+j] = e; ps += e; }
  red[g*32+lane] = ps; __syncthreads();
  for (int st = 16; st > 0; st >>= 1){ if (lane < st) red[g*32+lane] += red[g*32+lane+st]; __syncthreads(); }
  float inv = 1.f / red[g*32]; __syncthreads();
  for (int j = lane; j < NCMP; j += 32) sims[g*66+j] *= inv;
  __syncthreads();
  for (int p = tid; p < GQ*DH; p += 256){
    int gg = p >> 7, d = p & 127;
    float acc = 0.f;
    const float* cvp = cv + (size_t)h*NCMP*DH + d;
    for (int j = 0; j < NCMP; ++j) acc += sims[gg*66 + j] * cvp[j*DH];
    cmp_o[(size_t)n*DIM + (h*GQ + gg)*DH + d] = __float2bfloat16(acc);
  }
}

// ---------------- Fine attention — round-20 PASSING: T14 prefetch with NAMED SCALAR registers -------
#define FA_LOADK(blk) do{ \
    const bf16* p_ = kr + (size_t)((blk)*SEL_BLK + tK)*256 + h*DH; \
    k0 = *(const int4*)(p_ + dK);      \
    k1 = *(const int4*)(p_ + dK + 32); \
    k2 = *(const int4*)(p_ + dK + 64); \
    k3 = *(const int4*)(p_ + dK + 96); \
  }while(0)
#define FA_STOREK1(reg, db) do{ \
    unsigned w0_=(unsigned)(reg).x, w1_=(unsigned)(reg).y, w2_=(unsigned)(reg).z, w3_=(unsigned)(reg).w; \
    float* d_ = &kvbuf[(size_t)(db)*66 + tK]; \
    d_[0]   = bfbits2f(w0_ & 0xffffu); d_[66]  = bfbits2f(w0_ >> 16); \
    d_[132] = bfbits2f(w1_ & 0xffffu); d_[198] = bfbits2f(w1_ >> 16); \
    d_[264] = bfbits2f(w2_ & 0xffffu); d_[330] = bfbits2f(w2_ >> 16); \
    d_[396] = bfbits2f(w3_ & 0xffffu); d_[462] = bfbits2f(w3_ >> 16); \
  }while(0)
#define FA_STOREK do{ FA_STOREK1(k0,(dK)); FA_STOREK1(k1,(dK+32)); FA_STOREK1(k2,(dK+64)); FA_STOREK1(k3,(dK+96)); }while(0)
#define FA_QK(tile) do{ \
    float acc0_ = 0.f, acc1_ = 0.f; \
    const float* qp_ = &qs[qi*DH]; \
    const float* kp_ = &kvbuf[2*tx]; \
    _Pragma("unroll") \
    for (int d_ = 0; d_ < DH; d_ += 4){ \
      float4 a_ = *(const float4*)(qp_ + d_); \
      float2 b0_ = *(const float2*)(kp_ + (size_t)(d_  )*66); \
      float2 b1_ = *(const float2*)(kp_ + (size_t)(d_+1)*66); \
      float2 b2_ = *(const float2*)(kp_ + (size_t)(d_+2)*66); \
      float2 b3_ = *(const float2*)(kp_ + (size_t)(d_+3)*66); \
      acc0_ += a_.x*b0_.x; acc1_ += a_.x*b0_.y; \
      acc0_ += a_.y*b1_.x; acc1_ += a_.y*b1_.y; \
      acc0_ += a_.z*b2_.x; acc1_ += a_.z*b2_.y; \
      acc0_ += a_.w*b3_.x; acc1_ += a_.w*b3_.y; \
    } \
    *(float2*)&sims[(size_t)qi*322 + (tile)*SEL_BLK + 2*tx] = make_float2(acc0_*SCALE, acc1_*SCALE); \
  }while(0)
#define FA_LOADV(blk) do{ \
    const float* p_ = kv + (size_t)((blk)*SEL_BLK + tV)*512 + 256 + h*DH; \
    v0 = *(const float4*)(p_ + dV);         \
    v1 = *(const float4*)(p_ + 4096 + dV);  \
    v2 = *(const float4*)(p_ + 8192 + dV);  \
    v3 = *(const float4*)(p_ + 12288 + dV); \
    v4 = *(const float4*)(p_ + 16384 + dV); \
    v5 = *(const float4*)(p_ + 20480 + dV); \
    v6 = *(const float4*)(p_ + 24576 + dV); \
    v7 = *(const float4*)(p_ + 28672 + dV); \
  }while(0)
#define FA_STOREV do{ \
    float* d_ = &kvbuf[(size_t)tV*132 + dV]; \
    *(float4*)(d_)        = v0; \
    *(float4*)(d_ + 1056) = v1; \
    *(float4*)(d_ + 2112) = v2; \
    *(float4*)(d_ + 3168) = v3; \
    *(float4*)(d_ + 4224) = v4; \
    *(float4*)(d_ + 5280) = v5; \
    *(float4*)(d_ + 6336) = v6; \
    *(float4*)(d_ + 7392) = v7; \
  }while(0)
#define FA_PV(tile) do{ \
    const float* sp_ = &sims[(size_t)qi*322 + (tile)*SEL_BLK]; \
    const float* vp_ = &kvbuf[tx << 2]; \
    _Pragma("unroll 8") \
    for (int t_ = 0; t_ < SEL_BLK; ++t_){ \
      float p_ = sp_[t_]; \
      float4 vv_ = *(const float4*)(vp_ + (size_t)t_*132); \
      av0 += p_*vv_.x; av1 += p_*vv_.y; av2 += p_*vv_.z; av3 += p_*vv_.w; \
    } \
  }while(0)

__global__ __launch_bounds__(256) void fine_attn_kernel(const bf16* __restrict__ qr,
    const bf16* __restrict__ kr, const float* __restrict__ kv,
    const int* __restrict__ sel, bf16* __restrict__ fine_o){
  int bx = blockIdx.x;
  int h = bx >> 10, n = bx & 1023;
  int tid = threadIdx.x;
  __shared__ __align__(16) float kvbuf[8448];   // kT[128][66] (QK) | V[64][132] (PV)
  __shared__ __align__(16) float qs[GQ*DH];     // natural [qi][d]
  __shared__ float sims[GQ*322];
  __shared__ float red[GQ*32];
  const int qi = tid >> 5, tx = tid & 31;

  int s0_, s1_, s2_, s3_, s4_;
  {
    const int* sp = sel + (size_t)(h*N_TOK + n)*8;
    int b0 = sp[0], b1 = sp[1], b2 = sp[2], b3 = sp[3], b4 = sp[4];
    s0_ = (b0 < 0) ? 0 : (b0 > 15 ? 15 : b0);
    s1_ = (b1 < 0) ? 0 : (b1 > 15 ? 15 : b1);
    s2_ = (b2 < 0) ? 0 : (b2 > 15 ? 15 : b2);
    s3_ = (b3 < 0) ? 0 : (b3 > 15 ? 15 : b3);
    s4_ = (b4 < 0) ? 0 : (b4 > 15 ? 15 : b4);
  }
  for (int idx = tid; idx < GQ*DH; idx += 256)
    qs[idx] = b2f(qr[(size_t)n*DIM + h*(GQ*DH) + idx]);

  // ---- QK phase: per-thread coords. (tid+i*256)&63 == tid&63; d0_i = dK + 32*i.
  const int tK = tid & 63;
  const int dK = (tid >> 6) << 3;
  int4 k0, k1, k2, k3;
  FA_LOADK(s0_);
  __syncthreads(); FA_STOREK; __syncthreads(); FA_LOADK(s1_); FA_QK(0);
  __syncthreads(); FA_STOREK; __syncthreads(); FA_LOADK(s2_); FA_QK(1);
  __syncthreads(); FA_STOREK; __syncthreads(); FA_LOADK(s3_); FA_QK(2);
  __syncthreads(); FA_STOREK; __syncthreads(); FA_LOADK(s4_); FA_QK(3);
  __syncthreads(); FA_STOREK; __syncthreads();                FA_QK(4);

  // ---- prefetch V tile 0 (overlaps softmax). t_i = tV + 8*i; dV constant.
  const int tV = tid >> 5;
  const int dV = (tid & 31) << 2;
  float4 v0, v1, v2, v3, v4, v5, v6, v7;
  FA_LOADV(s0_);
  __syncthreads();

  // ---- softmax over 320 (unchanged mapping/order)
  {
    int g = qi, lane = tx;
    float m = -1e38f;
    for (int t = lane; t < T_TOT; t += 32) m = fmaxf(m, sims[g*322 + t]);
    red[g*32+lane] = m; __syncthreads();
    for (int st = 16; st > 0; st >>= 1){ if (lane < st) red[g*32+lane] = fmaxf(red[g*32+lane], red[g*32+lane+st]); __syncthreads(); }
    float gm = red[g*32]; __syncthreads();
    float ps = 0.f;
    for (int t = lane; t < T_TOT; t += 32){ float e = expf(sims[g*322+t] - gm); sims[g*322+t] = e; ps += e; }
    red[g*32+lane] = ps; __syncthreads();
    for (int st = 16; st > 0; st >>= 1){ if (lane < st) red[g*32+lane] += red[g*32+lane+st]; __syncthreads(); }
    float inv = 1.f / red[g*32]; __syncthreads();
    for (int t = lane; t < T_TOT; t += 32) sims[g*322+t] *= inv;
  }

  // ---- PV phase with prefetch
  float av0 = 0.f, av1 = 0.f, av2 = 0.f, av3 = 0.f;
  __syncthreads(); FA_STOREV; __syncthreads(); FA_LOADV(s1_); FA_PV(0);
  __syncthreads(); FA_STOREV; __syncthreads(); FA_LOADV(s2_); FA_PV(1);
  __syncthreads(); FA_STOREV; __syncthreads(); FA_LOADV(s3_); FA_PV(2);
  __syncthreads(); FA_STOREV; __syncthreads(); FA_LOADV(s4_); FA_PV(3);
  __syncthreads(); FA_STOREV; __syncthreads();                FA_PV(4);
  {
    bf16 o[4];
    o[0] = __float2bfloat16(av0);
    o[1] = __float2bfloat16(av1);
    o[2] = __float2bfloat16(av2);
    o[3] = __float2bfloat16(av3);
    *(ushort4*)(fine_o + (size_t)n*DIM + (h*GQ + qi)*DH + (tx << 2)) = *(const ushort4*)o;
  }
}

// ---------------- Sliding-window attention, flash-style online softmax --------------------------
__global__ __launch_bounds__(256) void slide_attn_kernel(const bf16* __restrict__ qr,
    const bf16* __restrict__ kr, const float* __restrict__ kv,
    bf16* __restrict__ slide_o){
  int hq = blockIdx.y;          // 16 heads
  int qt = blockIdx.x;          // 32 query tiles of 32
  int h = hq >> 3;
  int n0 = qt * 32;
  int tid = threadIdx.x;
  __shared__ float qT[128*36];   // [d][qi], pad 36
  __shared__ float kvb[128*68];  // K^T [d][t] pad 68 (QK) | V [t][128] (PV)
  __shared__ float stT[64*36];   // [t][qi] exp'd probs, pad 36

  const int ty  = tid >> 5;
  const int tx  = tid & 31;
  const int qi0 = ty << 2;

  for (int c = tid; c < 512; c += 256){
    int qi = c & 31, d0 = (c >> 5) << 3;
    int4 w = *(const int4*)(qr + (size_t)(n0+qi)*DIM + hq*DH + d0);
    float* dst = &qT[(size_t)d0*36 + qi];
    unsigned int wv[4] = {(unsigned)w.x,(unsigned)w.y,(unsigned)w.z,(unsigned)w.w};
    #pragma unroll
    for (int m = 0; m < 4; ++m){
      dst[(2*m  )*36] = bfbits2f(wv[m] & 0xffffu);
      dst[(2*m+1)*36] = bfbits2f(wv[m] >> 16);
    }
  }

  float acc[4][4] = {};
  float mrow[4] = {-1e30f,-1e30f,-1e30f,-1e30f};
  float lrow[4] = {0.f,0.f,0.f,0.f};
  float arow[4];
  const int kstart = n0 - 128;

  for (int tile = 0; tile < 5; ++tile){
    const int kbase = kstart + tile*64;
    __syncthreads();
    for (int c = tid; c < 1024; c += 256){
      int t = c & 63, d0 = (c >> 6) << 3;
      int kg = kbase + t;
      int kgc = min(max(kg, 0), N_TOK-1);
      int4 w = *(const int4*)(kr + (size_t)kgc*256 + h*DH + d0);
      float* dst = &kvb[(size_t)d0*68 + t];
      unsigned int wv[4] = {(unsigned)w.x,(unsigned)w.y,(unsigned)w.z,(unsigned)w.w};
      #pragma unroll
      for (int m = 0; m < 4; ++m){
        dst[(2*m  )*68] = bfbits2f(wv[m] & 0xffffu);
        dst[(2*m+1)*68] = bfbits2f(wv[m] >> 16);
      }
    }
    __syncthreads();
    float c0[8] = {};
    {
      const float* aP = qT + qi0;
      const float* bP = kvb + (tx << 1);
      #pragma unroll 4
      for (int d = 0; d < 128; ++d){
        float4 a = *(const float4*)(aP + d*36);
        float2 b = *(const float2*)(bP + d*68);
        c0[0] += a.x*b.x; c0[1] += a.x*b.y;
        c0[2] += a.y*b.x; c0[3] += a.y*b.y;
        c0[4] += a.z*b.x; c0[5] += a.z*b.y;
        c0[6] += a.w*b.x; c0[7] += a.w*b.y;
      }
    }
    const int kg0 = kbase + (tx << 1);
    #pragma unroll
    for (int i = 0; i < 4; ++i){
      int qg = n0 + qi0 + i;
      int d0 = qg - kg0, d1 = d0 - 1;
      bool v0 = (kg0   >= 0) && (kg0   < N_TOK) && (d0 <= 128) && (d0 >= -128);
      bool v1 = (kg0+1 >= 0) && (kg0+1 < N_TOK) && (d1 <= 128) && (d1 >= -128);
      float s0 = v0 ? c0[i*2  ]*SCALE : -1e30f;
      float s1 = v1 ? c0[i*2+1]*SCALE : -1e30f;
      float mi = fmaxf(s0, s1);
      #pragma unroll
      for (int off = 1; off < 32; off <<= 1) mi = fmaxf(mi, __shfl_xor(mi, off));
      float mold = mrow[i];
      float mnew = fmaxf(fmaxf(mold, mi), -1e20f);
      arow[i] = expf(mold - mnew);
      mrow[i] = mnew;
      float e0 = expf(s0 - mnew);
      float e1 = expf(s1 - mnew);
      float ps = e0 + e1;
      #pragma unroll
      for (int off = 1; off < 32; off <<= 1) ps += __shfl_xor(ps, off);
      lrow[i] = lrow[i]*arow[i] + ps;
      stT[(size_t)(2*tx  )*36 + qi0 + i] = e0;
      stT[(size_t)(2*tx+1)*36 + qi0 + i] = e1;
    }
    __syncthreads();
    for (int c = tid; c < 2048; c += 256){
      int t = c >> 5, d0 = (c & 31) << 2;
      int kg = kbase + t;
      int kgc = min(max(kg, 0), N_TOK-1);
      float4 v = *(const float4*)(kv + (size_t)kgc*512 + 256 + h*DH + d0);
      *(float4*)&kvb[(size_t)t*128 + d0] = v;
    }
    __syncthreads();
    #pragma unroll
    for (int i = 0; i < 4; ++i){
      float ar = arow[i];
      acc[i][0] *= ar; acc[i][1] *= ar; acc[i][2] *= ar; acc[i][3] *= ar;
    }
    {
      const float* pP = stT + qi0;
      const float* vP = kvb + (tx << 2);
      #pragma unroll 4
      for (int t = 0; t < 64; ++t){
        float4 p = *(const float4*)(pP + t*36);
        float4 v = *(const float4*)(vP + t*128);
        acc[0][0] += p.x*v.x; acc[0][1] += p.x*v.y; acc[0][2] += p.x*v.z; acc[0][3] += p.x*v.w;
        acc[1][0] += p.y*v.x; acc[1][1] += p.y*v.y; acc[1][2] += p.y*v.z; acc[1][3] += p.y*v.w;
        acc[2][0] += p.z*v.x; acc[2][1] += p.z*v.y; acc[2][2] += p.z*v.z; acc[2][3] += p.z*v.w;
        acc[3][0] += p.w*v.x; acc[3][1] += p.w*v.y; acc[3][2] += p.w*v.z; acc[3][3] += p.w*v.w;
      }
    }
  }
  #pragma unroll
  for (int i = 0; i < 4; ++i){
    int row = n0 + qi0 + i;
    float inv = 1.f / lrow[i];
    bf16 o[4];
    o[0] = __float2bfloat16(acc[i][0]*inv);
    o[1] = __float2bfloat16(acc[i][1]*inv);
    o[2] = __float2bfloat16(acc[i][2]*inv);
    o[3] = __float2bfloat16(acc[i][3]*inv);
    *(ushort4*)(slide_o + (size_t)row*DIM + hq*DH + (tx << 2)) = *(const ushort4*)o;
  }
}

// ---------------- Gated combine -> ocombT bf16 SLAB-TILED [s][row][kk] ------------------------------
__global__ __launch_bounds__(256) void combine_kernel(const bf16* __restrict__ cmp_o,
    const bf16* __restrict__ fine_o, const bf16* __restrict__ slide_o,
    const float* __restrict__ graw, const float* __restrict__ bg,
    unsigned short* __restrict__ ocombT){
  int n = blockIdx.x, tid = threadIdx.x;
  #pragma unroll
  for (int i = 0; i < 8; ++i){
    int c = tid + i*256;
    int hq = c >> 7;
    float g0 = 1.f/(1.f + expf(-(graw[(size_t)n*48 + hq*3 + 0] + bg[hq*3 + 0])));
    float g1 = 1.f/(1.f + expf(-(graw[(size_t)n*48 + hq*3 + 1] + bg[hq*3 + 1])));
    float g2 = 1.f/(1.f + expf(-(graw[(size_t)n*48 + hq*3 + 2] + bg[hq*3 + 2])));
    size_t idx = (size_t)n*DIM + c;
    float v = b2f(cmp_o[idx])*g0 + b2f(fine_o[idx])*g1 + b2f(slide_o[idx])*g2;
    int sl = c >> 5, kk = c & 31;
    ocombT[(size_t)sl*(N_TOK*32) + (size_t)n*32 + kk] = f2bf(v);
  }
}

extern "C" void kernel_launch(void* const* d_in, const int* in_sizes, int n_in,
                              void* d_out, int out_size, void* d_ws, size_t ws_size,
                              hipStream_t stream)
{
  const float* x      = (const float*)d_in[0];
  const float* g_norm = (const float*)d_in[1];
  const float* W_qkv  = (const float*)d_in[2];
  const float* k_pos  = (const float*)d_in[3];
  const float* v_pos  = (const float*)d_in[4];
  const float* mem_kv = (const float*)d_in[5];
  const float* Wk1    = (const float*)d_in[6];
  const float* bk1    = (const float*)d_in[7];
  const float* Wk2    = (const float*)d_in[8];
  const float* bk2    = (const float*)d_in[9];
  const float* Wv1    = (const float*)d_in[10];
  const float* bv1    = (const float*)d_in[11];
  const float* Wv2    = (const float*)d_in[12];
  const float* bv2    = (const float*)d_in[13];
  const float* Wg     = (const float*)d_in[14];
  const float* bg     = (const float*)d_in[15];
  const float* W_out  = (const float*)d_in[16];
  float* out = (float*)d_out;
  (void)ws_size; (void)in_sizes; (void)n_in; (void)out_size;

  // ---- Workspace layout (bytes), peak ~54.5 MB ----
  char* base = (char*)d_ws;
  float* q     = (float*)(base + 0);                 // 8 MB [n][2048] fp32, live -> cmp_attn
  float* xn    = (float*)(base + 8388608);           // 8 MB fp32
  bf16*  qr    = (bf16*) (base + 8388608);           // 4 MB (over xn, after xn dead)
  bf16*  kr    = (bf16*) (base + 12582912);          // 0.5 MB
  unsigned short* ocombT = (unsigned short*)(base + 8388608);  // 4 MB (over qr, after slide) slab-tiled
  float* kv    = (float*)(base + 16777216);          // 2 MB [n][512] fp32 (atomic-accumulated)
  float* hbuf2 = (float*)(base + 18874368);          // 4 MB: [2][128][4096] fp32 (k, v halves)
  bf16*  cmp_o = (bf16*) (base + 18874368);          // 4 MB (over hbuf2, after MLP2s)
  float* ckb   = (float*)(base + 23068672);          // 64 KB (raw)
  float* cvb   = (float*)(base + 23134208);          // 64 KB (raw)
  float* ck    = (float*)(base + 23199744);          // 65 KB
  float* cv    = (float*)(base + 23266304);          // 65 KB
  float* gates = (float*)(base + 23332864);          // 192 KB (raw, sigmoid folded in combine)
  int*   sel   = (int*)  (base + 23529472);          // 64 KB
  bf16*  fine_o  = (bf16*)(base + 0);                // 4 MB (over q, after cmp_attn)
  bf16*  slide_o = (bf16*)(base + 4194304);          // 4 MB (over q upper half)
  // Pre-split operands (xnh/xnl and ocombT are SLAB-TILED [s][row][32])
  unsigned short* xnh  = (unsigned short*)(base + 25165824);  // 4 MB bf16 hi(xn)
  unsigned short* xnl  = (unsigned short*)(base + 29360128);  // 4 MB bf16 lo(xn)
  unsigned short* WqhT = (unsigned short*)(base + 33554432);  // 10.49 MB: full W_qkv hi, [s][2560][32]
  unsigned short* WqlT = (unsigned short*)(base + 44040192);  // 10.49 MB: lo     (ends 54,525,952)
  unsigned short* WohT = WqhT;   // W_out split reuses first 8 MB of each region (after qkv GEMM)
  unsigned short* WolT = WqlT;
  unsigned short* fh   = (unsigned short*)(base + 41943040);  // 2 MB, tail of WqhT region (Wq dead)
  unsigned short* fl   = (unsigned short*)(base + 52428800);  // 2 MB, tail of WqlT region

  // Zero split-K accumulation targets (stream-ordered; graph-capture legal)
  hipMemsetAsync(gates, 0, (size_t)N_TOK*48*4,    stream);
  hipMemsetAsync(ckb,   0, (size_t)KVH*NWIN*DH*4, stream);
  hipMemsetAsync(cvb,   0, (size_t)KVH*NWIN*DH*4, stream);
  hipMemsetAsync(hbuf2, 0, (size_t)2*128*CDIM*4,  stream);
  hipMemsetAsync(q,     0, (size_t)N_TOK*DIM*4,   stream);   // qkvT z=2 accumulation targets
  hipMemsetAsync(kv,    0, (size_t)N_TOK*512*4,   stream);
  hipMemsetAsync(out,   0, (size_t)N_TOK*DIM*4,   stream);   // outT z=2 accumulation target

  // Full W_qkv (2560 cols) -> slab-tiled hi/lo bf16 split
  transpose_split_kernel<<<dim3(40, 32), 256, 0, stream>>>(W_qkv, 2560, 2560, WqhT, WqlT);
  rmsnorm_kernel<<<N_TOK, 256, 0, stream>>>(x, g_norm, xn, xnh, xnl);
  // gates_raw = xn @ Wg [1024 x 48] — z=16 (round-15, passing)
  gemm_splitk_kernel<<<dim3(1, 16, 16), 256, 0, stream>>>(xn, 0, nullptr, Wg, 48, gates, N_TOK, 48, DIM, 128);
  // q + kv in ONE LDS-free MFMA GEMM — K-split z=2 (10 blk/CU; 2-partial regroup, accepted class)
  gemm_mfma_qkvT_kernel<<<dim3(40, 32, 2), 256, 0, stream>>>(xnh, xnl, WqhT, WqlT, q, kv);
  // W_out -> slab-tiled hi/lo split (reuses first 8 MB of Wq regions; ordered after qkv GEMM)
  transpose_split_kernel<<<dim3(32, 32), 256, 0, stream>>>(W_out, 2048, 2048, WohT, WolT);
  // qr, kr (bf16) — xn dead after this point
  rope_kernel<<<N_TOK, 256, 0, stream>>>(q, kv, qr, kr);
  // compression MLP1s: staged MFMA (W1 pre-split removed — round-17 showed it net-negative)
  build_f_kernel<<<256, 256, 0, stream>>>(kv, k_pos, v_pos, fh, fl);
  gemm_mfma_mlp1_kernel<<<dim3(64, 4, 16), 256, 0, stream>>>(fh, fl, Wk1, Wv1, hbuf2);
  // MLP2s fused into one dispatch (round-14, passing)
  gemm_mlp2_fused_kernel<<<dim3(2, 2, 64), 256, 0, stream>>>(hbuf2, bk1, bv1, Wk2, Wv2, ckb, cvb);
  assemble_kernel<<<NCMP, 256, 0, stream>>>(ckb, cvb, mem_kv, bk2, bv2, ck, cv);
  // compressed attention + selection (-> cmp_o, over hbuf2 after MLP2s done)
  cmp_attn_kernel<<<KVH*N_TOK, 256, 0, stream>>>(q, ck, cv, cmp_o, sel);
  // fine attention (q dead -> fine_o over q region), round-20 named-scalar prefetch (passing)
  fine_attn_kernel<<<KVH*N_TOK, 256, 0, stream>>>(qr, kr, kv, sel, fine_o);
  // sliding attention (-> slide_o over q upper half)
  slide_attn_kernel<<<dim3(32, 16), 256, 0, stream>>>(qr, kr, kv, slide_o);
  // combine (qr dead -> ocombT over qr, slab-tiled); sigmoid(graw+bg) folded here
  combine_kernel<<<N_TOK, 256, 0, stream>>>(cmp_o, fine_o, slide_o, gates, bg, ocombT);
  // out = ocomb @ W_out — K-split z=2 (same rationale/class as qkvT)
  gemm_mfma_outT_kernel<<<dim3(32, 32, 2), 256, 0, stream>>>(ocombT, WohT, WolT, out);
}

// Round 22
// 739.572 us; speedup vs baseline: 1.0206x; 1.0206x over previous
//
#include <hip/hip_runtime.h>
#include <hip/hip_bf16.h>
#include <math.h>

typedef __hip_bfloat16 bf16;
typedef __attribute__((ext_vector_type(8))) short bf16x8;
typedef __attribute__((ext_vector_type(4))) float f32x4;

#define N_TOK 1024
#define DIM 2048
#define NHEADS 16
#define KVH 2
#define DH 128
#define GQ 8
#define NWIN 64
#define CMP_BLK 32
#define NCMP 65        // MEM_KV + NWIN
#define NFINE 16
#define SEL_BLK 64
#define T_TOT 320
#define CDIM 4096      // CMP_BLK*DH
#define SCALE 0.08838834764831845f

static __device__ __forceinline__ float b2f(bf16 v){ return __bfloat162float(v); }
static __device__ __forceinline__ float bfbits2f(unsigned int u){
  union { unsigned int i; float f; } x; x.i = u << 16; return x.f;
}
// RNE float->bf16 bits (matches __float2bfloat16 for normal values)
static __device__ __forceinline__ unsigned short f2bf(float f){
  union { float f; unsigned u; } x; x.f = f;
  unsigned r = x.u + 0x7fffu + ((x.u >> 16) & 1u);
  return (unsigned short)(r >> 16);
}

// ---------------- RMSNorm: x fp32 [N,DIM] -> xn fp32 + xnh/xnl bf16 hi/lo SLAB-TILED ----------------
__global__ __launch_bounds__(256) void rmsnorm_kernel(const float* __restrict__ x,
                                                      const float* __restrict__ g,
                                                      float* __restrict__ xn,
                                                      unsigned short* __restrict__ xnh,
                                                      unsigned short* __restrict__ xnl){
  int n = blockIdx.x, tid = threadIdx.x;
  __shared__ float red[256];
  const float* row = x + (size_t)n*DIM;
  float vals[8];
  float s = 0.f;
  #pragma unroll
  for (int i = 0; i < 8; ++i){ float v = row[tid + i*256]; vals[i] = v; s += v*v; }
  red[tid] = s; __syncthreads();
  for (int st = 128; st > 0; st >>= 1){ if (tid < st) red[tid] += red[tid+st]; __syncthreads(); }
  float scale = 1.0f / sqrtf(red[0]/(float)DIM + 1e-6f);
  #pragma unroll
  for (int i = 0; i < 8; ++i){
    int c = tid + i*256;
    float v = vals[i]*scale*g[c];
    xn[(size_t)n*DIM + c] = v;
    unsigned short h = f2bf(v);
    int sl = c >> 5, kk = c & 31;
    size_t o = (size_t)sl*(N_TOK*32) + (size_t)n*32 + kk;
    xnh[o] = h;
    xnl[o] = f2bf(v - bfbits2f(h));
  }
}

// ---------------- Transpose + hi/lo split into SLAB-TILED layout --------------------------------
__global__ __launch_bounds__(256) void transpose_split_kernel(const float* __restrict__ W, int ldw,
                                                              int ncols,
                                                              unsigned short* __restrict__ Th,
                                                              unsigned short* __restrict__ Tl){
  __shared__ float t[64][65];
  int bx = blockIdx.x;   // n tile
  int by = blockIdx.y;   // k tile
  int tid = threadIdx.x;
  #pragma unroll
  for (int i = 0; i < 16; ++i){
    int idx = tid + i*256;
    int r = idx >> 6, c = idx & 63;            // r=k_local, c=n_local (coalesced read)
    t[r][c] = W[(size_t)(by*64 + r)*ldw + bx*64 + c];
  }
  __syncthreads();
  #pragma unroll
  for (int i = 0; i < 16; ++i){
    int idx = tid + i*256;
    int nl = idx >> 6, kl = idx & 63;          // kl consecutive -> kk contiguous (coalesced)
    float v = t[kl][nl];
    unsigned short h = f2bf(v);
    unsigned short l = f2bf(v - bfbits2f(h));
    int s = by*2 + (kl >> 5), kk = kl & 31;
    size_t o = (size_t)s*((size_t)ncols*32) + (size_t)(bx*64 + nl)*32 + kk;
    Th[o] = h;
    Tl[o] = l;
  }
}

// ---------------- Split-K GEMM (64x64 tile) — kept for gates -----------------------------------
__global__ __launch_bounds__(256) void gemm_splitk_kernel(const void* __restrict__ Av, int a_is_bf16,
                                                          const float* __restrict__ afold,
                                                          const float* __restrict__ B, int ldb,
                                                          float* __restrict__ C,
                                                          int M, int N, int K, int kchunk){
  __shared__ __align__(16) float As[16*68];
  __shared__ __align__(16) float Bs[16*68];
  int tid = threadIdx.x;
  int tx = tid & 15, ty = tid >> 4;
  int m0 = blockIdx.y * 64, n0 = blockIdx.x * 64;
  int kz = blockIdx.z * kchunk;
  const float* Af = (const float*)Av;
  const bf16*  Ab = (const bf16*)Av;
  float c[4][4] = {};
  for (int k0 = kz; k0 < kz + kchunk; k0 += 16){
    #pragma unroll
    for (int i = 0; i < 4; ++i){
      int idx = tid + i*256;
      int kk = idx & 15, m = idx >> 4;
      size_t aidx = (size_t)(m0+m)*K + k0 + kk;
      float av = a_is_bf16 ? b2f(Ab[aidx]) : Af[aidx];
      if (afold) av = fmaxf(av + afold[k0+kk], 0.f);
      As[kk*68 + m] = av;
    }
    #pragma unroll
    for (int i = 0; i < 4; ++i){
      int idx = tid + i*256;
      int nn = idx & 63, kk = idx >> 6;
      int col = n0 + nn;
      Bs[kk*68 + nn] = (col < N) ? B[(size_t)(k0+kk)*ldb + col] : 0.f;
    }
    __syncthreads();
    #pragma unroll
    for (int kk = 0; kk < 16; ++kk){
      float a[4], b[4];
      *(float4*)a = *(const float4*)&As[kk*68 + ty*4];
      *(float4*)b = *(const float4*)&Bs[kk*68 + tx*4];
      #pragma unroll
      for (int i = 0; i < 4; ++i)
        #pragma unroll
        for (int j = 0; j < 4; ++j)
          c[i][j] += a[i]*b[j];
    }
    __syncthreads();
  }
  #pragma unroll
  for (int i = 0; i < 4; ++i){
    int row = m0 + ty*4 + i;
    #pragma unroll
    for (int j = 0; j < 4; ++j){
      int col = n0 + tx*4 + j;
      if (col < N) atomicAdd(&C[(size_t)row*N + col], c[i][j]);
    }
  }
}

// ---------------- MLP2 GEMM, k/v FUSED into one dispatch (round-14, passing) ------------------------
__global__ __launch_bounds__(256) void gemm_mlp2_fused_kernel(const float* __restrict__ hbuf2,
    const float* __restrict__ bk1, const float* __restrict__ bv1,
    const float* __restrict__ Wk2, const float* __restrict__ Wv2,
    float* __restrict__ ckb, float* __restrict__ cvb){
  const int kvsel = blockIdx.z >> 5;
  const int kz = (blockIdx.z & 31) * 128;
  const float* Af    = hbuf2 + (size_t)kvsel*128*CDIM;
  const float* afold = kvsel ? bv1 : bk1;
  const float* B     = kvsel ? Wv2 : Wk2;
  float* C           = kvsel ? cvb : ckb;
  __shared__ __align__(16) float As[16*68];
  __shared__ __align__(16) float Bs[16*68];
  int tid = threadIdx.x;
  int tx = tid & 15, ty = tid >> 4;
  int m0 = blockIdx.y * 64, n0 = blockIdx.x * 64;
  float c[4][4] = {};
  for (int k0 = kz; k0 < kz + 128; k0 += 16){
    #pragma unroll
    for (int i = 0; i < 4; ++i){
      int idx = tid + i*256;
      int kk = idx & 15, m = idx >> 4;
      float av = Af[(size_t)(m0+m)*CDIM + k0 + kk];
      av = fmaxf(av + afold[k0+kk], 0.f);
      As[kk*68 + m] = av;
    }
    #pragma unroll
    for (int i = 0; i < 4; ++i){
      int idx = tid + i*256;
      int nn = idx & 63, kk = idx >> 6;
      Bs[kk*68 + nn] = B[(size_t)(k0+kk)*DH + n0 + nn];
    }
    __syncthreads();
    #pragma unroll
    for (int kk = 0; kk < 16; ++kk){
      float a[4], b[4];
      *(float4*)a = *(const float4*)&As[kk*68 + ty*4];
      *(float4*)b = *(const float4*)&Bs[kk*68 + tx*4];
      #pragma unroll
      for (int i = 0; i < 4; ++i)
        #pragma unroll
        for (int j = 0; j < 4; ++j)
          c[i][j] += a[i]*b[j];
    }
    __syncthreads();
  }
  #pragma unroll
  for (int i = 0; i < 4; ++i){
    int row = m0 + ty*4 + i;
    #pragma unroll
    for (int j = 0; j < 4; ++j){
      int col = n0 + tx*4 + j;
      atomicAdd(&C[(size_t)row*DH + col], c[i][j]);
    }
  }
}

// ---------------- MLP1 GEMM via MFMA: B f32 LDS-staged + in-reg hi/lo, A SLAB-TILED -----------------
// Round-16/17 passing values. grid (64, 4, 16): z>>3 = k/v, z&7 = 16-slab chunk.
__global__ __launch_bounds__(256) void gemm_mfma_mlp1_kernel(const unsigned short* __restrict__ fh,
                                                             const unsigned short* __restrict__ fl,
                                                             const float* __restrict__ Wk1,
                                                             const float* __restrict__ Wv1,
                                                             float* __restrict__ hbuf2){
  const int kvsel = blockIdx.z >> 3;
  const int slab0 = (blockIdx.z & 7) * 16;     // 16 slabs = 512 k
  const int kz = slab0 * 32;
  const unsigned short* Ah = fh + (size_t)kvsel*524288 + (size_t)slab0*4096;
  const unsigned short* Al = fl + (size_t)kvsel*524288 + (size_t)slab0*4096;
  const float* B = kvsel ? Wv1 : Wk1;
  float* C = hbuf2 + (size_t)kvsel*524288;
  const int n0 = blockIdx.x * 64;
  const int m0 = blockIdx.y * 32;
  const int tid = threadIdx.x;
  const int wid = tid >> 6, lane = tid & 63;
  const int l15 = lane & 15, lg = lane >> 4;
  const int colL = wid*16 + l15;
  __shared__ __align__(16) float Bs[2][32][68];   // 17.4 KB

  f32x4 acc[2];
  #pragma unroll
  for (int m = 0; m < 2; ++m) acc[m] = (f32x4){0.f,0.f,0.f,0.f};

  const unsigned short* ahp[2];
  const unsigned short* alp[2];
  #pragma unroll
  for (int m = 0; m < 2; ++m){
    size_t ro = (size_t)(m0 + m*16 + l15)*32 + lg*8;
    ahp[m] = Ah + ro;
    alp[m] = Al + ro;
  }
  const int sr = tid >> 3, sc = (tid & 7) * 8;   // stage: row sr (of 32), 8 cols from sc

  float4 rb0, rb1;
  int4 rah[2], ral[2];
  {
    const float* bp = B + (size_t)(kz + sr)*CDIM + n0 + sc;
    rb0 = *(const float4*)(bp);
    rb1 = *(const float4*)(bp + 4);
    #pragma unroll
    for (int m = 0; m < 2; ++m){
      rah[m] = *(const int4*)(ahp[m]);
      ral[m] = *(const int4*)(alp[m]);
    }
  }

  #pragma unroll 1
  for (int s = 0; s < 16; ++s){
    const int buf = s & 1;                        // runtime index OK: LDS, not registers
    *(float4*)&Bs[buf][sr][sc]     = rb0;
    *(float4*)&Bs[buf][sr][sc + 4] = rb1;
    int4 cah[2], cal[2];
    #pragma unroll
    for (int m = 0; m < 2; ++m){ cah[m] = rah[m]; cal[m] = ral[m]; }
    __syncthreads();
    if (s + 1 < 16){
      const int kr = kz + (s+1)*32;
      const float* bp = B + (size_t)(kr + sr)*CDIM + n0 + sc;
      rb0 = *(const float4*)(bp);
      rb1 = *(const float4*)(bp + 4);
      #pragma unroll
      for (int m = 0; m < 2; ++m){
        rah[m] = *(const int4*)(ahp[m] + (size_t)(s+1)*4096);
        ral[m] = *(const int4*)(alp[m] + (size_t)(s+1)*4096);
      }
    }
    float bv[8];
    #pragma unroll
    for (int j = 0; j < 8; ++j) bv[j] = Bs[buf][lg*8 + j][colL];
    bf16x8 bh, bl;
    #pragma unroll
    for (int j = 0; j < 8; ++j){
      unsigned short h = f2bf(bv[j]);
      bh[j] = (short)h;
      bl[j] = (short)f2bf(bv[j] - bfbits2f(h));
    }
    #pragma unroll
    for (int m = 0; m < 2; ++m){
      union { int4 i; bf16x8 v; } uah, ual;
      uah.i = cah[m]; ual.i = cal[m];
      acc[m] = __builtin_amdgcn_mfma_f32_16x16x32_bf16(uah.v, bh, acc[m], 0, 0, 0);
      acc[m] = __builtin_amdgcn_mfma_f32_16x16x32_bf16(ual.v, bh, acc[m], 0, 0, 0);
      acc[m] = __builtin_amdgcn_mfma_f32_16x16x32_bf16(uah.v, bl, acc[m], 0, 0, 0);
    }
  }
  const int col = n0 + colL;
  #pragma unroll
  for (int m = 0; m < 2; ++m)
    #pragma unroll
    for (int r = 0; r < 4; ++r){
      const int row = m0 + m*16 + lg*4 + r;
      atomicAdd(&C[(size_t)row*CDIM + col], acc[m][r]);
    }
}

// ---------------- q+kv GEMM: LDS-FREE MFMA — ROUND-22: z=1 restored, DEPTH-4 register rings --------
// Round-21 K-split null (occupancy didn't rise); limiter is per-wave pipeline depth. Depth-4 rings:
// each load gets ~3 ring-computes (~18 MFMA) of latency coverage vs depth-2's ~6. Slab order 0..63
// and MFMA term order unchanged -> BIT-IDENTICAL to round-20. Named rings, unroll-constant indices.
#define QKV_MFMA(AH, AL, BH, BL) do{ \
    union { int4 i; bf16x8 v; } ubh_, ubl_; \
    ubh_.i = BH; ubl_.i = BL; \
    _Pragma("unroll") \
    for (int m_ = 0; m_ < 2; ++m_){ \
      union { int4 i; bf16x8 v; } uah_, ual_; \
      uah_.i = AH[m_]; ual_.i = AL[m_]; \
      acc[m_] = __builtin_amdgcn_mfma_f32_16x16x32_bf16(uah_.v, ubh_.v, acc[m_], 0, 0, 0); \
      acc[m_] = __builtin_amdgcn_mfma_f32_16x16x32_bf16(ual_.v, ubh_.v, acc[m_], 0, 0, 0); \
      acc[m_] = __builtin_amdgcn_mfma_f32_16x16x32_bf16(uah_.v, ubl_.v, acc[m_], 0, 0, 0); \
    } \
  }while(0)
#define QKV_FILL(AH, AL, BH, BL, S) do{ \
    _Pragma("unroll") \
    for (int m_ = 0; m_ < 2; ++m_){ \
      AH[m_] = *(const int4*)(aph[m_] + (size_t)(S)*ASTR); \
      AL[m_] = *(const int4*)(apl[m_] + (size_t)(S)*ASTR); \
    } \
    BH = *(const int4*)(bph + (size_t)(S)*BSTR); \
    BL = *(const int4*)(bpl + (size_t)(S)*BSTR); \
  }while(0)

__global__ __launch_bounds__(256) void gemm_mfma_qkvT_kernel(const unsigned short* __restrict__ Ah,
                                                             const unsigned short* __restrict__ Al,
                                                             const unsigned short* __restrict__ BhT,
                                                             const unsigned short* __restrict__ BlT,
                                                             float* __restrict__ Cq,
                                                             float* __restrict__ Ckv){
  const int n0 = blockIdx.x * 64;
  const int m0 = blockIdx.y * 32;
  const int tid = threadIdx.x;
  const int wid = tid >> 6, lane = tid & 63;
  const int l15 = lane & 15, lg = lane >> 4;
  const int col = n0 + wid*16 + l15;
  const size_t ASTR = (size_t)N_TOK*32;     // 32768
  const size_t BSTR = (size_t)2560*32;      // 81920

  f32x4 acc[2];
  #pragma unroll
  for (int m = 0; m < 2; ++m) acc[m] = (f32x4){0.f,0.f,0.f,0.f};

  const unsigned short* aph[2];
  const unsigned short* apl[2];
  #pragma unroll
  for (int m = 0; m < 2; ++m){
    size_t ro = (size_t)(m0 + m*16 + l15)*32 + lg*8;
    aph[m] = Ah + ro;
    apl[m] = Al + ro;
  }
  const unsigned short* bph = BhT + (size_t)col*32 + lg*8;
  const unsigned short* bpl = BlT + (size_t)col*32 + lg*8;

  int4 a0h[2], a0l[2], a1h[2], a1l[2], a2h[2], a2l[2], a3h[2], a3l[2];
  int4 b0h, b0l, b1h, b1l, b2h, b2l, b3h, b3l;
  QKV_FILL(a0h, a0l, b0h, b0l, 0);
  QKV_FILL(a1h, a1l, b1h, b1l, 1);
  QKV_FILL(a2h, a2l, b2h, b2l, 2);
  QKV_FILL(a3h, a3l, b3h, b3l, 3);

  #pragma unroll 1
  for (int s = 0; s < 64; s += 4){
    QKV_MFMA(a0h, a0l, b0h, b0l);
    if (s + 4 < 64) QKV_FILL(a0h, a0l, b0h, b0l, s+4);
    QKV_MFMA(a1h, a1l, b1h, b1l);
    if (s + 5 < 64) QKV_FILL(a1h, a1l, b1h, b1l, s+5);
    QKV_MFMA(a2h, a2l, b2h, b2l);
    if (s + 6 < 64) QKV_FILL(a2h, a2l, b2h, b2l, s+6);
    QKV_MFMA(a3h, a3l, b3h, b3l);
    if (s + 7 < 64) QKV_FILL(a3h, a3l, b3h, b3l, s+7);
  }
  #pragma unroll
  for (int m = 0; m < 2; ++m)
    #pragma unroll
    for (int r = 0; r < 4; ++r){
      const int row = m0 + m*16 + lg*4 + r;
      if (col < 2048) Cq[(size_t)row*DIM + col] = acc[m][r];
      else            Ckv[(size_t)row*512 + (col - 2048)] = acc[m][r];
    }
}

// ---------------- out-GEMM: LDS-FREE MFMA — ROUND-22: z=1 restored, DEPTH-4 rings ------------------
#define OUT_MFMA(AA, BH, BL) do{ \
    union { int4 i; bf16x8 v; } ubh_, ubl_; \
    ubh_.i = BH; ubl_.i = BL; \
    _Pragma("unroll") \
    for (int m_ = 0; m_ < 2; ++m_){ \
      union { int4 i; bf16x8 v; } ua_; ua_.i = AA[m_]; \
      acc[m_] = __builtin_amdgcn_mfma_f32_16x16x32_bf16(ua_.v, ubh_.v, acc[m_], 0, 0, 0); \
      acc[m_] = __builtin_amdgcn_mfma_f32_16x16x32_bf16(ua_.v, ubl_.v, acc[m_], 0, 0, 0); \
    } \
  }while(0)
#define OUT_FILL(AA, BH, BL, S) do{ \
    _Pragma("unroll") \
    for (int m_ = 0; m_ < 2; ++m_) \
      AA[m_] = *(const int4*)(ap[m_] + (size_t)(S)*ASTR); \
    BH = *(const int4*)(bph + (size_t)(S)*BSTR); \
    BL = *(const int4*)(bpl + (size_t)(S)*BSTR); \
  }while(0)

__global__ __launch_bounds__(256) void gemm_mfma_outT_kernel(const unsigned short* __restrict__ AT,
                                                             const unsigned short* __restrict__ BhT,
                                                             const unsigned short* __restrict__ BlT,
                                                             float* __restrict__ C){
  const int n0 = blockIdx.x * 64;
  const int m0 = blockIdx.y * 32;
  const int tid = threadIdx.x;
  const int wid = tid >> 6, lane = tid & 63;
  const int l15 = lane & 15, lg = lane >> 4;
  const int col = n0 + wid*16 + l15;
  const size_t ASTR = (size_t)N_TOK*32;     // 32768
  const size_t BSTR = (size_t)2048*32;      // 65536

  f32x4 acc[2];
  #pragma unroll
  for (int m = 0; m < 2; ++m) acc[m] = (f32x4){0.f,0.f,0.f,0.f};

  const unsigned short* ap[2];
  #pragma unroll
  for (int m = 0; m < 2; ++m)
    ap[m] = AT + (size_t)(m0 + m*16 + l15)*32 + lg*8;
  const unsigned short* bph = BhT + (size_t)col*32 + lg*8;
  const unsigned short* bpl = BlT + (size_t)col*32 + lg*8;

  int4 a0[2], a1[2], a2[2], a3[2];
  int4 b0h, b0l, b1h, b1l, b2h, b2l, b3h, b3l;
  OUT_FILL(a0, b0h, b0l, 0);
  OUT_FILL(a1, b1h, b1l, 1);
  OUT_FILL(a2, b2h, b2l, 2);
  OUT_FILL(a3, b3h, b3l, 3);

  #pragma unroll 1
  for (int s = 0; s < 64; s += 4){
    OUT_MFMA(a0, b0h, b0l);
    if (s + 4 < 64) OUT_FILL(a0, b0h, b0l, s+4);
    OUT_MFMA(a1, b1h, b1l);
    if (s + 5 < 64) OUT_FILL(a1, b1h, b1l, s+5);
    OUT_MFMA(a2, b2h, b2l);
    if (s + 6 < 64) OUT_FILL(a2, b2h, b2l, s+6);
    OUT_MFMA(a3, b3h, b3l);
    if (s + 7 < 64) OUT_FILL(a3, b3h, b3l, s+7);
  }
  #pragma unroll
  for (int m = 0; m < 2; ++m)
    #pragma unroll
    for (int r = 0; r < 4; ++r){
      const int row = m0 + m*16 + lg*4 + r;
      C[(size_t)row*DIM + col] = acc[m][r];
    }
}

// ---------------- RoPE: q fp32 [n][2048], kv fp32 [n][512] -> qr bf16 [n][2048], kr bf16 [n][256] ----
__global__ __launch_bounds__(256) void rope_kernel(const float* __restrict__ q,
    const float* __restrict__ kv, bf16* __restrict__ qr, bf16* __restrict__ kr){
  int n = blockIdx.x, tid = threadIdx.x;
  const float* qrow = q + (size_t)n*DIM;
  bf16* qrrow = qr + (size_t)n*DIM;
  #pragma unroll
  for (int i = 0; i < 4; ++i){
    int p = tid + i*256;
    int hd = p >> 6, ii = p & 63;
    float inv = powf(10000.f, -(float)ii/64.f);
    float ang = (float)n * inv;
    float cs = cosf(ang), sn = sinf(ang);
    float x1 = qrow[hd*DH + 2*ii], x2 = qrow[hd*DH + 2*ii + 1];
    qrrow[hd*DH + 2*ii]     = __float2bfloat16(x1*cs - x2*sn);
    qrrow[hd*DH + 2*ii + 1] = __float2bfloat16(x1*sn + x2*cs);
  }
  if (tid < 128){
    int h = tid >> 6, ii = tid & 63;
    float inv = powf(10000.f, -(float)ii/64.f);
    float ang = (float)n * inv;
    float cs = cosf(ang), sn = sinf(ang);
    const float* kvrow = kv + (size_t)n*512;
    float x1 = kvrow[h*DH + 2*ii], x2 = kvrow[h*DH + 2*ii + 1];
    bf16* krrow = kr + (size_t)n*256;
    krrow[h*DH + 2*ii]     = __float2bfloat16(x1*cs - x2*sn);
    krrow[h*DH + 2*ii + 1] = __float2bfloat16(x1*sn + x2*cs);
  }
}

// ---------------- Build compression-MLP input, k/v fused, SLAB-TILED bf16 hi/lo ---------------------
// fh/fl layout: [kv][128 slabs][128 rows][32] (slab = k/32 within CDIM).
__global__ __launch_bounds__(256) void build_f_kernel(const float* __restrict__ kv,
    const float* __restrict__ k_pos, const float* __restrict__ v_pos,
    unsigned short* __restrict__ fh, unsigned short* __restrict__ fl){
  int bw2 = blockIdx.x;          // 0..255: kvsel*128 + h*NWIN + w
  int kvsel = bw2 >> 7, bw = bw2 & 127;
  int voff = kvsel * 256;
  const float* pos = kvsel ? v_pos : k_pos;
  int h = bw >> 6, w = bw & 63;
  int tid = threadIdx.x;
  for (int idx = tid; idx < CMP_BLK*DH; idx += 256){
    int j = idx >> 7, d = idx & 127;
    int t = w*16 + j - 16;       // padded window index
    float kvv = (t >= 0) ? kv[(size_t)t*512 + voff + h*DH + d] : 0.f;
    float v = kvv + pos[(h*CMP_BLK + j)*DH + d];
    unsigned short hh = f2bf(v);
    int sl = idx >> 5, kk = idx & 31;
    size_t o = (size_t)kvsel*524288 + (size_t)sl*4096 + (size_t)bw*32 + kk;
    fh[o] = hh;
    fl[o] = f2bf(v - bfbits2f(hh));
  }
}

// ---------------- Assemble ck/cv [KVH][NCMP][DH]; MLP second bias folded here ----------------
__global__ __launch_bounds__(256) void assemble_kernel(const float* __restrict__ ckb,
    const float* __restrict__ cvb, const float* __restrict__ mem_kv,
    const float* __restrict__ bk2, const float* __restrict__ bv2,
    float* __restrict__ ck, float* __restrict__ cv){
  int j = blockIdx.x;            // 0..64
  int tid = threadIdx.x;         // 256 = KVH*DH
  int h = tid >> 7, d = tid & 127;
  float kvx, vvx;
  if (j == 0){
    kvx = mem_kv[(0*KVH + h)*DH + d];
    vvx = mem_kv[(1*KVH + h)*DH + d];
  } else {
    kvx = ckb[((size_t)h*NWIN + (j-1))*DH + d] + bk2[d];
    vvx = cvb[((size_t)h*NWIN + (j-1))*DH + d] + bv2[d];
  }
  ck[((size_t)h*NCMP + j)*DH + d] = kvx;
  cv[((size_t)h*NCMP + j)*DH + d] = vvx;
}

// ---------------- Compressed attention (pre-rope q, fp32) + importance + top-4 selection ----------------
__global__ __launch_bounds__(256) void cmp_attn_kernel(const float* __restrict__ q,
    const float* __restrict__ ck, const float* __restrict__ cv,
    bf16* __restrict__ cmp_o, int* __restrict__ sel){
  int bx = blockIdx.x;
  int h = bx >> 10, n = bx & 1023;
  int tid = threadIdx.x;
  __shared__ float cks[NCMP*129];
  __shared__ float qs[GQ*DH];
  __shared__ float sims[GQ*66];
  __shared__ float red[GQ*32];
  __shared__ float impb[NFINE];
  for (int idx = tid; idx < NCMP*DH; idx += 256){
    int j = idx >> 7, d = idx & 127;
    cks[j*129 + d] = ck[((size_t)h*NCMP + j)*DH + d];
  }
  for (int idx = tid; idx < GQ*DH; idx += 256)
    qs[idx] = q[(size_t)n*DIM + h*(GQ*DH) + idx];
  __syncthreads();
  for (int p = tid; p < GQ*NCMP; p += 256){
    int g = p / NCMP, j = p % NCMP;
    float acc = 0.f;
    const float* qp = &qs[g*DH];
    const float* kp = &cks[j*129];
    #pragma unroll 4
    for (int d = 0; d < DH; ++d) acc += qp[d]*kp[d];
    sims[g*66 + j] = acc * SCALE;
  }
  __syncthreads();
  if (tid < NFINE){
    float s = 0.f;
    for (int g = 0; g < GQ; ++g)
      #pragma unroll
      for (int c = 0; c < 4; ++c)
        s += sims[g*66 + 1 + tid*4 + c];
    impb[tid] = s;
  }
  __syncthreads();
  if (tid == 0){
    int own = n >> 6;
    impb[own] = -1e30f;
    int selbuf[5];
    #pragma unroll
    for (int r = 0; r < 4; ++r){
      float best = -1e38f; int bi = 0;
      for (int f = 0; f < NFINE; ++f)
        if (impb[f] > best){ best = impb[f]; bi = f; }   // strict > : lowest index on ties
      selbuf[r] = bi; impb[bi] = -1e38f;
    }
    selbuf[4] = own;
    for (int r = 0; r < 5; ++r) sel[(size_t)(h*N_TOK + n)*8 + r] = selbuf[r];
  }
  int g = tid >> 5, lane = tid & 31;
  float m = -1e38f;
  for (int j = lane; j < NCMP; j += 32) m = fmaxf(m, sims[g*66 + j]);
  red[g*32 + lane] = m; __syncthreads();
  for (int st = 16; st > 0; st >>= 1){ if (lane < st) red[g*32+lane] = fmaxf(red[g*32+lane], red[g*32+lane+st]); __syncthreads(); }
  float gm = red[g*32]; __syncthreads();
  float ps = 0.f;
  for (int j = lane; j < NCMP; j += 32){ float e = expf(sims[g*66+j] - gm); sims[g*66+j] = e; ps += e; }
  red[g*32+lane] = ps; __syncthreads();
  for (int st = 16; st > 0; st >>= 1){ if (lane < st) red[g*32+lane] += red[g*32+lane+st]; __syncthreads(); }
  float inv = 1.f / red[g*32]; __syncthreads();
  for (int j = lane; j < NCMP; j += 32) sims[g*66+j] *= inv;
  __syncthreads();
  for (int p = tid; p < GQ*DH; p += 256){
    int gg = p >> 7, d = p & 127;
    float acc = 0.f;
    const float* cvp = cv + (size_t)h*NCMP*DH + d;
    for (int j = 0; j < NCMP; ++j) acc += sims[gg*66 + j] * cvp[j*DH];
    cmp_o[(size_t)n*DIM + (h*GQ + gg)*DH + d] = __float2bfloat16(acc);
  }
}

// ---------------- Fine attention — round-20 PASSING: T14 prefetch with NAMED SCALAR registers -------
#define FA_LOADK(blk) do{ \
    const bf16* p_ = kr + (size_t)((blk)*SEL_BLK + tK)*256 + h*DH; \
    k0 = *(const int4*)(p_ + dK);      \
    k1 = *(const int4*)(p_ + dK + 32); \
    k2 = *(const int4*)(p_ + dK + 64); \
    k3 = *(const int4*)(p_ + dK + 96); \
  }while(0)
#define FA_STOREK1(reg, db) do{ \
    unsigned w0_=(unsigned)(reg).x, w1_=(unsigned)(reg).y, w2_=(unsigned)(reg).z, w3_=(unsigned)(reg).w; \
    float* d_ = &kvbuf[(size_t)(db)*66 + tK]; \
    d_[0]   = bfbits2f(w0_ & 0xffffu); d_[66]  = bfbits2f(w0_ >> 16); \
    d_[132] = bfbits2f(w1_ & 0xffffu); d_[198] = bfbits2f(w1_ >> 16); \
    d_[264] = bfbits2f(w2_ & 0xffffu); d_[330] = bfbits2f(w2_ >> 16); \
    d_[396] = bfbits2f(w3_ & 0xffffu); d_[462] = bfbits2f(w3_ >> 16); \
  }while(0)
#define FA_STOREK do{ FA_STOREK1(k0,(dK)); FA_STOREK1(k1,(dK+32)); FA_STOREK1(k2,(dK+64)); FA_STOREK1(k3,(dK+96)); }while(0)
#define FA_QK(tile) do{ \
    float acc0_ = 0.f, acc1_ = 0.f; \
    const float* qp_ = &qs[qi*DH]; \
    const float* kp_ = &kvbuf[2*tx]; \
    _Pragma("unroll") \
    for (int d_ = 0; d_ < DH; d_ += 4){ \
      float4 a_ = *(const float4*)(qp_ + d_); \
      float2 b0_ = *(const float2*)(kp_ + (size_t)(d_  )*66); \
      float2 b1_ = *(const float2*)(kp_ + (size_t)(d_+1)*66); \
      float2 b2_ = *(const float2*)(kp_ + (size_t)(d_+2)*66); \
      float2 b3_ = *(const float2*)(kp_ + (size_t)(d_+3)*66); \
      acc0_ += a_.x*b0_.x; acc1_ += a_.x*b0_.y; \
      acc0_ += a_.y*b1_.x; acc1_ += a_.y*b1_.y; \
      acc0_ += a_.z*b2_.x; acc1_ += a_.z*b2_.y; \
      acc0_ += a_.w*b3_.x; acc1_ += a_.w*b3_.y; \
    } \
    *(float2*)&sims[(size_t)qi*322 + (tile)*SEL_BLK + 2*tx] = make_float2(acc0_*SCALE, acc1_*SCALE); \
  }while(0)
#define FA_LOADV(blk) do{ \
    const float* p_ = kv + (size_t)((blk)*SEL_BLK + tV)*512 + 256 + h*DH; \
    v0 = *(const float4*)(p_ + dV);         \
    v1 = *(const float4*)(p_ + 4096 + dV);  \
    v2 = *(const float4*)(p_ + 8192 + dV);  \
    v3 = *(const float4*)(p_ + 12288 + dV); \
    v4 = *(const float4*)(p_ + 16384 + dV); \
    v5 = *(const float4*)(p_ + 20480 + dV); \
    v6 = *(const float4*)(p_ + 24576 + dV); \
    v7 = *(const float4*)(p_ + 28672 + dV); \
  }while(0)
#define FA_STOREV do{ \
    float* d_ = &kvbuf[(size_t)tV*132 + dV]; \
    *(float4*)(d_)        = v0; \
    *(float4*)(d_ + 1056) = v1; \
    *(float4*)(d_ + 2112) = v2; \
    *(float4*)(d_ + 3168) = v3; \
    *(float4*)(d_ + 4224) = v4; \
    *(float4*)(d_ + 5280) = v5; \
    *(float4*)(d_ + 6336) = v6; \
    *(float4*)(d_ + 7392) = v7; \
  }while(0)
#define FA_PV(tile) do{ \
    const float* sp_ = &sims[(size_t)qi*322 + (tile)*SEL_BLK]; \
    const float* vp_ = &kvbuf[tx << 2]; \
    _Pragma("unroll 8") \
    for (int t_ = 0; t_ < SEL_BLK; ++t_){ \
      float p_ = sp_[t_]; \
      float4 vv_ = *(const float4*)(vp_ + (size_t)t_*132); \
      av0 += p_*vv_.x; av1 += p_*vv_.y; av2 += p_*vv_.z; av3 += p_*vv_.w; \
    } \
  }while(0)

__global__ __launch_bounds__(256) void fine_attn_kernel(const bf16* __restrict__ qr,
    const bf16* __restrict__ kr, const float* __restrict__ kv,
    const int* __restrict__ sel, bf16* __restrict__ fine_o){
  int bx = blockIdx.x;
  int h = bx >> 10, n = bx & 1023;
  int tid = threadIdx.x;
  __shared__ __align__(16) float kvbuf[8448];   // kT[128][66] (QK) | V[64][132] (PV)
  __shared__ __align__(16) float qs[GQ*DH];     // natural [qi][d]
  __shared__ float sims[GQ*322];
  __shared__ float red[GQ*32];
  const int qi = tid >> 5, tx = tid & 31;

  int s0_, s1_, s2_, s3_, s4_;
  {
    const int* sp = sel + (size_t)(h*N_TOK + n)*8;
    int b0 = sp[0], b1 = sp[1], b2 = sp[2], b3 = sp[3], b4 = sp[4];
    s0_ = (b0 < 0) ? 0 : (b0 > 15 ? 15 : b0);
    s1_ = (b1 < 0) ? 0 : (b1 > 15 ? 15 : b1);
    s2_ = (b2 < 0) ? 0 : (b2 > 15 ? 15 : b2);
    s3_ = (b3 < 0) ? 0 : (b3 > 15 ? 15 : b3);
    s4_ = (b4 < 0) ? 0 : (b4 > 15 ? 15 : b4);
  }
  for (int idx = tid; idx < GQ*DH; idx += 256)
    qs[idx] = b2f(qr[(size_t)n*DIM + h*(GQ*DH) + idx]);

  // ---- QK phase: per-thread coords. (tid+i*256)&63 == tid&63; d0_i = dK + 32*i.
  const int tK = tid & 63;
  const int dK = (tid >> 6) << 3;
  int4 k0, k1, k2, k3;
  FA_LOADK(s0_);
  __syncthreads(); FA_STOREK; __syncthreads(); FA_LOADK(s1_); FA_QK(0);
  __syncthreads(); FA_STOREK; __syncthreads(); FA_LOADK(s2_); FA_QK(1);
  __syncthreads(); FA_STOREK; __syncthreads(); FA_LOADK(s3_); FA_QK(2);
  __syncthreads(); FA_STOREK; __syncthreads(); FA_LOADK(s4_); FA_QK(3);
  __syncthreads(); FA_STOREK; __syncthreads();                FA_QK(4);

  // ---- prefetch V tile 0 (overlaps softmax). t_i = tV + 8*i; dV constant.
  const int tV = tid >> 5;
  const int dV = (tid & 31) << 2;
  float4 v0, v1, v2, v3, v4, v5, v6, v7;
  FA_LOADV(s0_);
  __syncthreads();

  // ---- softmax over 320 (unchanged mapping/order)
  {
    int g = qi, lane = tx;
    float m = -1e38f;
    for (int t = lane; t < T_TOT; t += 32) m = fmaxf(m, sims[g*322 + t]);
    red[g*32+lane] = m; __syncthreads();
    for (int st = 16; st > 0; st >>= 1){ if (lane < st) red[g*32+lane] = fmaxf(red[g*32+lane], red[g*32+lane+st]); __syncthreads(); }
    float gm = red[g*32]; __syncthreads();
    float ps = 0.f;
    for (int t = lane; t < T_TOT; t += 32){ float e = expf(sims[g*322+t] - gm); sims[g*322+t] = e; ps += e; }
    red[g*32+lane] = ps; __syncthreads();
    for (int st = 16; st > 0; st >>= 1){ if (lane < st) red[g*32+lane] += red[g*32+lane+st]; __syncthreads(); }
    float inv = 1.f / red[g*32]; __syncthreads();
    for (int t = lane; t < T_TOT; t += 32) sims[g*322+t] *= inv;
  }

  // ---- PV phase with prefetch
  float av0 = 0.f, av1 = 0.f, av2 = 0.f, av3 = 0.f;
  __syncthreads(); FA_STOREV; __syncthreads(); FA_LOADV(s1_); FA_PV(0);
  __syncthreads(); FA_STOREV; __syncthreads(); FA_LOADV(s2_); FA_PV(1);
  __syncthreads(); FA_STOREV; __syncthreads(); FA_LOADV(s3_); FA_PV(2);
  __syncthreads(); FA_STOREV; __syncthreads(); FA_LOADV(s4_); FA_PV(3);
  __syncthreads(); FA_STOREV; __syncthreads();                FA_PV(4);
  {
    bf16 o[4];
    o[0] = __float2bfloat16(av0);
    o[1] = __float2bfloat16(av1);
    o[2] = __float2bfloat16(av2);
    o[3] = __float2bfloat16(av3);
    *(ushort4*)(fine_o + (size_t)n*DIM + (h*GQ + qi)*DH + (tx << 2)) = *(const ushort4*)o;
  }
}

// ---------------- Sliding-window attention, flash-style online softmax --------------------------
__global__ __launch_bounds__(256) void slide_attn_kernel(const bf16* __restrict__ qr,
    const bf16* __restrict__ kr, const float* __restrict__ kv,
    bf16* __restrict__ slide_o){
  int hq = blockIdx.y;          // 16 heads
  int qt = blockIdx.x;          // 32 query tiles of 32
  int h = hq >> 3;
  int n0 = qt * 32;
  int tid = threadIdx.x;
  __shared__ float qT[128*36];   // [d][qi], pad 36
  __shared__ float kvb[128*68];  // K^T [d][t] pad 68 (QK) | V [t][128] (PV)
  __shared__ float stT[64*36];   // [t][qi] exp'd probs, pad 36

  const int ty  = tid >> 5;
  const int tx  = tid & 31;
  const int qi0 = ty << 2;

  for (int c = tid; c < 512; c += 256){
    int qi = c & 31, d0 = (c >> 5) << 3;
    int4 w = *(const int4*)(qr + (size_t)(n0+qi)*DIM + hq*DH + d0);
    float* dst = &qT[(size_t)d0*36 + qi];
    unsigned int wv[4] = {(unsigned)w.x,(unsigned)w.y,(unsigned)w.z,(unsigned)w.w};
    #pragma unroll
    for (int m = 0; m < 4; ++m){
      dst[(2*m  )*36] = bfbits2f(wv[m] & 0xffffu);
      dst[(2*m+1)*36] = bfbits2f(wv[m] >> 16);
    }
  }

  float acc[4][4] = {};
  float mrow[4] = {-1e30f,-1e30f,-1e30f,-1e30f};
  float lrow[4] = {0.f,0.f,0.f,0.f};
  float arow[4];
  const int kstart = n0 - 128;

  for (int tile = 0; tile < 5; ++tile){
    const int kbase = kstart + tile*64;
    __syncthreads();
    for (int c = tid; c < 1024; c += 256){
      int t = c & 63, d0 = (c >> 6) << 3;
      int kg = kbase + t;
      int kgc = min(max(kg, 0), N_TOK-1);
      int4 w = *(const int4*)(kr + (size_t)kgc*256 + h*DH + d0);
      float* dst = &kvb[(size_t)d0*68 + t];
      unsigned int wv[4] = {(unsigned)w.x,(unsigned)w.y,(unsigned)w.z,(unsigned)w.w};
      #pragma unroll
      for (int m = 0; m < 4; ++m){
        dst[(2*m  )*68] = bfbits2f(wv[m] & 0xffffu);
        dst[(2*m+1)*68] = bfbits2f(wv[m] >> 16);
      }
    }
    __syncthreads();
    float c0[8] = {};
    {
      const float* aP = qT + qi0;
      const float* bP = kvb + (tx << 1);
      #pragma unroll 4
      for (int d = 0; d < 128; ++d){
        float4 a = *(const float4*)(aP + d*36);
        float2 b = *(const float2*)(bP + d*68);
        c0[0] += a.x*b.x; c0[1] += a.x*b.y;
        c0[2] += a.y*b.x; c0[3] += a.y*b.y;
        c0[4] += a.z*b.x; c0[5] += a.z*b.y;
        c0[6] += a.w*b.x; c0[7] += a.w*b.y;
      }
    }
    const int kg0 = kbase + (tx << 1);
    #pragma unroll
    for (int i = 0; i < 4; ++i){
      int qg = n0 + qi0 + i;
      int d0 = qg - kg0, d1 = d0 - 1;
      bool v0 = (kg0   >= 0) && (kg0   < N_TOK) && (d0 <= 128) && (d0 >= -128);
      bool v1 = (kg0+1 >= 0) && (kg0+1 < N_TOK) && (d1 <= 128) && (d1 >= -128);
      float s0 = v0 ? c0[i*2  ]*SCALE : -1e30f;
      float s1 = v1 ? c0[i*2+1]*SCALE : -1e30f;
      float mi = fmaxf(s0, s1);
      #pragma unroll
      for (int off = 1; off < 32; off <<= 1) mi = fmaxf(mi, __shfl_xor(mi, off));
      float mold = mrow[i];
      float mnew = fmaxf(fmaxf(mold, mi), -1e20f);
      arow[i] = expf(mold - mnew);
      mrow[i] = mnew;
      float e0 = expf(s0 - mnew);
      float e1 = expf(s1 - mnew);
      float ps = e0 + e1;
      #pragma unroll
      for (int off = 1; off < 32; off <<= 1) ps += __shfl_xor(ps, off);
      lrow[i] = lrow[i]*arow[i] + ps;
      stT[(size_t)(2*tx  )*36 + qi0 + i] = e0;
      stT[(size_t)(2*tx+1)*36 + qi0 + i] = e1;
    }
    __syncthreads();
    for (int c = tid; c < 2048; c += 256){
      int t = c >> 5, d0 = (c & 31) << 2;
      int kg = kbase + t;
      int kgc = min(max(kg, 0), N_TOK-1);
      float4 v = *(const float4*)(kv + (size_t)kgc*512 + 256 + h*DH + d0);
      *(float4*)&kvb[(size_t)t*128 + d0] = v;
    }
    __syncthreads();
    #pragma unroll
    for (int i = 0; i < 4; ++i){
      float ar = arow[i];
      acc[i][0] *= ar; acc[i][1] *= ar; acc[i][2] *= ar; acc[i][3] *= ar;
    }
    {
      const float* pP = stT + qi0;
      const float* vP = kvb + (tx << 2);
      #pragma unroll 4
      for (int t = 0; t < 64; ++t){
        float4 p = *(const float4*)(pP + t*36);
        float4 v = *(const float4*)(vP + t*128);
        acc[0][0] += p.x*v.x; acc[0][1] += p.x*v.y; acc[0][2] += p.x*v.z; acc[0][3] += p.x*v.w;
        acc[1][0] += p.y*v.x; acc[1][1] += p.y*v.y; acc[1][2] += p.y*v.z; acc[1][3] += p.y*v.w;
        acc[2][0] += p.z*v.x; acc[2][1] += p.z*v.y; acc[2][2] += p.z*v.z; acc[2][3] += p.z*v.w;
        acc[3][0] += p.w*v.x; acc[3][1] += p.w*v.y; acc[3][2] += p.w*v.z; acc[3][3] += p.w*v.w;
      }
    }
  }
  #pragma unroll
  for (int i = 0; i < 4; ++i){
    int row = n0 + qi0 + i;
    float inv = 1.f / lrow[i];
    bf16 o[4];
    o[0] = __float2bfloat16(acc[i][0]*inv);
    o[1] = __float2bfloat16(acc[i][1]*inv);
    o[2] = __float2bfloat16(acc[i][2]*inv);
    o[3] = __float2bfloat16(acc[i][3]*inv);
    *(ushort4*)(slide_o + (size_t)row*DIM + hq*DH + (tx << 2)) = *(const ushort4*)o;
  }
}

// ---------------- Gated combine -> ocombT bf16 SLAB-TILED [s][row][kk] ------------------------------
__global__ __launch_bounds__(256) void combine_kernel(const bf16* __restrict__ cmp_o,
    const bf16* __restrict__ fine_o, const bf16* __restrict__ slide_o,
    const float* __restrict__ graw, const float* __restrict__ bg,
    unsigned short* __restrict__ ocombT){
  int n = blockIdx.x, tid = threadIdx.x;
  #pragma unroll
  for (int i = 0; i < 8; ++i){
    int c = tid + i*256;
    int hq = c >> 7;
    float g0 = 1.f/(1.f + expf(-(graw[(size_t)n*48 + hq*3 + 0] + bg[hq*3 + 0])));
    float g1 = 1.f/(1.f + expf(-(graw[(size_t)n*48 + hq*3 + 1] + bg[hq*3 + 1])));
    float g2 = 1.f/(1.f + expf(-(graw[(size_t)n*48 + hq*3 + 2] + bg[hq*3 + 2])));
    size_t idx = (size_t)n*DIM + c;
    float v = b2f(cmp_o[idx])*g0 + b2f(fine_o[idx])*g1 + b2f(slide_o[idx])*g2;
    int sl = c >> 5, kk = c & 31;
    ocombT[(size_t)sl*(N_TOK*32) + (size_t)n*32 + kk] = f2bf(v);
  }
}

extern "C" void kernel_launch(void* const* d_in, const int* in_sizes, int n_in,
                              void* d_out, int out_size, void* d_ws, size_t ws_size,
                              hipStream_t stream)
{
  const float* x      = (const float*)d_in[0];
  const float* g_norm = (const float*)d_in[1];
  const float* W_qkv  = (const float*)d_in[2];
  const float* k_pos  = (const float*)d_in[3];
  const float* v_pos  = (const float*)d_in[4];
  const float* mem_kv = (const float*)d_in[5];
  const float* Wk1    = (const float*)d_in[6];
  const float* bk1    = (const float*)d_in[7];
  const float* Wk2    = (const float*)d_in[8];
  const float* bk2    = (const float*)d_in[9];
  const float* Wv1    = (const float*)d_in[10];
  const float* bv1    = (const float*)d_in[11];
  const float* Wv2    = (const float*)d_in[12];
  const float* bv2    = (const float*)d_in[13];
  const float* Wg     = (const float*)d_in[14];
  const float* bg     = (const float*)d_in[15];
  const float* W_out  = (const float*)d_in[16];
  float* out = (float*)d_out;
  (void)ws_size; (void)in_sizes; (void)n_in; (void)out_size;

  // ---- Workspace layout (bytes), peak ~54.5 MB ----
  char* base = (char*)d_ws;
  float* q     = (float*)(base + 0);                 // 8 MB [n][2048] fp32, live -> cmp_attn
  float* xn    = (float*)(base + 8388608);           // 8 MB fp32
  bf16*  qr    = (bf16*) (base + 8388608);           // 4 MB (over xn, after xn dead)
  bf16*  kr    = (bf16*) (base + 12582912);          // 0.5 MB
  unsigned short* ocombT = (unsigned short*)(base + 8388608);  // 4 MB (over qr, after slide) slab-tiled
  float* kv    = (float*)(base + 16777216);          // 2 MB [n][512] fp32 (direct-stored by qkv GEMM)
  float* hbuf2 = (float*)(base + 18874368);          // 4 MB: [2][128][4096] fp32 (k, v halves)
  bf16*  cmp_o = (bf16*) (base + 18874368);          // 4 MB (over hbuf2, after MLP2s)
  float* ckb   = (float*)(base + 23068672);          // 64 KB (raw)
  float* cvb   = (float*)(base + 23134208);          // 64 KB (raw)
  float* ck    = (float*)(base + 23199744);          // 65 KB
  float* cv    = (float*)(base + 23266304);          // 65 KB
  float* gates = (float*)(base + 23332864);          // 192 KB (raw, sigmoid folded in combine)
  int*   sel   = (int*)  (base + 23529472);          // 64 KB
  bf16*  fine_o  = (bf16*)(base + 0);                // 4 MB (over q, after cmp_attn)
  bf16*  slide_o = (bf16*)(base + 4194304);          // 4 MB (over q upper half)
  // Pre-split operands (xnh/xnl and ocombT are SLAB-TILED [s][row][32])
  unsigned short* xnh  = (unsigned short*)(base + 25165824);  // 4 MB bf16 hi(xn)
  unsigned short* xnl  = (unsigned short*)(base + 29360128);  // 4 MB bf16 lo(xn)
  unsigned short* WqhT = (unsigned short*)(base + 33554432);  // 10.49 MB: full W_qkv hi, [s][2560][32]
  unsigned short* WqlT = (unsigned short*)(base + 44040192);  // 10.49 MB: lo     (ends 54,525,952)
  unsigned short* WohT = WqhT;   // W_out split reuses first 8 MB of each region (after qkv GEMM)
  unsigned short* WolT = WqlT;
  unsigned short* fh   = (unsigned short*)(base + 41943040);  // 2 MB, tail of WqhT region (Wq dead)
  unsigned short* fl   = (unsigned short*)(base + 52428800);  // 2 MB, tail of WqlT region

  // Zero split-K accumulation targets (stream-ordered; graph-capture legal)
  hipMemsetAsync(gates, 0, (size_t)N_TOK*48*4,   stream);
  hipMemsetAsync(ckb,   0, (size_t)KVH*NWIN*DH*4, stream);
  hipMemsetAsync(cvb,   0, (size_t)KVH*NWIN*DH*4, stream);
  hipMemsetAsync(hbuf2, 0, (size_t)2*128*CDIM*4,  stream);

  // Full W_qkv (2560 cols) -> slab-tiled hi/lo bf16 split
  transpose_split_kernel<<<dim3(40, 32), 256, 0, stream>>>(W_qkv, 2560, 2560, WqhT, WqlT);
  rmsnorm_kernel<<<N_TOK, 256, 0, stream>>>(x, g_norm, xn, xnh, xnl);
  // gates_raw = xn @ Wg [1024 x 48] — z=16 (round-15, passing)
  gemm_splitk_kernel<<<dim3(1, 16, 16), 256, 0, stream>>>(xn, 0, nullptr, Wg, 48, gates, N_TOK, 48, DIM, 128);
  // q + kv in ONE LDS-free MFMA GEMM — z=1 restored, depth-4 rings (bit-identical to round-20)
  gemm_mfma_qkvT_kernel<<<dim3(40, 32), 256, 0, stream>>>(xnh, xnl, WqhT, WqlT, q, kv);
  // W_out -> slab-tiled hi/lo split (reuses first 8 MB of Wq regions; ordered after qkv GEMM)
  transpose_split_kernel<<<dim3(32, 32), 256, 0, stream>>>(W_out, 2048, 2048, WohT, WolT);
  // qr, kr (bf16) — xn dead after this point
  rope_kernel<<<N_TOK, 256, 0, stream>>>(q, kv, qr, kr);
  // compression MLP1s: staged MFMA (round-17 passing)
  build_f_kernel<<<256, 256, 0, stream>>>(kv, k_pos, v_pos, fh, fl);
  gemm_mfma_mlp1_kernel<<<dim3(64, 4, 16), 256, 0, stream>>>(fh, fl, Wk1, Wv1, hbuf2);
  // MLP2s fused into one dispatch (round-14, passing)
  gemm_mlp2_fused_kernel<<<dim3(2, 2, 64), 256, 0, stream>>>(hbuf2, bk1, bv1, Wk2, Wv2, ckb, cvb);
  assemble_kernel<<<NCMP, 256, 0, stream>>>(ckb, cvb, mem_kv, bk2, bv2, ck, cv);
  // compressed attention + selection (-> cmp_o, over hbuf2 after MLP2s done)
  cmp_attn_kernel<<<KVH*N_TOK, 256, 0, stream>>>(q, ck, cv, cmp_o, sel);
  // fine attention (q dead -> fine_o over q region), round-20 named-scalar prefetch (passing)
  fine_attn_kernel<<<KVH*N_TOK, 256, 0, stream>>>(qr, kr, kv, sel, fine_o);
  // sliding attention (-> slide_o over q upper half)
  slide_attn_kernel<<<dim3(32, 16), 256, 0, stream>>>(qr, kr, kv, slide_o);
  // combine (qr dead -> ocombT over qr, slab-tiled); sigmoid(graw+bg) folded here
  combine_kernel<<<N_TOK, 256, 0, stream>>>(cmp_o, fine_o, slide_o, gates, bg, ocombT);
  // out = ocomb @ W_out — z=1 restored, depth-4 rings (bit-identical to round-20)
  gemm_mfma_outT_kernel<<<dim3(32, 32), 256, 0, stream>>>(ocombT, WohT, WolT, out);
}

// Round 23
// 706.219 us; speedup vs baseline: 1.0688x; 1.0472x over previous
//
#include <hip/hip_runtime.h>
#include <hip/hip_bf16.h>
#include <math.h>

typedef __hip_bfloat16 bf16;
typedef __attribute__((ext_vector_type(8))) short bf16x8;
typedef __attribute__((ext_vector_type(4))) float f32x4;

#define N_TOK 1024
#define DIM 2048
#define NHEADS 16
#define KVH 2
#define DH 128
#define GQ 8
#define NWIN 64
#define CMP_BLK 32
#define NCMP 65        // MEM_KV + NWIN
#define NFINE 16
#define SEL_BLK 64
#define T_TOT 320
#define CDIM 4096      // CMP_BLK*DH
#define SCALE 0.08838834764831845f

static __device__ __forceinline__ float b2f(bf16 v){ return __bfloat162float(v); }
static __device__ __forceinline__ float bfbits2f(unsigned int u){
  union { unsigned int i; float f; } x; x.i = u << 16; return x.f;
}
// RNE float->bf16 bits (matches __float2bfloat16 for normal values)
static __device__ __forceinline__ unsigned short f2bf(float f){
  union { float f; unsigned u; } x; x.f = f;
  unsigned r = x.u + 0x7fffu + ((x.u >> 16) & 1u);
  return (unsigned short)(r >> 16);
}

// ---------------- RMSNorm: x fp32 [N,DIM] -> xn fp32 + xnh/xnl bf16 hi/lo SLAB-TILED ----------------
__global__ __launch_bounds__(256) void rmsnorm_kernel(const float* __restrict__ x,
                                                      const float* __restrict__ g,
                                                      float* __restrict__ xn,
                                                      unsigned short* __restrict__ xnh,
                                                      unsigned short* __restrict__ xnl){
  int n = blockIdx.x, tid = threadIdx.x;
  __shared__ float red[256];
  const float* row = x + (size_t)n*DIM;
  float vals[8];
  float s = 0.f;
  #pragma unroll
  for (int i = 0; i < 8; ++i){ float v = row[tid + i*256]; vals[i] = v; s += v*v; }
  red[tid] = s; __syncthreads();
  for (int st = 128; st > 0; st >>= 1){ if (tid < st) red[tid] += red[tid+st]; __syncthreads(); }
  float scale = 1.0f / sqrtf(red[0]/(float)DIM + 1e-6f);
  #pragma unroll
  for (int i = 0; i < 8; ++i){
    int c = tid + i*256;
    float v = vals[i]*scale*g[c];
    xn[(size_t)n*DIM + c] = v;
    unsigned short h = f2bf(v);
    int sl = c >> 5, kk = c & 31;
    size_t o = (size_t)sl*(N_TOK*32) + (size_t)n*32 + kk;
    xnh[o] = h;
    xnl[o] = f2bf(v - bfbits2f(h));
  }
}

// ---------------- Transpose + hi/lo split into SLAB-TILED layout --------------------------------
__global__ __launch_bounds__(256) void transpose_split_kernel(const float* __restrict__ W, int ldw,
                                                              int ncols,
                                                              unsigned short* __restrict__ Th,
                                                              unsigned short* __restrict__ Tl){
  __shared__ float t[64][65];
  int bx = blockIdx.x;   // n tile
  int by = blockIdx.y;   // k tile
  int tid = threadIdx.x;
  #pragma unroll
  for (int i = 0; i < 16; ++i){
    int idx = tid + i*256;
    int r = idx >> 6, c = idx & 63;            // r=k_local, c=n_local (coalesced read)
    t[r][c] = W[(size_t)(by*64 + r)*ldw + bx*64 + c];
  }
  __syncthreads();
  #pragma unroll
  for (int i = 0; i < 16; ++i){
    int idx = tid + i*256;
    int nl = idx >> 6, kl = idx & 63;          // kl consecutive -> kk contiguous (coalesced)
    float v = t[kl][nl];
    unsigned short h = f2bf(v);
    unsigned short l = f2bf(v - bfbits2f(h));
    int s = by*2 + (kl >> 5), kk = kl & 31;
    size_t o = (size_t)s*((size_t)ncols*32) + (size_t)(bx*64 + nl)*32 + kk;
    Th[o] = h;
    Tl[o] = l;
  }
}

// ---------------- Split-K GEMM (64x64 tile) — kept for gates -----------------------------------
__global__ __launch_bounds__(256) void gemm_splitk_kernel(const void* __restrict__ Av, int a_is_bf16,
                                                          const float* __restrict__ afold,
                                                          const float* __restrict__ B, int ldb,
                                                          float* __restrict__ C,
                                                          int M, int N, int K, int kchunk){
  __shared__ __align__(16) float As[16*68];
  __shared__ __align__(16) float Bs[16*68];
  int tid = threadIdx.x;
  int tx = tid & 15, ty = tid >> 4;
  int m0 = blockIdx.y * 64, n0 = blockIdx.x * 64;
  int kz = blockIdx.z * kchunk;
  const float* Af = (const float*)Av;
  const bf16*  Ab = (const bf16*)Av;
  float c[4][4] = {};
  for (int k0 = kz; k0 < kz + kchunk; k0 += 16){
    #pragma unroll
    for (int i = 0; i < 4; ++i){
      int idx = tid + i*256;
      int kk = idx & 15, m = idx >> 4;
      size_t aidx = (size_t)(m0+m)*K + k0 + kk;
      float av = a_is_bf16 ? b2f(Ab[aidx]) : Af[aidx];
      if (afold) av = fmaxf(av + afold[k0+kk], 0.f);
      As[kk*68 + m] = av;
    }
    #pragma unroll
    for (int i = 0; i < 4; ++i){
      int idx = tid + i*256;
      int nn = idx & 63, kk = idx >> 6;
      int col = n0 + nn;
      Bs[kk*68 + nn] = (col < N) ? B[(size_t)(k0+kk)*ldb + col] : 0.f;
    }
    __syncthreads();
    #pragma unroll
    for (int kk = 0; kk < 16; ++kk){
      float a[4], b[4];
      *(float4*)a = *(const float4*)&As[kk*68 + ty*4];
      *(float4*)b = *(const float4*)&Bs[kk*68 + tx*4];
      #pragma unroll
      for (int i = 0; i < 4; ++i)
        #pragma unroll
        for (int j = 0; j < 4; ++j)
          c[i][j] += a[i]*b[j];
    }
    __syncthreads();
  }
  #pragma unroll
  for (int i = 0; i < 4; ++i){
    int row = m0 + ty*4 + i;
    #pragma unroll
    for (int j = 0; j < 4; ++j){
      int col = n0 + tx*4 + j;
      if (col < N) atomicAdd(&C[(size_t)row*N + col], c[i][j]);
    }
  }
}

// ---------------- MLP2 GEMM, k/v FUSED into one dispatch (round-14, passing) ------------------------
__global__ __launch_bounds__(256) void gemm_mlp2_fused_kernel(const float* __restrict__ hbuf2,
    const float* __restrict__ bk1, const float* __restrict__ bv1,
    const float* __restrict__ Wk2, const float* __restrict__ Wv2,
    float* __restrict__ ckb, float* __restrict__ cvb){
  const int kvsel = blockIdx.z >> 5;
  const int kz = (blockIdx.z & 31) * 128;
  const float* Af    = hbuf2 + (size_t)kvsel*128*CDIM;
  const float* afold = kvsel ? bv1 : bk1;
  const float* B     = kvsel ? Wv2 : Wk2;
  float* C           = kvsel ? cvb : ckb;
  __shared__ __align__(16) float As[16*68];
  __shared__ __align__(16) float Bs[16*68];
  int tid = threadIdx.x;
  int tx = tid & 15, ty = tid >> 4;
  int m0 = blockIdx.y * 64, n0 = blockIdx.x * 64;
  float c[4][4] = {};
  for (int k0 = kz; k0 < kz + 128; k0 += 16){
    #pragma unroll
    for (int i = 0; i < 4; ++i){
      int idx = tid + i*256;
      int kk = idx & 15, m = idx >> 4;
      float av = Af[(size_t)(m0+m)*CDIM + k0 + kk];
      av = fmaxf(av + afold[k0+kk], 0.f);
      As[kk*68 + m] = av;
    }
    #pragma unroll
    for (int i = 0; i < 4; ++i){
      int idx = tid + i*256;
      int nn = idx & 63, kk = idx >> 6;
      Bs[kk*68 + nn] = B[(size_t)(k0+kk)*DH + n0 + nn];
    }
    __syncthreads();
    #pragma unroll
    for (int kk = 0; kk < 16; ++kk){
      float a[4], b[4];
      *(float4*)a = *(const float4*)&As[kk*68 + ty*4];
      *(float4*)b = *(const float4*)&Bs[kk*68 + tx*4];
      #pragma unroll
      for (int i = 0; i < 4; ++i)
        #pragma unroll
        for (int j = 0; j < 4; ++j)
          c[i][j] += a[i]*b[j];
    }
    __syncthreads();
  }
  #pragma unroll
  for (int i = 0; i < 4; ++i){
    int row = m0 + ty*4 + i;
    #pragma unroll
    for (int j = 0; j < 4; ++j){
      int col = n0 + tx*4 + j;
      atomicAdd(&C[(size_t)row*DH + col], c[i][j]);
    }
  }
}

// ---------------- MLP1 GEMM via MFMA: B f32 LDS-staged + in-reg hi/lo, A SLAB-TILED -----------------
// Round-16/17 passing values. grid (64, 4, 16): z>>3 = k/v, z&7 = 16-slab chunk.
__global__ __launch_bounds__(256) void gemm_mfma_mlp1_kernel(const unsigned short* __restrict__ fh,
                                                             const unsigned short* __restrict__ fl,
                                                             const float* __restrict__ Wk1,
                                                             const float* __restrict__ Wv1,
                                                             float* __restrict__ hbuf2){
  const int kvsel = blockIdx.z >> 3;
  const int slab0 = (blockIdx.z & 7) * 16;     // 16 slabs = 512 k
  const int kz = slab0 * 32;
  const unsigned short* Ah = fh + (size_t)kvsel*524288 + (size_t)slab0*4096;
  const unsigned short* Al = fl + (size_t)kvsel*524288 + (size_t)slab0*4096;
  const float* B = kvsel ? Wv1 : Wk1;
  float* C = hbuf2 + (size_t)kvsel*524288;
  const int n0 = blockIdx.x * 64;
  const int m0 = blockIdx.y * 32;
  const int tid = threadIdx.x;
  const int wid = tid >> 6, lane = tid & 63;
  const int l15 = lane & 15, lg = lane >> 4;
  const int colL = wid*16 + l15;
  __shared__ __align__(16) float Bs[2][32][68];   // 17.4 KB

  f32x4 acc[2];
  #pragma unroll
  for (int m = 0; m < 2; ++m) acc[m] = (f32x4){0.f,0.f,0.f,0.f};

  const unsigned short* ahp[2];
  const unsigned short* alp[2];
  #pragma unroll
  for (int m = 0; m < 2; ++m){
    size_t ro = (size_t)(m0 + m*16 + l15)*32 + lg*8;
    ahp[m] = Ah + ro;
    alp[m] = Al + ro;
  }
  const int sr = tid >> 3, sc = (tid & 7) * 8;   // stage: row sr (of 32), 8 cols from sc

  float4 rb0, rb1;
  int4 rah[2], ral[2];
  {
    const float* bp = B + (size_t)(kz + sr)*CDIM + n0 + sc;
    rb0 = *(const float4*)(bp);
    rb1 = *(const float4*)(bp + 4);
    #pragma unroll
    for (int m = 0; m < 2; ++m){
      rah[m] = *(const int4*)(ahp[m]);
      ral[m] = *(const int4*)(alp[m]);
    }
  }

  #pragma unroll 1
  for (int s = 0; s < 16; ++s){
    const int buf = s & 1;                        // runtime index OK: LDS, not registers
    *(float4*)&Bs[buf][sr][sc]     = rb0;
    *(float4*)&Bs[buf][sr][sc + 4] = rb1;
    int4 cah[2], cal[2];
    #pragma unroll
    for (int m = 0; m < 2; ++m){ cah[m] = rah[m]; cal[m] = ral[m]; }
    __syncthreads();
    if (s + 1 < 16){
      const int kr = kz + (s+1)*32;
      const float* bp = B + (size_t)(kr + sr)*CDIM + n0 + sc;
      rb0 = *(const float4*)(bp);
      rb1 = *(const float4*)(bp + 4);
      #pragma unroll
      for (int m = 0; m < 2; ++m){
        rah[m] = *(const int4*)(ahp[m] + (size_t)(s+1)*4096);
        ral[m] = *(const int4*)(alp[m] + (size_t)(s+1)*4096);
      }
    }
    float bv[8];
    #pragma unroll
    for (int j = 0; j < 8; ++j) bv[j] = Bs[buf][lg*8 + j][colL];
    bf16x8 bh, bl;
    #pragma unroll
    for (int j = 0; j < 8; ++j){
      unsigned short h = f2bf(bv[j]);
      bh[j] = (short)h;
      bl[j] = (short)f2bf(bv[j] - bfbits2f(h));
    }
    #pragma unroll
    for (int m = 0; m < 2; ++m){
      union { int4 i; bf16x8 v; } uah, ual;
      uah.i = cah[m]; ual.i = cal[m];
      acc[m] = __builtin_amdgcn_mfma_f32_16x16x32_bf16(uah.v, bh, acc[m], 0, 0, 0);
      acc[m] = __builtin_amdgcn_mfma_f32_16x16x32_bf16(ual.v, bh, acc[m], 0, 0, 0);
      acc[m] = __builtin_amdgcn_mfma_f32_16x16x32_bf16(uah.v, bl, acc[m], 0, 0, 0);
    }
  }
  const int col = n0 + colL;
  #pragma unroll
  for (int m = 0; m < 2; ++m)
    #pragma unroll
    for (int r = 0; r < 4; ++r){
      const int row = m0 + m*16 + lg*4 + r;
      atomicAdd(&C[(size_t)row*CDIM + col], acc[m][r]);
    }
}

// ---------------- q+kv GEMM — ROUND-23: WIDE WAVE TILE 32x32 (2 n-frags), depth-2 rings -------------
// Rounds 21/22 proved occupancy- and ILP-insensitivity -> L2-traffic-bound. Wide tile: per slab a
// wave's 8KB of loads feed 12 MFMA (was 6KB/6) -> 33% less traffic per FLOP. Per-output K order and
// 3-term order unchanged -> BIT-IDENTICAL to round-20. grid (20, 32): block = 32 rows x 128 cols.
#define QKV_MFMA1(ACC, AH, AL, BH, BL) do{ \
    union { int4 i; bf16x8 v; } ubh_, ubl_; \
    ubh_.i = BH; ubl_.i = BL; \
    _Pragma("unroll") \
    for (int m_ = 0; m_ < 2; ++m_){ \
      union { int4 i; bf16x8 v; } uah_, ual_; \
      uah_.i = AH[m_]; ual_.i = AL[m_]; \
      ACC[m_] = __builtin_amdgcn_mfma_f32_16x16x32_bf16(uah_.v, ubh_.v, ACC[m_], 0, 0, 0); \
      ACC[m_] = __builtin_amdgcn_mfma_f32_16x16x32_bf16(ual_.v, ubh_.v, ACC[m_], 0, 0, 0); \
      ACC[m_] = __builtin_amdgcn_mfma_f32_16x16x32_bf16(uah_.v, ubl_.v, ACC[m_], 0, 0, 0); \
    } \
  }while(0)
#define QKV_FILL(AH, AL, BH0, BL0, BH1, BL1, S) do{ \
    _Pragma("unroll") \
    for (int m_ = 0; m_ < 2; ++m_){ \
      AH[m_] = *(const int4*)(aph[m_] + (size_t)(S)*ASTR); \
      AL[m_] = *(const int4*)(apl[m_] + (size_t)(S)*ASTR); \
    } \
    BH0 = *(const int4*)(bph0 + (size_t)(S)*BSTR); \
    BL0 = *(const int4*)(bpl0 + (size_t)(S)*BSTR); \
    BH1 = *(const int4*)(bph1 + (size_t)(S)*BSTR); \
    BL1 = *(const int4*)(bpl1 + (size_t)(S)*BSTR); \
  }while(0)

__global__ __launch_bounds__(256) void gemm_mfma_qkvT_kernel(const unsigned short* __restrict__ Ah,
                                                             const unsigned short* __restrict__ Al,
                                                             const unsigned short* __restrict__ BhT,
                                                             const unsigned short* __restrict__ BlT,
                                                             float* __restrict__ Cq,
                                                             float* __restrict__ Ckv){
  const int n0 = blockIdx.x * 128;
  const int m0 = blockIdx.y * 32;
  const int tid = threadIdx.x;
  const int wid = tid >> 6, lane = tid & 63;
  const int l15 = lane & 15, lg = lane >> 4;
  const int col0 = n0 + wid*32 + l15;
  const int col1 = col0 + 16;
  const size_t ASTR = (size_t)N_TOK*32;     // 32768
  const size_t BSTR = (size_t)2560*32;      // 81920

  f32x4 acc0[2], acc1[2];
  #pragma unroll
  for (int m = 0; m < 2; ++m){ acc0[m] = (f32x4){0.f,0.f,0.f,0.f}; acc1[m] = (f32x4){0.f,0.f,0.f,0.f}; }

  const unsigned short* aph[2];
  const unsigned short* apl[2];
  #pragma unroll
  for (int m = 0; m < 2; ++m){
    size_t ro = (size_t)(m0 + m*16 + l15)*32 + lg*8;
    aph[m] = Ah + ro;
    apl[m] = Al + ro;
  }
  const unsigned short* bph0 = BhT + (size_t)col0*32 + lg*8;
  const unsigned short* bpl0 = BlT + (size_t)col0*32 + lg*8;
  const unsigned short* bph1 = BhT + (size_t)col1*32 + lg*8;
  const unsigned short* bpl1 = BlT + (size_t)col1*32 + lg*8;

  int4 r0ah[2], r0al[2], r1ah[2], r1al[2];
  int4 r0bh0, r0bl0, r0bh1, r0bl1, r1bh0, r1bl0, r1bh1, r1bl1;
  QKV_FILL(r0ah, r0al, r0bh0, r0bl0, r0bh1, r0bl1, 0);
  QKV_FILL(r1ah, r1al, r1bh0, r1bl0, r1bh1, r1bl1, 1);

  #pragma unroll 1
  for (int s = 0; s < 64; s += 2){
    QKV_MFMA1(acc0, r0ah, r0al, r0bh0, r0bl0);
    QKV_MFMA1(acc1, r0ah, r0al, r0bh1, r0bl1);
    if (s + 2 < 64) QKV_FILL(r0ah, r0al, r0bh0, r0bl0, r0bh1, r0bl1, s+2);
    QKV_MFMA1(acc0, r1ah, r1al, r1bh0, r1bl0);
    QKV_MFMA1(acc1, r1ah, r1al, r1bh1, r1bl1);
    if (s + 3 < 64) QKV_FILL(r1ah, r1al, r1bh0, r1bl0, r1bh1, r1bl1, s+3);
  }
  #pragma unroll
  for (int m = 0; m < 2; ++m)
    #pragma unroll
    for (int r = 0; r < 4; ++r){
      const int row = m0 + m*16 + lg*4 + r;
      if (col0 < 2048) Cq[(size_t)row*DIM + col0] = acc0[m][r];
      else             Ckv[(size_t)row*512 + (col0 - 2048)] = acc0[m][r];
      if (col1 < 2048) Cq[(size_t)row*DIM + col1] = acc1[m][r];
      else             Ckv[(size_t)row*512 + (col1 - 2048)] = acc1[m][r];
    }
}

// ---------------- out-GEMM — ROUND-23: WIDE WAVE TILE 32x32, depth-2 rings, 2-term ------------------
#define OUT_MFMA1(ACC, AA, BH, BL) do{ \
    union { int4 i; bf16x8 v; } ubh_, ubl_; \
    ubh_.i = BH; ubl_.i = BL; \
    _Pragma("unroll") \
    for (int m_ = 0; m_ < 2; ++m_){ \
      union { int4 i; bf16x8 v; } ua_; ua_.i = AA[m_]; \
      ACC[m_] = __builtin_amdgcn_mfma_f32_16x16x32_bf16(ua_.v, ubh_.v, ACC[m_], 0, 0, 0); \
      ACC[m_] = __builtin_amdgcn_mfma_f32_16x16x32_bf16(ua_.v, ubl_.v, ACC[m_], 0, 0, 0); \
    } \
  }while(0)
#define OUT_FILL(AA, BH0, BL0, BH1, BL1, S) do{ \
    _Pragma("unroll") \
    for (int m_ = 0; m_ < 2; ++m_) \
      AA[m_] = *(const int4*)(ap[m_] + (size_t)(S)*ASTR); \
    BH0 = *(const int4*)(bph0 + (size_t)(S)*BSTR); \
    BL0 = *(const int4*)(bpl0 + (size_t)(S)*BSTR); \
    BH1 = *(const int4*)(bph1 + (size_t)(S)*BSTR); \
    BL1 = *(const int4*)(bpl1 + (size_t)(S)*BSTR); \
  }while(0)

__global__ __launch_bounds__(256) void gemm_mfma_outT_kernel(const unsigned short* __restrict__ AT,
                                                             const unsigned short* __restrict__ BhT,
                                                             const unsigned short* __restrict__ BlT,
                                                             float* __restrict__ C){
  const int n0 = blockIdx.x * 128;
  const int m0 = blockIdx.y * 32;
  const int tid = threadIdx.x;
  const int wid = tid >> 6, lane = tid & 63;
  const int l15 = lane & 15, lg = lane >> 4;
  const int col0 = n0 + wid*32 + l15;
  const int col1 = col0 + 16;
  const size_t ASTR = (size_t)N_TOK*32;     // 32768
  const size_t BSTR = (size_t)2048*32;      // 65536

  f32x4 acc0[2], acc1[2];
  #pragma unroll
  for (int m = 0; m < 2; ++m){ acc0[m] = (f32x4){0.f,0.f,0.f,0.f}; acc1[m] = (f32x4){0.f,0.f,0.f,0.f}; }

  const unsigned short* ap[2];
  #pragma unroll
  for (int m = 0; m < 2; ++m)
    ap[m] = AT + (size_t)(m0 + m*16 + l15)*32 + lg*8;
  const unsigned short* bph0 = BhT + (size_t)col0*32 + lg*8;
  const unsigned short* bpl0 = BlT + (size_t)col0*32 + lg*8;
  const unsigned short* bph1 = BhT + (size_t)col1*32 + lg*8;
  const unsigned short* bpl1 = BlT + (size_t)col1*32 + lg*8;

  int4 r0a[2], r1a[2];
  int4 r0bh0, r0bl0, r0bh1, r0bl1, r1bh0, r1bl0, r1bh1, r1bl1;
  OUT_FILL(r0a, r0bh0, r0bl0, r0bh1, r0bl1, 0);
  OUT_FILL(r1a, r1bh0, r1bl0, r1bh1, r1bl1, 1);

  #pragma unroll 1
  for (int s = 0; s < 64; s += 2){
    OUT_MFMA1(acc0, r0a, r0bh0, r0bl0);
    OUT_MFMA1(acc1, r0a, r0bh1, r0bl1);
    if (s + 2 < 64) OUT_FILL(r0a, r0bh0, r0bl0, r0bh1, r0bl1, s+2);
    OUT_MFMA1(acc0, r1a, r1bh0, r1bl0);
    OUT_MFMA1(acc1, r1a, r1bh1, r1bl1);
    if (s + 3 < 64) OUT_FILL(r1a, r1bh0, r1bl0, r1bh1, r1bl1, s+3);
  }
  #pragma unroll
  for (int m = 0; m < 2; ++m)
    #pragma unroll
    for (int r = 0; r < 4; ++r){
      const int row = m0 + m*16 + lg*4 + r;
      C[(size_t)row*DIM + col0] = acc0[m][r];
      C[(size_t)row*DIM + col1] = acc1[m][r];
    }
}

// ---------------- RoPE: q fp32 [n][2048], kv fp32 [n][512] -> qr bf16 [n][2048], kr bf16 [n][256] ----
__global__ __launch_bounds__(256) void rope_kernel(const float* __restrict__ q,
    const float* __restrict__ kv, bf16* __restrict__ qr, bf16* __restrict__ kr){
  int n = blockIdx.x, tid = threadIdx.x;
  const float* qrow = q + (size_t)n*DIM;
  bf16* qrrow = qr + (size_t)n*DIM;
  #pragma unroll
  for (int i = 0; i < 4; ++i){
    int p = tid + i*256;
    int hd = p >> 6, ii = p & 63;
    float inv = powf(10000.f, -(float)ii/64.f);
    float ang = (float)n * inv;
    float cs = cosf(ang), sn = sinf(ang);
    float x1 = qrow[hd*DH + 2*ii], x2 = qrow[hd*DH + 2*ii + 1];
    qrrow[hd*DH + 2*ii]     = __float2bfloat16(x1*cs - x2*sn);
    qrrow[hd*DH + 2*ii + 1] = __float2bfloat16(x1*sn + x2*cs);
  }
  if (tid < 128){
    int h = tid >> 6, ii = tid & 63;
    float inv = powf(10000.f, -(float)ii/64.f);
    float ang = (float)n * inv;
    float cs = cosf(ang), sn = sinf(ang);
    const float* kvrow = kv + (size_t)n*512;
    float x1 = kvrow[h*DH + 2*ii], x2 = kvrow[h*DH + 2*ii + 1];
    bf16* krrow = kr + (size_t)n*256;
    krrow[h*DH + 2*ii]     = __float2bfloat16(x1*cs - x2*sn);
    krrow[h*DH + 2*ii + 1] = __float2bfloat16(x1*sn + x2*cs);
  }
}

// ---------------- Build compression-MLP input, k/v fused, SLAB-TILED bf16 hi/lo ---------------------
// fh/fl layout: [kv][128 slabs][128 rows][32] (slab = k/32 within CDIM).
__global__ __launch_bounds__(256) void build_f_kernel(const float* __restrict__ kv,
    const float* __restrict__ k_pos, const float* __restrict__ v_pos,
    unsigned short* __restrict__ fh, unsigned short* __restrict__ fl){
  int bw2 = blockIdx.x;          // 0..255: kvsel*128 + h*NWIN + w
  int kvsel = bw2 >> 7, bw = bw2 & 127;
  int voff = kvsel * 256;
  const float* pos = kvsel ? v_pos : k_pos;
  int h = bw >> 6, w = bw & 63;
  int tid = threadIdx.x;
  for (int idx = tid; idx < CMP_BLK*DH; idx += 256){
    int j = idx >> 7, d = idx & 127;
    int t = w*16 + j - 16;       // padded window index
    float kvv = (t >= 0) ? kv[(size_t)t*512 + voff + h*DH + d] : 0.f;
    float v = kvv + pos[(h*CMP_BLK + j)*DH + d];
    unsigned short hh = f2bf(v);
    int sl = idx >> 5, kk = idx & 31;
    size_t o = (size_t)kvsel*524288 + (size_t)sl*4096 + (size_t)bw*32 + kk;
    fh[o] = hh;
    fl[o] = f2bf(v - bfbits2f(hh));
  }
}

// ---------------- Assemble ck/cv [KVH][NCMP][DH]; MLP second bias folded here ----------------
__global__ __launch_bounds__(256) void assemble_kernel(const float* __restrict__ ckb,
    const float* __restrict__ cvb, const float* __restrict__ mem_kv,
    const float* __restrict__ bk2, const float* __restrict__ bv2,
    float* __restrict__ ck, float* __restrict__ cv){
  int j = blockIdx.x;            // 0..64
  int tid = threadIdx.x;         // 256 = KVH*DH
  int h = tid >> 7, d = tid & 127;
  float kvx, vvx;
  if (j == 0){
    kvx = mem_kv[(0*KVH + h)*DH + d];
    vvx = mem_kv[(1*KVH + h)*DH + d];
  } else {
    kvx = ckb[((size_t)h*NWIN + (j-1))*DH + d] + bk2[d];
    vvx = cvb[((size_t)h*NWIN + (j-1))*DH + d] + bv2[d];
  }
  ck[((size_t)h*NCMP + j)*DH + d] = kvx;
  cv[((size_t)h*NCMP + j)*DH + d] = vvx;
}

// ---------------- Compressed attention (pre-rope q, fp32) + importance + top-4 selection ----------------
__global__ __launch_bounds__(256) void cmp_attn_kernel(const float* __restrict__ q,
    const float* __restrict__ ck, const float* __restrict__ cv,
    bf16* __restrict__ cmp_o, int* __restrict__ sel){
  int bx = blockIdx.x;
  int h = bx >> 10, n = bx & 1023;
  int tid = threadIdx.x;
  __shared__ float cks[NCMP*129];
  __shared__ float qs[GQ*DH];
  __shared__ float sims[GQ*66];
  __shared__ float red[GQ*32];
  __shared__ float impb[NFINE];
  for (int idx = tid; idx < NCMP*DH; idx += 256){
    int j = idx >> 7, d = idx & 127;
    cks[j*129 + d] = ck[((size_t)h*NCMP + j)*DH + d];
  }
  for (int idx = tid; idx < GQ*DH; idx += 256)
    qs[idx] = q[(size_t)n*DIM + h*(GQ*DH) + idx];
  __syncthreads();
  for (int p = tid; p < GQ*NCMP; p += 256){
    int g = p / NCMP, j = p % NCMP;
    float acc = 0.f;
    const float* qp = &qs[g*DH];
    const float* kp = &cks[j*129];
    #pragma unroll 4
    for (int d = 0; d < DH; ++d) acc += qp[d]*kp[d];
    sims[g*66 + j] = acc * SCALE;
  }
  __syncthreads();
  if (tid < NFINE){
    float s = 0.f;
    for (int g = 0; g < GQ; ++g)
      #pragma unroll
      for (int c = 0; c < 4; ++c)
        s += sims[g*66 + 1 + tid*4 + c];
    impb[tid] = s;
  }
  __syncthreads();
  if (tid == 0){
    int own = n >> 6;
    impb[own] = -1e30f;
    int selbuf[5];
    #pragma unroll
    for (int r = 0; r < 4; ++r){
      float best = -1e38f; int bi = 0;
      for (int f = 0; f < NFINE; ++f)
        if (impb[f] > best){ best = impb[f]; bi = f; }   // strict > : lowest index on ties
      selbuf[r] = bi; impb[bi] = -1e38f;
    }
    selbuf[4] = own;
    for (int r = 0; r < 5; ++r) sel[(size_t)(h*N_TOK + n)*8 + r] = selbuf[r];
  }
  int g = tid >> 5, lane = tid & 31;
  float m = -1e38f;
  for (int j = lane; j < NCMP; j += 32) m = fmaxf(m, sims[g*66 + j]);
  red[g*32 + lane] = m; __syncthreads();
  for (int st = 16; st > 0; st >>= 1){ if (lane < st) red[g*32+lane] = fmaxf(red[g*32+lane], red[g*32+lane+st]); __syncthreads(); }
  float gm = red[g*32]; __syncthreads();
  float ps = 0.f;
  for (int j = lane; j < NCMP; j += 32){ float e = expf(sims[g*66+j] - gm); sims[g*66+j] = e; ps += e; }
  red[g*32+lane] = ps; __syncthreads();
  for (int st = 16; st > 0; st >>= 1){ if (lane < st) red[g*32+lane] += red[g*32+lane+st]; __syncthreads(); }
  float inv = 1.f / red[g*32]; __syncthreads();
  for (int j = lane; j < NCMP; j += 32) sims[g*66+j] *= inv;
  __syncthreads();
  for (int p = tid; p < GQ*DH; p += 256){
    int gg = p >> 7, d = p & 127;
    float acc = 0.f;
    const float* cvp = cv + (size_t)h*NCMP*DH + d;
    for (int j = 0; j < NCMP; ++j) acc += sims[gg*66 + j] * cvp[j*DH];
    cmp_o[(size_t)n*DIM + (h*GQ + gg)*DH + d] = __float2bfloat16(acc);
  }
}

// ---------------- Fine attention — round-20 PASSING: T14 prefetch with NAMED SCALAR registers -------
#define FA_LOADK(blk) do{ \
    const bf16* p_ = kr + (size_t)((blk)*SEL_BLK + tK)*256 + h*DH; \
    k0 = *(const int4*)(p_ + dK);      \
    k1 = *(const int4*)(p_ + dK + 32); \
    k2 = *(const int4*)(p_ + dK + 64); \
    k3 = *(const int4*)(p_ + dK + 96); \
  }while(0)
#define FA_STOREK1(reg, db) do{ \
    unsigned w0_=(unsigned)(reg).x, w1_=(unsigned)(reg).y, w2_=(unsigned)(reg).z, w3_=(unsigned)(reg).w; \
    float* d_ = &kvbuf[(size_t)(db)*66 + tK]; \
    d_[0]   = bfbits2f(w0_ & 0xffffu); d_[66]  = bfbits2f(w0_ >> 16); \
    d_[132] = bfbits2f(w1_ & 0xffffu); d_[198] = bfbits2f(w1_ >> 16); \
    d_[264] = bfbits2f(w2_ & 0xffffu); d_[330] = bfbits2f(w2_ >> 16); \
    d_[396] = bfbits2f(w3_ & 0xffffu); d_[462] = bfbits2f(w3_ >> 16); \
  }while(0)
#define FA_STOREK do{ FA_STOREK1(k0,(dK)); FA_STOREK1(k1,(dK+32)); FA_STOREK1(k2,(dK+64)); FA_STOREK1(k3,(dK+96)); }while(0)
#define FA_QK(tile) do{ \
    float acc0_ = 0.f, acc1_ = 0.f; \
    const float* qp_ = &qs[qi*DH]; \
    const float* kp_ = &kvbuf[2*tx]; \
    _Pragma("unroll") \
    for (int d_ = 0; d_ < DH; d_ += 4){ \
      float4 a_ = *(const float4*)(qp_ + d_); \
      float2 b0_ = *(const float2*)(kp_ + (size_t)(d_  )*66); \
      float2 b1_ = *(const float2*)(kp_ + (size_t)(d_+1)*66); \
      float2 b2_ = *(const float2*)(kp_ + (size_t)(d_+2)*66); \
      float2 b3_ = *(const float2*)(kp_ + (size_t)(d_+3)*66); \
      acc0_ += a_.x*b0_.x; acc1_ += a_.x*b0_.y; \
      acc0_ += a_.y*b1_.x; acc1_ += a_.y*b1_.y; \
      acc0_ += a_.z*b2_.x; acc1_ += a_.z*b2_.y; \
      acc0_ += a_.w*b3_.x; acc1_ += a_.w*b3_.y; \
    } \
    *(float2*)&sims[(size_t)qi*322 + (tile)*SEL_BLK + 2*tx] = make_float2(acc0_*SCALE, acc1_*SCALE); \
  }while(0)
#define FA_LOADV(blk) do{ \
    const float* p_ = kv + (size_t)((blk)*SEL_BLK + tV)*512 + 256 + h*DH; \
    v0 = *(const float4*)(p_ + dV);         \
    v1 = *(const float4*)(p_ + 4096 + dV);  \
    v2 = *(const float4*)(p_ + 8192 + dV);  \
    v3 = *(const float4*)(p_ + 12288 + dV); \
    v4 = *(const float4*)(p_ + 16384 + dV); \
    v5 = *(const float4*)(p_ + 20480 + dV); \
    v6 = *(const float4*)(p_ + 24576 + dV); \
    v7 = *(const float4*)(p_ + 28672 + dV); \
  }while(0)
#define FA_STOREV do{ \
    float* d_ = &kvbuf[(size_t)tV*132 + dV]; \
    *(float4*)(d_)        = v0; \
    *(float4*)(d_ + 1056) = v1; \
    *(float4*)(d_ + 2112) = v2; \
    *(float4*)(d_ + 3168) = v3; \
    *(float4*)(d_ + 4224) = v4; \
    *(float4*)(d_ + 5280) = v5; \
    *(float4*)(d_ + 6336) = v6; \
    *(float4*)(d_ + 7392) = v7; \
  }while(0)
#define FA_PV(tile) do{ \
    const float* sp_ = &sims[(size_t)qi*322 + (tile)*SEL_BLK]; \
    const float* vp_ = &kvbuf[tx << 2]; \
    _Pragma("unroll 8") \
    for (int t_ = 0; t_ < SEL_BLK; ++t_){ \
      float p_ = sp_[t_]; \
      float4 vv_ = *(const float4*)(vp_ + (size_t)t_*132); \
      av0 += p_*vv_.x; av1 += p_*vv_.y; av2 += p_*vv_.z; av3 += p_*vv_.w; \
    } \
  }while(0)

__global__ __launch_bounds__(256) void fine_attn_kernel(const bf16* __restrict__ qr,
    const bf16* __restrict__ kr, const float* __restrict__ kv,
    const int* __restrict__ sel, bf16* __restrict__ fine_o){
  int bx = blockIdx.x;
  int h = bx >> 10, n = bx & 1023;
  int tid = threadIdx.x;
  __shared__ __align__(16) float kvbuf[8448];   // kT[128][66] (QK) | V[64][132] (PV)
  __shared__ __align__(16) float qs[GQ*DH];     // natural [qi][d]
  __shared__ float sims[GQ*322];
  __shared__ float red[GQ*32];
  const int qi = tid >> 5, tx = tid & 31;

  int s0_, s1_, s2_, s3_, s4_;
  {
    const int* sp = sel + (size_t)(h*N_TOK + n)*8;
    int b0 = sp[0], b1 = sp[1], b2 = sp[2], b3 = sp[3], b4 = sp[4];
    s0_ = (b0 < 0) ? 0 : (b0 > 15 ? 15 : b0);
    s1_ = (b1 < 0) ? 0 : (b1 > 15 ? 15 : b1);
    s2_ = (b2 < 0) ? 0 : (b2 > 15 ? 15 : b2);
    s3_ = (b3 < 0) ? 0 : (b3 > 15 ? 15 : b3);
    s4_ = (b4 < 0) ? 0 : (b4 > 15 ? 15 : b4);
  }
  for (int idx = tid; idx < GQ*DH; idx += 256)
    qs[idx] = b2f(qr[(size_t)n*DIM + h*(GQ*DH) + idx]);

  // ---- QK phase: per-thread coords. (tid+i*256)&63 == tid&63; d0_i = dK + 32*i.
  const int tK = tid & 63;
  const int dK = (tid >> 6) << 3;
  int4 k0, k1, k2, k3;
  FA_LOADK(s0_);
  __syncthreads(); FA_STOREK; __syncthreads(); FA_LOADK(s1_); FA_QK(0);
  __syncthreads(); FA_STOREK; __syncthreads(); FA_LOADK(s2_); FA_QK(1);
  __syncthreads(); FA_STOREK; __syncthreads(); FA_LOADK(s3_); FA_QK(2);
  __syncthreads(); FA_STOREK; __syncthreads(); FA_LOADK(s4_); FA_QK(3);
  __syncthreads(); FA_STOREK; __syncthreads();                FA_QK(4);

  // ---- prefetch V tile 0 (overlaps softmax). t_i = tV + 8*i; dV constant.
  const int tV = tid >> 5;
  const int dV = (tid & 31) << 2;
  float4 v0, v1, v2, v3, v4, v5, v6, v7;
  FA_LOADV(s0_);
  __syncthreads();

  // ---- softmax over 320 (unchanged mapping/order)
  {
    int g = qi, lane = tx;
    float m = -1e38f;
    for (int t = lane; t < T_TOT; t += 32) m = fmaxf(m, sims[g*322 + t]);
    red[g*32+lane] = m; __syncthreads();
    for (int st = 16; st > 0; st >>= 1){ if (lane < st) red[g*32+lane] = fmaxf(red[g*32+lane], red[g*32+lane+st]); __syncthreads(); }
    float gm = red[g*32]; __syncthreads();
    float ps = 0.f;
    for (int t = lane; t < T_TOT; t += 32){ float e = expf(sims[g*322+t] - gm); sims[g*322+t] = e; ps += e; }
    red[g*32+lane] = ps; __syncthreads();
    for (int st = 16; st > 0; st >>= 1){ if (lane < st) red[g*32+lane] += red[g*32+lane+st]; __syncthreads(); }
    float inv = 1.f / red[g*32]; __syncthreads();
    for (int t = lane; t < T_TOT; t += 32) sims[g*322+t] *= inv;
  }

  // ---- PV phase with prefetch
  float av0 = 0.f, av1 = 0.f, av2 = 0.f, av3 = 0.f;
  __syncthreads(); FA_STOREV; __syncthreads(); FA_LOADV(s1_); FA_PV(0);
  __syncthreads(); FA_STOREV; __syncthreads(); FA_LOADV(s2_); FA_PV(1);
  __syncthreads(); FA_STOREV; __syncthreads(); FA_LOADV(s3_); FA_PV(2);
  __syncthreads(); FA_STOREV; __syncthreads(); FA_LOADV(s4_); FA_PV(3);
  __syncthreads(); FA_STOREV; __syncthreads();                FA_PV(4);
  {
    bf16 o[4];
    o[0] = __float2bfloat16(av0);
    o[1] = __float2bfloat16(av1);
    o[2] = __float2bfloat16(av2);
    o[3] = __float2bfloat16(av3);
    *(ushort4*)(fine_o + (size_t)n*DIM + (h*GQ + qi)*DH + (tx << 2)) = *(const ushort4*)o;
  }
}

// ---------------- Sliding-window attention, flash-style online softmax --------------------------
__global__ __launch_bounds__(256) void slide_attn_kernel(const bf16* __restrict__ qr,
    const bf16* __restrict__ kr, const float* __restrict__ kv,
    bf16* __restrict__ slide_o){
  int hq = blockIdx.y;          // 16 heads
  int qt = blockIdx.x;          // 32 query tiles of 32
  int h = hq >> 3;
  int n0 = qt * 32;
  int tid = threadIdx.x;
  __shared__ float qT[128*36];   // [d][qi], pad 36
  __shared__ float kvb[128*68];  // K^T [d][t] pad 68 (QK) | V [t][128] (PV)
  __shared__ float stT[64*36];   // [t][qi] exp'd probs, pad 36

  const int ty  = tid >> 5;
  const int tx  = tid & 31;
  const int qi0 = ty << 2;

  for (int c = tid; c < 512; c += 256){
    int qi = c & 31, d0 = (c >> 5) << 3;
    int4 w = *(const int4*)(qr + (size_t)(n0+qi)*DIM + hq*DH + d0);
    float* dst = &qT[(size_t)d0*36 + qi];
    unsigned int wv[4] = {(unsigned)w.x,(unsigned)w.y,(unsigned)w.z,(unsigned)w.w};
    #pragma unroll
    for (int m = 0; m < 4; ++m){
      dst[(2*m  )*36] = bfbits2f(wv[m] & 0xffffu);
      dst[(2*m+1)*36] = bfbits2f(wv[m] >> 16);
    }
  }

  float acc[4][4] = {};
  float mrow[4] = {-1e30f,-1e30f,-1e30f,-1e30f};
  float lrow[4] = {0.f,0.f,0.f,0.f};
  float arow[4];
  const int kstart = n0 - 128;

  for (int tile = 0; tile < 5; ++tile){
    const int kbase = kstart + tile*64;
    __syncthreads();
    for (int c = tid; c < 1024; c += 256){
      int t = c & 63, d0 = (c >> 6) << 3;
      int kg = kbase + t;
      int kgc = min(max(kg, 0), N_TOK-1);
      int4 w = *(const int4*)(kr + (size_t)kgc*256 + h*DH + d0);
      float* dst = &kvb[(size_t)d0*68 + t];
      unsigned int wv[4] = {(unsigned)w.x,(unsigned)w.y,(unsigned)w.z,(unsigned)w.w};
      #pragma unroll
      for (int m = 0; m < 4; ++m){
        dst[(2*m  )*68] = bfbits2f(wv[m] & 0xffffu);
        dst[(2*m+1)*68] = bfbits2f(wv[m] >> 16);
      }
    }
    __syncthreads();
    float c0[8] = {};
    {
      const float* aP = qT + qi0;
      const float* bP = kvb + (tx << 1);
      #pragma unroll 4
      for (int d = 0; d < 128; ++d){
        float4 a = *(const float4*)(aP + d*36);
        float2 b = *(const float2*)(bP + d*68);
        c0[0] += a.x*b.x; c0[1] += a.x*b.y;
        c0[2] += a.y*b.x; c0[3] += a.y*b.y;
        c0[4] += a.z*b.x; c0[5] += a.z*b.y;
        c0[6] += a.w*b.x; c0[7] += a.w*b.y;
      }
    }
    const int kg0 = kbase + (tx << 1);
    #pragma unroll
    for (int i = 0; i < 4; ++i){
      int qg = n0 + qi0 + i;
      int d0 = qg - kg0, d1 = d0 - 1;
      bool v0 = (kg0   >= 0) && (kg0   < N_TOK) && (d0 <= 128) && (d0 >= -128);
      bool v1 = (kg0+1 >= 0) && (kg0+1 < N_TOK) && (d1 <= 128) && (d1 >= -128);
      float s0 = v0 ? c0[i*2  ]*SCALE : -1e30f;
      float s1 = v1 ? c0[i*2+1]*SCALE : -1e30f;
      float mi = fmaxf(s0, s1);
      #pragma unroll
      for (int off = 1; off < 32; off <<= 1) mi = fmaxf(mi, __shfl_xor(mi, off));
      float mold = mrow[i];
      float mnew = fmaxf(fmaxf(mold, mi), -1e20f);
      arow[i] = expf(mold - mnew);
      mrow[i] = mnew;
      float e0 = expf(s0 - mnew);
      float e1 = expf(s1 - mnew);
      float ps = e0 + e1;
      #pragma unroll
      for (int off = 1; off < 32; off <<= 1) ps += __shfl_xor(ps, off);
      lrow[i] = lrow[i]*arow[i] + ps;
      stT[(size_t)(2*tx  )*36 + qi0 + i] = e0;
      stT[(size_t)(2*tx+1)*36 + qi0 + i] = e1;
    }
    __syncthreads();
    for (int c = tid; c < 2048; c += 256){
      int t = c >> 5, d0 = (c & 31) << 2;
      int kg = kbase + t;
      int kgc = min(max(kg, 0), N_TOK-1);
      float4 v = *(const float4*)(kv + (size_t)kgc*512 + 256 + h*DH + d0);
      *(float4*)&kvb[(size_t)t*128 + d0] = v;
    }
    __syncthreads();
    #pragma unroll
    for (int i = 0; i < 4; ++i){
      float ar = arow[i];
      acc[i][0] *= ar; acc[i][1] *= ar; acc[i][2] *= ar; acc[i][3] *= ar;
    }
    {
      const float* pP = stT + qi0;
      const float* vP = kvb + (tx << 2);
      #pragma unroll 4
      for (int t = 0; t < 64; ++t){
        float4 p = *(const float4*)(pP + t*36);
        float4 v = *(const float4*)(vP + t*128);
        acc[0][0] += p.x*v.x; acc[0][1] += p.x*v.y; acc[0][2] += p.x*v.z; acc[0][3] += p.x*v.w;
        acc[1][0] += p.y*v.x; acc[1][1] += p.y*v.y; acc[1][2] += p.y*v.z; acc[1][3] += p.y*v.w;
        acc[2][0] += p.z*v.x; acc[2][1] += p.z*v.y; acc[2][2] += p.z*v.z; acc[2][3] += p.z*v.w;
        acc[3][0] += p.w*v.x; acc[3][1] += p.w*v.y; acc[3][2] += p.w*v.z; acc[3][3] += p.w*v.w;
      }
    }
  }
  #pragma unroll
  for (int i = 0; i < 4; ++i){
    int row = n0 + qi0 + i;
    float inv = 1.f / lrow[i];
    bf16 o[4];
    o[0] = __float2bfloat16(acc[i][0]*inv);
    o[1] = __float2bfloat16(acc[i][1]*inv);
    o[2] = __float2bfloat16(acc[i][2]*inv);
    o[3] = __float2bfloat16(acc[i][3]*inv);
    *(ushort4*)(slide_o + (size_t)row*DIM + hq*DH + (tx << 2)) = *(const ushort4*)o;
  }
}

// ---------------- Gated combine -> ocombT bf16 SLAB-TILED [s][row][kk] ------------------------------
__global__ __launch_bounds__(256) void combine_kernel(const bf16* __restrict__ cmp_o,
    const bf16* __restrict__ fine_o, const bf16* __restrict__ slide_o,
    const float* __restrict__ graw, const float* __restrict__ bg,
    unsigned short* __restrict__ ocombT){
  int n = blockIdx.x, tid = threadIdx.x;
  #pragma unroll
  for (int i = 0; i < 8; ++i){
    int c = tid + i*256;
    int hq = c >> 7;
    float g0 = 1.f/(1.f + expf(-(graw[(size_t)n*48 + hq*3 + 0] + bg[hq*3 + 0])));
    float g1 = 1.f/(1.f + expf(-(graw[(size_t)n*48 + hq*3 + 1] + bg[hq*3 + 1])));
    float g2 = 1.f/(1.f + expf(-(graw[(size_t)n*48 + hq*3 + 2] + bg[hq*3 + 2])));
    size_t idx = (size_t)n*DIM + c;
    float v = b2f(cmp_o[idx])*g0 + b2f(fine_o[idx])*g1 + b2f(slide_o[idx])*g2;
    int sl = c >> 5, kk = c & 31;
    ocombT[(size_t)sl*(N_TOK*32) + (size_t)n*32 + kk] = f2bf(v);
  }
}

extern "C" void kernel_launch(void* const* d_in, const int* in_sizes, int n_in,
                              void* d_out, int out_size, void* d_ws, size_t ws_size,
                              hipStream_t stream)
{
  const float* x      = (const float*)d_in[0];
  const float* g_norm = (const float*)d_in[1];
  const float* W_qkv  = (const float*)d_in[2];
  const float* k_pos  = (const float*)d_in[3];
  const float* v_pos  = (const float*)d_in[4];
  const float* mem_kv = (const float*)d_in[5];
  const float* Wk1    = (const float*)d_in[6];
  const float* bk1    = (const float*)d_in[7];
  const float* Wk2    = (const float*)d_in[8];
  const float* bk2    = (const float*)d_in[9];
  const float* Wv1    = (const float*)d_in[10];
  const float* bv1    = (const float*)d_in[11];
  const float* Wv2    = (const float*)d_in[12];
  const float* bv2    = (const float*)d_in[13];
  const float* Wg     = (const float*)d_in[14];
  const float* bg     = (const float*)d_in[15];
  const float* W_out  = (const float*)d_in[16];
  float* out = (float*)d_out;
  (void)ws_size; (void)in_sizes; (void)n_in; (void)out_size;

  // ---- Workspace layout (bytes), peak ~54.5 MB ----
  char* base = (char*)d_ws;
  float* q     = (float*)(base + 0);                 // 8 MB [n][2048] fp32, live -> cmp_attn
  float* xn    = (float*)(base + 8388608);           // 8 MB fp32
  bf16*  qr    = (bf16*) (base + 8388608);           // 4 MB (over xn, after xn dead)
  bf16*  kr    = (bf16*) (base + 12582912);          // 0.5 MB
  unsigned short* ocombT = (unsigned short*)(base + 8388608);  // 4 MB (over qr, after slide) slab-tiled
  float* kv    = (float*)(base + 16777216);          // 2 MB [n][512] fp32 (direct-stored by qkv GEMM)
  float* hbuf2 = (float*)(base + 18874368);          // 4 MB: [2][128][4096] fp32 (k, v halves)
  bf16*  cmp_o = (bf16*) (base + 18874368);          // 4 MB (over hbuf2, after MLP2s)
  float* ckb   = (float*)(base + 23068672);          // 64 KB (raw)
  float* cvb   = (float*)(base + 23134208);          // 64 KB (raw)
  float* ck    = (float*)(base + 23199744);          // 65 KB
  float* cv    = (float*)(base + 23266304);          // 65 KB
  float* gates = (float*)(base + 23332864);          // 192 KB (raw, sigmoid folded in combine)
  int*   sel   = (int*)  (base + 23529472);          // 64 KB
  bf16*  fine_o  = (bf16*)(base + 0);                // 4 MB (over q, after cmp_attn)
  bf16*  slide_o = (bf16*)(base + 4194304);          // 4 MB (over q upper half)
  // Pre-split operands (xnh/xnl and ocombT are SLAB-TILED [s][row][32])
  unsigned short* xnh  = (unsigned short*)(base + 25165824);  // 4 MB bf16 hi(xn)
  unsigned short* xnl  = (unsigned short*)(base + 29360128);  // 4 MB bf16 lo(xn)
  unsigned short* WqhT = (unsigned short*)(base + 33554432);  // 10.49 MB: full W_qkv hi, [s][2560][32]
  unsigned short* WqlT = (unsigned short*)(base + 44040192);  // 10.49 MB: lo     (ends 54,525,952)
  unsigned short* WohT = WqhT;   // W_out split reuses first 8 MB of each region (after qkv GEMM)
  unsigned short* WolT = WqlT;
  unsigned short* fh   = (unsigned short*)(base + 41943040);  // 2 MB, tail of WqhT region (Wq dead)
  unsigned short* fl   = (unsigned short*)(base + 52428800);  // 2 MB, tail of WqlT region

  // Zero split-K accumulation targets (stream-ordered; graph-capture legal)
  hipMemsetAsync(gates, 0, (size_t)N_TOK*48*4,   stream);
  hipMemsetAsync(ckb,   0, (size_t)KVH*NWIN*DH*4, stream);
  hipMemsetAsync(cvb,   0, (size_t)KVH*NWIN*DH*4, stream);
  hipMemsetAsync(hbuf2, 0, (size_t)2*128*CDIM*4,  stream);

  // Full W_qkv (2560 cols) -> slab-tiled hi/lo bf16 split
  transpose_split_kernel<<<dim3(40, 32), 256, 0, stream>>>(W_qkv, 2560, 2560, WqhT, WqlT);
  rmsnorm_kernel<<<N_TOK, 256, 0, stream>>>(x, g_norm, xn, xnh, xnl);
  // gates_raw = xn @ Wg [1024 x 48] — z=16 (round-15, passing)
  gemm_splitk_kernel<<<dim3(1, 16, 16), 256, 0, stream>>>(xn, 0, nullptr, Wg, 48, gates, N_TOK, 48, DIM, 128);
  // q + kv in ONE LDS-free MFMA GEMM — wide 32x32 wave tile (bit-identical values to round-20)
  gemm_mfma_qkvT_kernel<<<dim3(20, 32), 256, 0, stream>>>(xnh, xnl, WqhT, WqlT, q, kv);
  // W_out -> slab-tiled hi/lo split (reuses first 8 MB of Wq regions; ordered after qkv GEMM)
  transpose_split_kernel<<<dim3(32, 32), 256, 0, stream>>>(W_out, 2048, 2048, WohT, WolT);
  // qr, kr (bf16) — xn dead after this point
  rope_kernel<<<N_TOK, 256, 0, stream>>>(q, kv, qr, kr);
  // compression MLP1s: staged MFMA (round-17 passing)
  build_f_kernel<<<256, 256, 0, stream>>>(kv, k_pos, v_pos, fh, fl);
  gemm_mfma_mlp1_kernel<<<dim3(64, 4, 16), 256, 0, stream>>>(fh, fl, Wk1, Wv1, hbuf2);
  // MLP2s fused into one dispatch (round-14, passing)
  gemm_mlp2_fused_kernel<<<dim3(2, 2, 64), 256, 0, stream>>>(hbuf2, bk1, bv1, Wk2, Wv2, ckb, cvb);
  assemble_kernel<<<NCMP, 256, 0, stream>>>(ckb, cvb, mem_kv, bk2, bv2, ck, cv);
  // compressed attention + selection (-> cmp_o, over hbuf2 after MLP2s done)
  cmp_attn_kernel<<<KVH*N_TOK, 256, 0, stream>>>(q, ck, cv, cmp_o, sel);
  // fine attention (q dead -> fine_o over q region), round-20 named-scalar prefetch (passing)
  fine_attn_kernel<<<KVH*N_TOK, 256, 0, stream>>>(qr, kr, kv, sel, fine_o);
  // sliding attention (-> slide_o over q upper half)
  slide_attn_kernel<<<dim3(32, 16), 256, 0, stream>>>(qr, kr, kv, slide_o);
  // combine (qr dead -> ocombT over qr, slab-tiled); sigmoid(graw+bg) folded here
  combine_kernel<<<N_TOK, 256, 0, stream>>>(cmp_o, fine_o, slide_o, gates, bg, ocombT);
  // out = ocomb @ W_out — wide 32x32 wave tile (bit-identical values to round-20)
  gemm_mfma_outT_kernel<<<dim3(16, 32), 256, 0, stream>>>(ocombT, WohT, WolT, out);
}

// Round 24
// 697.206 us; speedup vs baseline: 1.0826x; 1.0129x over previous
//
#include <hip/hip_runtime.h>
#include <hip/hip_bf16.h>
#include <math.h>

typedef __hip_bfloat16 bf16;
typedef __attribute__((ext_vector_type(8))) short bf16x8;
typedef __attribute__((ext_vector_type(4))) float f32x4;

#define N_TOK 1024
#define DIM 2048
#define NHEADS 16
#define KVH 2
#define DH 128
#define GQ 8
#define NWIN 64
#define CMP_BLK 32
#define NCMP 65        // MEM_KV + NWIN
#define NFINE 16
#define SEL_BLK 64
#define T_TOT 320
#define CDIM 4096      // CMP_BLK*DH
#define SCALE 0.08838834764831845f

static __device__ __forceinline__ float b2f(bf16 v){ return __bfloat162float(v); }
static __device__ __forceinline__ float bfbits2f(unsigned int u){
  union { unsigned int i; float f; } x; x.i = u << 16; return x.f;
}
// RNE float->bf16 bits (matches __float2bfloat16 for normal values)
static __device__ __forceinline__ unsigned short f2bf(float f){
  union { float f; unsigned u; } x; x.f = f;
  unsigned r = x.u + 0x7fffu + ((x.u >> 16) & 1u);
  return (unsigned short)(r >> 16);
}

// ---------------- RMSNorm: x fp32 [N,DIM] -> xn fp32 + xnh/xnl bf16 hi/lo SLAB-TILED ----------------
__global__ __launch_bounds__(256) void rmsnorm_kernel(const float* __restrict__ x,
                                                      const float* __restrict__ g,
                                                      float* __restrict__ xn,
                                                      unsigned short* __restrict__ xnh,
                                                      unsigned short* __restrict__ xnl){
  int n = blockIdx.x, tid = threadIdx.x;
  __shared__ float red[256];
  const float* row = x + (size_t)n*DIM;
  float vals[8];
  float s = 0.f;
  #pragma unroll
  for (int i = 0; i < 8; ++i){ float v = row[tid + i*256]; vals[i] = v; s += v*v; }
  red[tid] = s; __syncthreads();
  for (int st = 128; st > 0; st >>= 1){ if (tid < st) red[tid] += red[tid+st]; __syncthreads(); }
  float scale = 1.0f / sqrtf(red[0]/(float)DIM + 1e-6f);
  #pragma unroll
  for (int i = 0; i < 8; ++i){
    int c = tid + i*256;
    float v = vals[i]*scale*g[c];
    xn[(size_t)n*DIM + c] = v;
    unsigned short h = f2bf(v);
    int sl = c >> 5, kk = c & 31;
    size_t o = (size_t)sl*(N_TOK*32) + (size_t)n*32 + kk;
    xnh[o] = h;
    xnl[o] = f2bf(v - bfbits2f(h));
  }
}

// ---------------- Transpose + hi/lo split into SLAB-TILED layout --------------------------------
__global__ __launch_bounds__(256) void transpose_split_kernel(const float* __restrict__ W, int ldw,
                                                              int ncols,
                                                              unsigned short* __restrict__ Th,
                                                              unsigned short* __restrict__ Tl){
  __shared__ float t[64][65];
  int bx = blockIdx.x;   // n tile
  int by = blockIdx.y;   // k tile
  int tid = threadIdx.x;
  #pragma unroll
  for (int i = 0; i < 16; ++i){
    int idx = tid + i*256;
    int r = idx >> 6, c = idx & 63;            // r=k_local, c=n_local (coalesced read)
    t[r][c] = W[(size_t)(by*64 + r)*ldw + bx*64 + c];
  }
  __syncthreads();
  #pragma unroll
  for (int i = 0; i < 16; ++i){
    int idx = tid + i*256;
    int nl = idx >> 6, kl = idx & 63;          // kl consecutive -> kk contiguous (coalesced)
    float v = t[kl][nl];
    unsigned short h = f2bf(v);
    unsigned short l = f2bf(v - bfbits2f(h));
    int s = by*2 + (kl >> 5), kk = kl & 31;
    size_t o = (size_t)s*((size_t)ncols*32) + (size_t)(bx*64 + nl)*32 + kk;
    Th[o] = h;
    Tl[o] = l;
  }
}

// ---------------- Split-K GEMM (64x64 tile) — kept for gates -----------------------------------
__global__ __launch_bounds__(256) void gemm_splitk_kernel(const void* __restrict__ Av, int a_is_bf16,
                                                          const float* __restrict__ afold,
                                                          const float* __restrict__ B, int ldb,
                                                          float* __restrict__ C,
                                                          int M, int N, int K, int kchunk){
  __shared__ __align__(16) float As[16*68];
  __shared__ __align__(16) float Bs[16*68];
  int tid = threadIdx.x;
  int tx = tid & 15, ty = tid >> 4;
  int m0 = blockIdx.y * 64, n0 = blockIdx.x * 64;
  int kz = blockIdx.z * kchunk;
  const float* Af = (const float*)Av;
  const bf16*  Ab = (const bf16*)Av;
  float c[4][4] = {};
  for (int k0 = kz; k0 < kz + kchunk; k0 += 16){
    #pragma unroll
    for (int i = 0; i < 4; ++i){
      int idx = tid + i*256;
      int kk = idx & 15, m = idx >> 4;
      size_t aidx = (size_t)(m0+m)*K + k0 + kk;
      float av = a_is_bf16 ? b2f(Ab[aidx]) : Af[aidx];
      if (afold) av = fmaxf(av + afold[k0+kk], 0.f);
      As[kk*68 + m] = av;
    }
    #pragma unroll
    for (int i = 0; i < 4; ++i){
      int idx = tid + i*256;
      int nn = idx & 63, kk = idx >> 6;
      int col = n0 + nn;
      Bs[kk*68 + nn] = (col < N) ? B[(size_t)(k0+kk)*ldb + col] : 0.f;
    }
    __syncthreads();
    #pragma unroll
    for (int kk = 0; kk < 16; ++kk){
      float a[4], b[4];
      *(float4*)a = *(const float4*)&As[kk*68 + ty*4];
      *(float4*)b = *(const float4*)&Bs[kk*68 + tx*4];
      #pragma unroll
      for (int i = 0; i < 4; ++i)
        #pragma unroll
        for (int j = 0; j < 4; ++j)
          c[i][j] += a[i]*b[j];
    }
    __syncthreads();
  }
  #pragma unroll
  for (int i = 0; i < 4; ++i){
    int row = m0 + ty*4 + i;
    #pragma unroll
    for (int j = 0; j < 4; ++j){
      int col = n0 + tx*4 + j;
      if (col < N) atomicAdd(&C[(size_t)row*N + col], c[i][j]);
    }
  }
}

// ---------------- MLP2 GEMM, k/v FUSED into one dispatch (round-14, passing) ------------------------
__global__ __launch_bounds__(256) void gemm_mlp2_fused_kernel(const float* __restrict__ hbuf2,
    const float* __restrict__ bk1, const float* __restrict__ bv1,
    const float* __restrict__ Wk2, const float* __restrict__ Wv2,
    float* __restrict__ ckb, float* __restrict__ cvb){
  const int kvsel = blockIdx.z >> 5;
  const int kz = (blockIdx.z & 31) * 128;
  const float* Af    = hbuf2 + (size_t)kvsel*128*CDIM;
  const float* afold = kvsel ? bv1 : bk1;
  const float* B     = kvsel ? Wv2 : Wk2;
  float* C           = kvsel ? cvb : ckb;
  __shared__ __align__(16) float As[16*68];
  __shared__ __align__(16) float Bs[16*68];
  int tid = threadIdx.x;
  int tx = tid & 15, ty = tid >> 4;
  int m0 = blockIdx.y * 64, n0 = blockIdx.x * 64;
  float c[4][4] = {};
  for (int k0 = kz; k0 < kz + 128; k0 += 16){
    #pragma unroll
    for (int i = 0; i < 4; ++i){
      int idx = tid + i*256;
      int kk = idx & 15, m = idx >> 4;
      float av = Af[(size_t)(m0+m)*CDIM + k0 + kk];
      av = fmaxf(av + afold[k0+kk], 0.f);
      As[kk*68 + m] = av;
    }
    #pragma unroll
    for (int i = 0; i < 4; ++i){
      int idx = tid + i*256;
      int nn = idx & 63, kk = idx >> 6;
      Bs[kk*68 + nn] = B[(size_t)(k0+kk)*DH + n0 + nn];
    }
    __syncthreads();
    #pragma unroll
    for (int kk = 0; kk < 16; ++kk){
      float a[4], b[4];
      *(float4*)a = *(const float4*)&As[kk*68 + ty*4];
      *(float4*)b = *(const float4*)&Bs[kk*68 + tx*4];
      #pragma unroll
      for (int i = 0; i < 4; ++i)
        #pragma unroll
        for (int j = 0; j < 4; ++j)
          c[i][j] += a[i]*b[j];
    }
    __syncthreads();
  }
  #pragma unroll
  for (int i = 0; i < 4; ++i){
    int row = m0 + ty*4 + i;
    #pragma unroll
    for (int j = 0; j < 4; ++j){
      int col = n0 + tx*4 + j;
      atomicAdd(&C[(size_t)row*DH + col], c[i][j]);
    }
  }
}

// ---------------- MLP1 GEMM via MFMA — ROUND-24: 4 m-frags + z=16 (rounds 14+15 combined) -----------
// Round-14 proved 4 m-frags halves per-B-element conversion VALU (22->13%) but lost occupancy at
// grid 1024; round-15 proved z=16 TLP but reverted to 2 m-frags. Combination: grid (64, 2, 16) =
// 2048 WGs = 8 blk/CU (LDS 17.4KB allows 9) AND conversions feed 12 MFMA each. Same 8x512 k-chunk
// grouping and 3-term order as round-23 -> bit-identical.
__global__ __launch_bounds__(256) void gemm_mfma_mlp1_kernel(const unsigned short* __restrict__ fh,
                                                             const unsigned short* __restrict__ fl,
                                                             const float* __restrict__ Wk1,
                                                             const float* __restrict__ Wv1,
                                                             float* __restrict__ hbuf2){
  const int kvsel = blockIdx.z >> 3;
  const int slab0 = (blockIdx.z & 7) * 16;     // 16 slabs = 512 k
  const int kz = slab0 * 32;
  const unsigned short* Ah = fh + (size_t)kvsel*524288 + (size_t)slab0*4096;
  const unsigned short* Al = fl + (size_t)kvsel*524288 + (size_t)slab0*4096;
  const float* B = kvsel ? Wv1 : Wk1;
  float* C = hbuf2 + (size_t)kvsel*524288;
  const int n0 = blockIdx.x * 64;
  const int m0 = blockIdx.y * 64;              // 4 m-frags = 64 rows/block
  const int tid = threadIdx.x;
  const int wid = tid >> 6, lane = tid & 63;
  const int l15 = lane & 15, lg = lane >> 4;
  const int colL = wid*16 + l15;
  __shared__ __align__(16) float Bs[2][32][68];   // 17.4 KB

  f32x4 acc[4];
  #pragma unroll
  for (int m = 0; m < 4; ++m) acc[m] = (f32x4){0.f,0.f,0.f,0.f};

  const unsigned short* ahp[4];
  const unsigned short* alp[4];
  #pragma unroll
  for (int m = 0; m < 4; ++m){
    size_t ro = (size_t)(m0 + m*16 + l15)*32 + lg*8;
    ahp[m] = Ah + ro;
    alp[m] = Al + ro;
  }
  const int sr = tid >> 3, sc = (tid & 7) * 8;   // stage: row sr (of 32), 8 cols from sc

  float4 rb0, rb1;
  int4 rah[4], ral[4];
  {
    const float* bp = B + (size_t)(kz + sr)*CDIM + n0 + sc;
    rb0 = *(const float4*)(bp);
    rb1 = *(const float4*)(bp + 4);
    #pragma unroll
    for (int m = 0; m < 4; ++m){
      rah[m] = *(const int4*)(ahp[m]);
      ral[m] = *(const int4*)(alp[m]);
    }
  }

  #pragma unroll 1
  for (int s = 0; s < 16; ++s){
    const int buf = s & 1;                        // runtime index OK: LDS, not registers
    *(float4*)&Bs[buf][sr][sc]     = rb0;
    *(float4*)&Bs[buf][sr][sc + 4] = rb1;
    int4 cah[4], cal[4];
    #pragma unroll
    for (int m = 0; m < 4; ++m){ cah[m] = rah[m]; cal[m] = ral[m]; }
    __syncthreads();
    if (s + 1 < 16){
      const int kr = kz + (s+1)*32;
      const float* bp = B + (size_t)(kr + sr)*CDIM + n0 + sc;
      rb0 = *(const float4*)(bp);
      rb1 = *(const float4*)(bp + 4);
      #pragma unroll
      for (int m = 0; m < 4; ++m){
        rah[m] = *(const int4*)(ahp[m] + (size_t)(s+1)*4096);
        ral[m] = *(const int4*)(alp[m] + (size_t)(s+1)*4096);
      }
    }
    float bv[8];
    #pragma unroll
    for (int j = 0; j < 8; ++j) bv[j] = Bs[buf][lg*8 + j][colL];
    bf16x8 bh, bl;
    #pragma unroll
    for (int j = 0; j < 8; ++j){
      unsigned short h = f2bf(bv[j]);
      bh[j] = (short)h;
      bl[j] = (short)f2bf(bv[j] - bfbits2f(h));
    }
    #pragma unroll
    for (int m = 0; m < 4; ++m){
      union { int4 i; bf16x8 v; } uah, ual;
      uah.i = cah[m]; ual.i = cal[m];
      acc[m] = __builtin_amdgcn_mfma_f32_16x16x32_bf16(uah.v, bh, acc[m], 0, 0, 0);
      acc[m] = __builtin_amdgcn_mfma_f32_16x16x32_bf16(ual.v, bh, acc[m], 0, 0, 0);
      acc[m] = __builtin_amdgcn_mfma_f32_16x16x32_bf16(uah.v, bl, acc[m], 0, 0, 0);
    }
  }
  const int col = n0 + colL;
  #pragma unroll
  for (int m = 0; m < 4; ++m)
    #pragma unroll
    for (int r = 0; r < 4; ++r){
      const int row = m0 + m*16 + lg*4 + r;
      atomicAdd(&C[(size_t)row*CDIM + col], acc[m][r]);
    }
}

// ---------------- q+kv GEMM — round-23 PASSING: WIDE WAVE TILE 32x32, depth-2 rings -----------------
#define QKV_MFMA1(ACC, AH, AL, BH, BL) do{ \
    union { int4 i; bf16x8 v; } ubh_, ubl_; \
    ubh_.i = BH; ubl_.i = BL; \
    _Pragma("unroll") \
    for (int m_ = 0; m_ < 2; ++m_){ \
      union { int4 i; bf16x8 v; } uah_, ual_; \
      uah_.i = AH[m_]; ual_.i = AL[m_]; \
      ACC[m_] = __builtin_amdgcn_mfma_f32_16x16x32_bf16(uah_.v, ubh_.v, ACC[m_], 0, 0, 0); \
      ACC[m_] = __builtin_amdgcn_mfma_f32_16x16x32_bf16(ual_.v, ubh_.v, ACC[m_], 0, 0, 0); \
      ACC[m_] = __builtin_amdgcn_mfma_f32_16x16x32_bf16(uah_.v, ubl_.v, ACC[m_], 0, 0, 0); \
    } \
  }while(0)
#define QKV_FILL(AH, AL, BH0, BL0, BH1, BL1, S) do{ \
    _Pragma("unroll") \
    for (int m_ = 0; m_ < 2; ++m_){ \
      AH[m_] = *(const int4*)(aph[m_] + (size_t)(S)*ASTR); \
      AL[m_] = *(const int4*)(apl[m_] + (size_t)(S)*ASTR); \
    } \
    BH0 = *(const int4*)(bph0 + (size_t)(S)*BSTR); \
    BL0 = *(const int4*)(bpl0 + (size_t)(S)*BSTR); \
    BH1 = *(const int4*)(bph1 + (size_t)(S)*BSTR); \
    BL1 = *(const int4*)(bpl1 + (size_t)(S)*BSTR); \
  }while(0)

__global__ __launch_bounds__(256) void gemm_mfma_qkvT_kernel(const unsigned short* __restrict__ Ah,
                                                             const unsigned short* __restrict__ Al,
                                                             const unsigned short* __restrict__ BhT,
                                                             const unsigned short* __restrict__ BlT,
                                                             float* __restrict__ Cq,
                                                             float* __restrict__ Ckv){
  const int n0 = blockIdx.x * 128;
  const int m0 = blockIdx.y * 32;
  const int tid = threadIdx.x;
  const int wid = tid >> 6, lane = tid & 63;
  const int l15 = lane & 15, lg = lane >> 4;
  const int col0 = n0 + wid*32 + l15;
  const int col1 = col0 + 16;
  const size_t ASTR = (size_t)N_TOK*32;     // 32768
  const size_t BSTR = (size_t)2560*32;      // 81920

  f32x4 acc0[2], acc1[2];
  #pragma unroll
  for (int m = 0; m < 2; ++m){ acc0[m] = (f32x4){0.f,0.f,0.f,0.f}; acc1[m] = (f32x4){0.f,0.f,0.f,0.f}; }

  const unsigned short* aph[2];
  const unsigned short* apl[2];
  #pragma unroll
  for (int m = 0; m < 2; ++m){
    size_t ro = (size_t)(m0 + m*16 + l15)*32 + lg*8;
    aph[m] = Ah + ro;
    apl[m] = Al + ro;
  }
  const unsigned short* bph0 = BhT + (size_t)col0*32 + lg*8;
  const unsigned short* bpl0 = BlT + (size_t)col0*32 + lg*8;
  const unsigned short* bph1 = BhT + (size_t)col1*32 + lg*8;
  const unsigned short* bpl1 = BlT + (size_t)col1*32 + lg*8;

  int4 r0ah[2], r0al[2], r1ah[2], r1al[2];
  int4 r0bh0, r0bl0, r0bh1, r0bl1, r1bh0, r1bl0, r1bh1, r1bl1;
  QKV_FILL(r0ah, r0al, r0bh0, r0bl0, r0bh1, r0bl1, 0);
  QKV_FILL(r1ah, r1al, r1bh0, r1bl0, r1bh1, r1bl1, 1);

  #pragma unroll 1
  for (int s = 0; s < 64; s += 2){
    QKV_MFMA1(acc0, r0ah, r0al, r0bh0, r0bl0);
    QKV_MFMA1(acc1, r0ah, r0al, r0bh1, r0bl1);
    if (s + 2 < 64) QKV_FILL(r0ah, r0al, r0bh0, r0bl0, r0bh1, r0bl1, s+2);
    QKV_MFMA1(acc0, r1ah, r1al, r1bh0, r1bl0);
    QKV_MFMA1(acc1, r1ah, r1al, r1bh1, r1bl1);
    if (s + 3 < 64) QKV_FILL(r1ah, r1al, r1bh0, r1bl0, r1bh1, r1bl1, s+3);
  }
  #pragma unroll
  for (int m = 0; m < 2; ++m)
    #pragma unroll
    for (int r = 0; r < 4; ++r){
      const int row = m0 + m*16 + lg*4 + r;
      if (col0 < 2048) Cq[(size_t)row*DIM + col0] = acc0[m][r];
      else             Ckv[(size_t)row*512 + (col0 - 2048)] = acc0[m][r];
      if (col1 < 2048) Cq[(size_t)row*DIM + col1] = acc1[m][r];
      else             Ckv[(size_t)row*512 + (col1 - 2048)] = acc1[m][r];
    }
}

// ---------------- out-GEMM — round-23 PASSING: WIDE WAVE TILE 32x32, depth-2 rings, 2-term ----------
#define OUT_MFMA1(ACC, AA, BH, BL) do{ \
    union { int4 i; bf16x8 v; } ubh_, ubl_; \
    ubh_.i = BH; ubl_.i = BL; \
    _Pragma("unroll") \
    for (int m_ = 0; m_ < 2; ++m_){ \
      union { int4 i; bf16x8 v; } ua_; ua_.i = AA[m_]; \
      ACC[m_] = __builtin_amdgcn_mfma_f32_16x16x32_bf16(ua_.v, ubh_.v, ACC[m_], 0, 0, 0); \
      ACC[m_] = __builtin_amdgcn_mfma_f32_16x16x32_bf16(ua_.v, ubl_.v, ACC[m_], 0, 0, 0); \
    } \
  }while(0)
#define OUT_FILL(AA, BH0, BL0, BH1, BL1, S) do{ \
    _Pragma("unroll") \
    for (int m_ = 0; m_ < 2; ++m_) \
      AA[m_] = *(const int4*)(ap[m_] + (size_t)(S)*ASTR); \
    BH0 = *(const int4*)(bph0 + (size_t)(S)*BSTR); \
    BL0 = *(const int4*)(bpl0 + (size_t)(S)*BSTR); \
    BH1 = *(const int4*)(bph1 + (size_t)(S)*BSTR); \
    BL1 = *(const int4*)(bpl1 + (size_t)(S)*BSTR); \
  }while(0)

__global__ __launch_bounds__(256) void gemm_mfma_outT_kernel(const unsigned short* __restrict__ AT,
                                                             const unsigned short* __restrict__ BhT,
                                                             const unsigned short* __restrict__ BlT,
                                                             float* __restrict__ C){
  const int n0 = blockIdx.x * 128;
  const int m0 = blockIdx.y * 32;
  const int tid = threadIdx.x;
  const int wid = tid >> 6, lane = tid & 63;
  const int l15 = lane & 15, lg = lane >> 4;
  const int col0 = n0 + wid*32 + l15;
  const int col1 = col0 + 16;
  const size_t ASTR = (size_t)N_TOK*32;     // 32768
  const size_t BSTR = (size_t)2048*32;      // 65536

  f32x4 acc0[2], acc1[2];
  #pragma unroll
  for (int m = 0; m < 2; ++m){ acc0[m] = (f32x4){0.f,0.f,0.f,0.f}; acc1[m] = (f32x4){0.f,0.f,0.f,0.f}; }

  const unsigned short* ap[2];
  #pragma unroll
  for (int m = 0; m < 2; ++m)
    ap[m] = AT + (size_t)(m0 + m*16 + l15)*32 + lg*8;
  const unsigned short* bph0 = BhT + (size_t)col0*32 + lg*8;
  const unsigned short* bpl0 = BlT + (size_t)col0*32 + lg*8;
  const unsigned short* bph1 = BhT + (size_t)col1*32 + lg*8;
  const unsigned short* bpl1 = BlT + (size_t)col1*32 + lg*8;

  int4 r0a[2], r1a[2];
  int4 r0bh0, r0bl0, r0bh1, r0bl1, r1bh0, r1bl0, r1bh1, r1bl1;
  OUT_FILL(r0a, r0bh0, r0bl0, r0bh1, r0bl1, 0);
  OUT_FILL(r1a, r1bh0, r1bl0, r1bh1, r1bl1, 1);

  #pragma unroll 1
  for (int s = 0; s < 64; s += 2){
    OUT_MFMA1(acc0, r0a, r0bh0, r0bl0);
    OUT_MFMA1(acc1, r0a, r0bh1, r0bl1);
    if (s + 2 < 64) OUT_FILL(r0a, r0bh0, r0bl0, r0bh1, r0bl1, s+2);
    OUT_MFMA1(acc0, r1a, r1bh0, r1bl0);
    OUT_MFMA1(acc1, r1a, r1bh1, r1bl1);
    if (s + 3 < 64) OUT_FILL(r1a, r1bh0, r1bl0, r1bh1, r1bl1, s+3);
  }
  #pragma unroll
  for (int m = 0; m < 2; ++m)
    #pragma unroll
    for (int r = 0; r < 4; ++r){
      const int row = m0 + m*16 + lg*4 + r;
      C[(size_t)row*DIM + col0] = acc0[m][r];
      C[(size_t)row*DIM + col1] = acc1[m][r];
    }
}

// ---------------- RoPE: q fp32 [n][2048], kv fp32 [n][512] -> qr bf16 [n][2048], kr bf16 [n][256] ----
__global__ __launch_bounds__(256) void rope_kernel(const float* __restrict__ q,
    const float* __restrict__ kv, bf16* __restrict__ qr, bf16* __restrict__ kr){
  int n = blockIdx.x, tid = threadIdx.x;
  const float* qrow = q + (size_t)n*DIM;
  bf16* qrrow = qr + (size_t)n*DIM;
  #pragma unroll
  for (int i = 0; i < 4; ++i){
    int p = tid + i*256;
    int hd = p >> 6, ii = p & 63;
    float inv = powf(10000.f, -(float)ii/64.f);
    float ang = (float)n * inv;
    float cs = cosf(ang), sn = sinf(ang);
    float x1 = qrow[hd*DH + 2*ii], x2 = qrow[hd*DH + 2*ii + 1];
    qrrow[hd*DH + 2*ii]     = __float2bfloat16(x1*cs - x2*sn);
    qrrow[hd*DH + 2*ii + 1] = __float2bfloat16(x1*sn + x2*cs);
  }
  if (tid < 128){
    int h = tid >> 6, ii = tid & 63;
    float inv = powf(10000.f, -(float)ii/64.f);
    float ang = (float)n * inv;
    float cs = cosf(ang), sn = sinf(ang);
    const float* kvrow = kv + (size_t)n*512;
    float x1 = kvrow[h*DH + 2*ii], x2 = kvrow[h*DH + 2*ii + 1];
    bf16* krrow = kr + (size_t)n*256;
    krrow[h*DH + 2*ii]     = __float2bfloat16(x1*cs - x2*sn);
    krrow[h*DH + 2*ii + 1] = __float2bfloat16(x1*sn + x2*cs);
  }
}

// ---------------- Build compression-MLP input, k/v fused, SLAB-TILED bf16 hi/lo ---------------------
// fh/fl layout: [kv][128 slabs][128 rows][32] (slab = k/32 within CDIM).
__global__ __launch_bounds__(256) void build_f_kernel(const float* __restrict__ kv,
    const float* __restrict__ k_pos, const float* __restrict__ v_pos,
    unsigned short* __restrict__ fh, unsigned short* __restrict__ fl){
  int bw2 = blockIdx.x;          // 0..255: kvsel*128 + h*NWIN + w
  int kvsel = bw2 >> 7, bw = bw2 & 127;
  int voff = kvsel * 256;
  const float* pos = kvsel ? v_pos : k_pos;
  int h = bw >> 6, w = bw & 63;
  int tid = threadIdx.x;
  for (int idx = tid; idx < CMP_BLK*DH; idx += 256){
    int j = idx >> 7, d = idx & 127;
    int t = w*16 + j - 16;       // padded window index
    float kvv = (t >= 0) ? kv[(size_t)t*512 + voff + h*DH + d] : 0.f;
    float v = kvv + pos[(h*CMP_BLK + j)*DH + d];
    unsigned short hh = f2bf(v);
    int sl = idx >> 5, kk = idx & 31;
    size_t o = (size_t)kvsel*524288 + (size_t)sl*4096 + (size_t)bw*32 + kk;
    fh[o] = hh;
    fl[o] = f2bf(v - bfbits2f(hh));
  }
}

// ---------------- Assemble ck/cv [KVH][NCMP][DH]; MLP second bias folded here ----------------
__global__ __launch_bounds__(256) void assemble_kernel(const float* __restrict__ ckb,
    const float* __restrict__ cvb, const float* __restrict__ mem_kv,
    const float* __restrict__ bk2, const float* __restrict__ bv2,
    float* __restrict__ ck, float* __restrict__ cv){
  int j = blockIdx.x;            // 0..64
  int tid = threadIdx.x;         // 256 = KVH*DH
  int h = tid >> 7, d = tid & 127;
  float kvx, vvx;
  if (j == 0){
    kvx = mem_kv[(0*KVH + h)*DH + d];
    vvx = mem_kv[(1*KVH + h)*DH + d];
  } else {
    kvx = ckb[((size_t)h*NWIN + (j-1))*DH + d] + bk2[d];
    vvx = cvb[((size_t)h*NWIN + (j-1))*DH + d] + bv2[d];
  }
  ck[((size_t)h*NCMP + j)*DH + d] = kvx;
  cv[((size_t)h*NCMP + j)*DH + d] = vvx;
}

// ---------------- Compressed attention (pre-rope q, fp32) + importance + top-4 selection ----------------
__global__ __launch_bounds__(256) void cmp_attn_kernel(const float* __restrict__ q,
    const float* __restrict__ ck, const float* __restrict__ cv,
    bf16* __restrict__ cmp_o, int* __restrict__ sel){
  int bx = blockIdx.x;
  int h = bx >> 10, n = bx & 1023;
  int tid = threadIdx.x;
  __shared__ float cks[NCMP*129];
  __shared__ float qs[GQ*DH];
  __shared__ float sims[GQ*66];
  __shared__ float red[GQ*32];
  __shared__ float impb[NFINE];
  for (int idx = tid; idx < NCMP*DH; idx += 256){
    int j = idx >> 7, d = idx & 127;
    cks[j*129 + d] = ck[((size_t)h*NCMP + j)*DH + d];
  }
  for (int idx = tid; idx < GQ*DH; idx += 256)
    qs[idx] = q[(size_t)n*DIM + h*(GQ*DH) + idx];
  __syncthreads();
  for (int p = tid; p < GQ*NCMP; p += 256){
    int g = p / NCMP, j = p % NCMP;
    float acc = 0.f;
    const float* qp = &qs[g*DH];
    const float* kp = &cks[j*129];
    #pragma unroll 4
    for (int d = 0; d < DH; ++d) acc += qp[d]*kp[d];
    sims[g*66 + j] = acc * SCALE;
  }
  __syncthreads();
  if (tid < NFINE){
    float s = 0.f;
    for (int g = 0; g < GQ; ++g)
      #pragma unroll
      for (int c = 0; c < 4; ++c)
        s += sims[g*66 + 1 + tid*4 + c];
    impb[tid] = s;
  }
  __syncthreads();
  if (tid == 0){
    int own = n >> 6;
    impb[own] = -1e30f;
    int selbuf[5];
    #pragma unroll
    for (int r = 0; r < 4; ++r){
      float best = -1e38f; int bi = 0;
      for (int f = 0; f < NFINE; ++f)
        if (impb[f] > best){ best = impb[f]; bi = f; }   // strict > : lowest index on ties
      selbuf[r] = bi; impb[bi] = -1e38f;
    }
    selbuf[4] = own;
    for (int r = 0; r < 5; ++r) sel[(size_t)(h*N_TOK + n)*8 + r] = selbuf[r];
  }
  int g = tid >> 5, lane = tid & 31;
  float m = -1e38f;
  for (int j = lane; j < NCMP; j += 32) m = fmaxf(m, sims[g*66 + j]);
  red[g*32 + lane] = m; __syncthreads();
  for (int st = 16; st > 0; st >>= 1){ if (lane < st) red[g*32+lane] = fmaxf(red[g*32+lane], red[g*32+lane+st]); __syncthreads(); }
  float gm = red[g*32]; __syncthreads();
  float ps = 0.f;
  for (int j = lane; j < NCMP; j += 32){ float e = expf(sims[g*66+j] - gm); sims[g*66+j] = e; ps += e; }
  red[g*32+lane] = ps; __syncthreads();
  for (int st = 16; st > 0; st >>= 1){ if (lane < st) red[g*32+lane] += red[g*32+lane+st]; __syncthreads(); }
  float inv = 1.f / red[g*32]; __syncthreads();
  for (int j = lane; j < NCMP; j += 32) sims[g*66+j] *= inv;
  __syncthreads();
  for (int p = tid; p < GQ*DH; p += 256){
    int gg = p >> 7, d = p & 127;
    float acc = 0.f;
    const float* cvp = cv + (size_t)h*NCMP*DH + d;
    for (int j = 0; j < NCMP; ++j) acc += sims[gg*66 + j] * cvp[j*DH];
    cmp_o[(size_t)n*DIM + (h*GQ + gg)*DH + d] = __float2bfloat16(acc);
  }
}

// ---------------- Fine attention — round-20 PASSING: T14 prefetch with NAMED SCALAR registers -------
#define FA_LOADK(blk) do{ \
    const bf16* p_ = kr + (size_t)((blk)*SEL_BLK + tK)*256 + h*DH; \
    k0 = *(const int4*)(p_ + dK);      \
    k1 = *(const int4*)(p_ + dK + 32); \
    k2 = *(const int4*)(p_ + dK + 64); \
    k3 = *(const int4*)(p_ + dK + 96); \
  }while(0)
#define FA_STOREK1(reg, db) do{ \
    unsigned w0_=(unsigned)(reg).x, w1_=(unsigned)(reg).y, w2_=(unsigned)(reg).z, w3_=(unsigned)(reg).w; \
    float* d_ = &kvbuf[(size_t)(db)*66 + tK]; \
    d_[0]   = bfbits2f(w0_ & 0xffffu); d_[66]  = bfbits2f(w0_ >> 16); \
    d_[132] = bfbits2f(w1_ & 0xffffu); d_[198] = bfbits2f(w1_ >> 16); \
    d_[264] = bfbits2f(w2_ & 0xffffu); d_[330] = bfbits2f(w2_ >> 16); \
    d_[396] = bfbits2f(w3_ & 0xffffu); d_[462] = bfbits2f(w3_ >> 16); \
  }while(0)
#define FA_STOREK do{ FA_STOREK1(k0,(dK)); FA_STOREK1(k1,(dK+32)); FA_STOREK1(k2,(dK+64)); FA_STOREK1(k3,(dK+96)); }while(0)
#define FA_QK(tile) do{ \
    float acc0_ = 0.f, acc1_ = 0.f; \
    const float* qp_ = &qs[qi*DH]; \
    const float* kp_ = &kvbuf[2*tx]; \
    _Pragma("unroll") \
    for (int d_ = 0; d_ < DH; d_ += 4){ \
      float4 a_ = *(const float4*)(qp_ + d_); \
      float2 b0_ = *(const float2*)(kp_ + (size_t)(d_  )*66); \
      float2 b1_ = *(const float2*)(kp_ + (size_t)(d_+1)*66); \
      float2 b2_ = *(const float2*)(kp_ + (size_t)(d_+2)*66); \
      float2 b3_ = *(const float2*)(kp_ + (size_t)(d_+3)*66); \
      acc0_ += a_.x*b0_.x; acc1_ += a_.x*b0_.y; \
      acc0_ += a_.y*b1_.x; acc1_ += a_.y*b1_.y; \
      acc0_ += a_.z*b2_.x; acc1_ += a_.z*b2_.y; \
      acc0_ += a_.w*b3_.x; acc1_ += a_.w*b3_.y; \
    } \
    *(float2*)&sims[(size_t)qi*322 + (tile)*SEL_BLK + 2*tx] = make_float2(acc0_*SCALE, acc1_*SCALE); \
  }while(0)
#define FA_LOADV(blk) do{ \
    const float* p_ = kv + (size_t)((blk)*SEL_BLK + tV)*512 + 256 + h*DH; \
    v0 = *(const float4*)(p_ + dV);         \
    v1 = *(const float4*)(p_ + 4096 + dV);  \
    v2 = *(const float4*)(p_ + 8192 + dV);  \
    v3 = *(const float4*)(p_ + 12288 + dV); \
    v4 = *(const float4*)(p_ + 16384 + dV); \
    v5 = *(const float4*)(p_ + 20480 + dV); \
    v6 = *(const float4*)(p_ + 24576 + dV); \
    v7 = *(const float4*)(p_ + 28672 + dV); \
  }while(0)
#define FA_STOREV do{ \
    float* d_ = &kvbuf[(size_t)tV*132 + dV]; \
    *(float4*)(d_)        = v0; \
    *(float4*)(d_ + 1056) = v1; \
    *(float4*)(d_ + 2112) = v2; \
    *(float4*)(d_ + 3168) = v3; \
    *(float4*)(d_ + 4224) = v4; \
    *(float4*)(d_ + 5280) = v5; \
    *(float4*)(d_ + 6336) = v6; \
    *(float4*)(d_ + 7392) = v7; \
  }while(0)
#define FA_PV(tile) do{ \
    const float* sp_ = &sims[(size_t)qi*322 + (tile)*SEL_BLK]; \
    const float* vp_ = &kvbuf[tx << 2]; \
    _Pragma("unroll 8") \
    for (int t_ = 0; t_ < SEL_BLK; ++t_){ \
      float p_ = sp_[t_]; \
      float4 vv_ = *(const float4*)(vp_ + (size_t)t_*132); \
      av0 += p_*vv_.x; av1 += p_*vv_.y; av2 += p_*vv_.z; av3 += p_*vv_.w; \
    } \
  }while(0)

__global__ __launch_bounds__(256) void fine_attn_kernel(const bf16* __restrict__ qr,
    const bf16* __restrict__ kr, const float* __restrict__ kv,
    const int* __restrict__ sel, bf16* __restrict__ fine_o){
  int bx = blockIdx.x;
  int h = bx >> 10, n = bx & 1023;
  int tid = threadIdx.x;
  __shared__ __align__(16) float kvbuf[8448];   // kT[128][66] (QK) | V[64][132] (PV)
  __shared__ __align__(16) float qs[GQ*DH];     // natural [qi][d]
  __shared__ float sims[GQ*322];
  __shared__ float red[GQ*32];
  const int qi = tid >> 5, tx = tid & 31;

  int s0_, s1_, s2_, s3_, s4_;
  {
    const int* sp = sel + (size_t)(h*N_TOK + n)*8;
    int b0 = sp[0], b1 = sp[1], b2 = sp[2], b3 = sp[3], b4 = sp[4];
    s0_ = (b0 < 0) ? 0 : (b0 > 15 ? 15 : b0);
    s1_ = (b1 < 0) ? 0 : (b1 > 15 ? 15 : b1);
    s2_ = (b2 < 0) ? 0 : (b2 > 15 ? 15 : b2);
    s3_ = (b3 < 0) ? 0 : (b3 > 15 ? 15 : b3);
    s4_ = (b4 < 0) ? 0 : (b4 > 15 ? 15 : b4);
  }
  for (int idx = tid; idx < GQ*DH; idx += 256)
    qs[idx] = b2f(qr[(size_t)n*DIM + h*(GQ*DH) + idx]);

  // ---- QK phase: per-thread coords. (tid+i*256)&63 == tid&63; d0_i = dK + 32*i.
  const int tK = tid & 63;
  const int dK = (tid >> 6) << 3;
  int4 k0, k1, k2, k3;
  FA_LOADK(s0_);
  __syncthreads(); FA_STOREK; __syncthreads(); FA_LOADK(s1_); FA_QK(0);
  __syncthreads(); FA_STOREK; __syncthreads(); FA_LOADK(s2_); FA_QK(1);
  __syncthreads(); FA_STOREK; __syncthreads(); FA_LOADK(s3_); FA_QK(2);
  __syncthreads(); FA_STOREK; __syncthreads(); FA_LOADK(s4_); FA_QK(3);
  __syncthreads(); FA_STOREK; __syncthreads();                FA_QK(4);

  // ---- prefetch V tile 0 (overlaps softmax). t_i = tV + 8*i; dV constant.
  const int tV = tid >> 5;
  const int dV = (tid & 31) << 2;
  float4 v0, v1, v2, v3, v4, v5, v6, v7;
  FA_LOADV(s0_);
  __syncthreads();

  // ---- softmax over 320 (unchanged mapping/order)
  {
    int g = qi, lane = tx;
    float m = -1e38f;
    for (int t = lane; t < T_TOT; t += 32) m = fmaxf(m, sims[g*322 + t]);
    red[g*32+lane] = m; __syncthreads();
    for (int st = 16; st > 0; st >>= 1){ if (lane < st) red[g*32+lane] = fmaxf(red[g*32+lane], red[g*32+lane+st]); __syncthreads(); }
    float gm = red[g*32]; __syncthreads();
    float ps = 0.f;
    for (int t = lane; t < T_TOT; t += 32){ float e = expf(sims[g*322+t] - gm); sims[g*322+t] = e; ps += e; }
    red[g*32+lane] = ps; __syncthreads();
    for (int st = 16; st > 0; st >>= 1){ if (lane < st) red[g*32+lane] += red[g*32+lane+st]; __syncthreads(); }
    float inv = 1.f / red[g*32]; __syncthreads();
    for (int t = lane; t < T_TOT; t += 32) sims[g*322+t] *= inv;
  }

  // ---- PV phase with prefetch
  float av0 = 0.f, av1 = 0.f, av2 = 0.f, av3 = 0.f;
  __syncthreads(); FA_STOREV; __syncthreads(); FA_LOADV(s1_); FA_PV(0);
  __syncthreads(); FA_STOREV; __syncthreads(); FA_LOADV(s2_); FA_PV(1);
  __syncthreads(); FA_STOREV; __syncthreads(); FA_LOADV(s3_); FA_PV(2);
  __syncthreads(); FA_STOREV; __syncthreads(); FA_LOADV(s4_); FA_PV(3);
  __syncthreads(); FA_STOREV; __syncthreads();                FA_PV(4);
  {
    bf16 o[4];
    o[0] = __float2bfloat16(av0);
    o[1] = __float2bfloat16(av1);
    o[2] = __float2bfloat16(av2);
    o[3] = __float2bfloat16(av3);
    *(ushort4*)(fine_o + (size_t)n*DIM + (h*GQ + qi)*DH + (tx << 2)) = *(const ushort4*)o;
  }
}

// ---------------- Sliding-window attention, flash-style online softmax --------------------------
__global__ __launch_bounds__(256) void slide_attn_kernel(const bf16* __restrict__ qr,
    const bf16* __restrict__ kr, const float* __restrict__ kv,
    bf16* __restrict__ slide_o){
  int hq = blockIdx.y;          // 16 heads
  int qt = blockIdx.x;          // 32 query tiles of 32
  int h = hq >> 3;
  int n0 = qt * 32;
  int tid = threadIdx.x;
  __shared__ float qT[128*36];   // [d][qi], pad 36
  __shared__ float kvb[128*68];  // K^T [d][t] pad 68 (QK) | V [t][128] (PV)
  __shared__ float stT[64*36];   // [t][qi] exp'd probs, pad 36

  const int ty  = tid >> 5;
  const int tx  = tid & 31;
  const int qi0 = ty << 2;

  for (int c = tid; c < 512; c += 256){
    int qi = c & 31, d0 = (c >> 5) << 3;
    int4 w = *(const int4*)(qr + (size_t)(n0+qi)*DIM + hq*DH + d0);
    float* dst = &qT[(size_t)d0*36 + qi];
    unsigned int wv[4] = {(unsigned)w.x,(unsigned)w.y,(unsigned)w.z,(unsigned)w.w};
    #pragma unroll
    for (int m = 0; m < 4; ++m){
      dst[(2*m  )*36] = bfbits2f(wv[m] & 0xffffu);
      dst[(2*m+1)*36] = bfbits2f(wv[m] >> 16);
    }
  }

  float acc[4][4] = {};
  float mrow[4] = {-1e30f,-1e30f,-1e30f,-1e30f};
  float lrow[4] = {0.f,0.f,0.f,0.f};
  float arow[4];
  const int kstart = n0 - 128;

  for (int tile = 0; tile < 5; ++tile){
    const int kbase = kstart + tile*64;
    __syncthreads();
    for (int c = tid; c < 1024; c += 256){
      int t = c & 63, d0 = (c >> 6) << 3;
      int kg = kbase + t;
      int kgc = min(max(kg, 0), N_TOK-1);
      int4 w = *(const int4*)(kr + (size_t)kgc*256 + h*DH + d0);
      float* dst = &kvb[(size_t)d0*68 + t];
      unsigned int wv[4] = {(unsigned)w.x,(unsigned)w.y,(unsigned)w.z,(unsigned)w.w};
      #pragma unroll
      for (int m = 0; m < 4; ++m){
        dst[(2*m  )*68] = bfbits2f(wv[m] & 0xffffu);
        dst[(2*m+1)*68] = bfbits2f(wv[m] >> 16);
      }
    }
    __syncthreads();
    float c0[8] = {};
    {
      const float* aP = qT + qi0;
      const float* bP = kvb + (tx << 1);
      #pragma unroll 4
      for (int d = 0; d < 128; ++d){
        float4 a = *(const float4*)(aP + d*36);
        float2 b = *(const float2*)(bP + d*68);
        c0[0] += a.x*b.x; c0[1] += a.x*b.y;
        c0[2] += a.y*b.x; c0[3] += a.y*b.y;
        c0[4] += a.z*b.x; c0[5] += a.z*b.y;
        c0[6] += a.w*b.x; c0[7] += a.w*b.y;
      }
    }
    const int kg0 = kbase + (tx << 1);
    #pragma unroll
    for (int i = 0; i < 4; ++i){
      int qg = n0 + qi0 + i;
      int d0 = qg - kg0, d1 = d0 - 1;
      bool v0 = (kg0   >= 0) && (kg0   < N_TOK) && (d0 <= 128) && (d0 >= -128);
      bool v1 = (kg0+1 >= 0) && (kg0+1 < N_TOK) && (d1 <= 128) && (d1 >= -128);
      float s0 = v0 ? c0[i*2  ]*SCALE : -1e30f;
      float s1 = v1 ? c0[i*2+1]*SCALE : -1e30f;
      float mi = fmaxf(s0, s1);
      #pragma unroll
      for (int off = 1; off < 32; off <<= 1) mi = fmaxf(mi, __shfl_xor(mi, off));
      float mold = mrow[i];
      float mnew = fmaxf(fmaxf(mold, mi), -1e20f);
      arow[i] = expf(mold - mnew);
      mrow[i] = mnew;
      float e0 = expf(s0 - mnew);
      float e1 = expf(s1 - mnew);
      float ps = e0 + e1;
      #pragma unroll
      for (int off = 1; off < 32; off <<= 1) ps += __shfl_xor(ps, off);
      lrow[i] = lrow[i]*arow[i] + ps;
      stT[(size_t)(2*tx  )*36 + qi0 + i] = e0;
      stT[(size_t)(2*tx+1)*36 + qi0 + i] = e1;
    }
    __syncthreads();
    for (int c = tid; c < 2048; c += 256){
      int t = c >> 5, d0 = (c & 31) << 2;
      int kg = kbase + t;
      int kgc = min(max(kg, 0), N_TOK-1);
      float4 v = *(const float4*)(kv + (size_t)kgc*512 + 256 + h*DH + d0);
      *(float4*)&kvb[(size_t)t*128 + d0] = v;
    }
    __syncthreads();
    #pragma unroll
    for (int i = 0; i < 4; ++i){
      float ar = arow[i];
      acc[i][0] *= ar; acc[i][1] *= ar; acc[i][2] *= ar; acc[i][3] *= ar;
    }
    {
      const float* pP = stT + qi0;
      const float* vP = kvb + (tx << 2);
      #pragma unroll 4
      for (int t = 0; t < 64; ++t){
        float4 p = *(const float4*)(pP + t*36);
        float4 v = *(const float4*)(vP + t*128);
        acc[0][0] += p.x*v.x; acc[0][1] += p.x*v.y; acc[0][2] += p.x*v.z; acc[0][3] += p.x*v.w;
        acc[1][0] += p.y*v.x; acc[1][1] += p.y*v.y; acc[1][2] += p.y*v.z; acc[1][3] += p.y*v.w;
        acc[2][0] += p.z*v.x; acc[2][1] += p.z*v.y; acc[2][2] += p.z*v.z; acc[2][3] += p.z*v.w;
        acc[3][0] += p.w*v.x; acc[3][1] += p.w*v.y; acc[3][2] += p.w*v.z; acc[3][3] += p.w*v.w;
      }
    }
  }
  #pragma unroll
  for (int i = 0; i < 4; ++i){
    int row = n0 + qi0 + i;
    float inv = 1.f / lrow[i];
    bf16 o[4];
    o[0] = __float2bfloat16(acc[i][0]*inv);
    o[1] = __float2bfloat16(acc[i][1]*inv);
    o[2] = __float2bfloat16(acc[i][2]*inv);
    o[3] = __float2bfloat16(acc[i][3]*inv);
    *(ushort4*)(slide_o + (size_t)row*DIM + hq*DH + (tx << 2)) = *(const ushort4*)o;
  }
}

// ---------------- Gated combine -> ocombT bf16 SLAB-TILED [s][row][kk] ------------------------------
__global__ __launch_bounds__(256) void combine_kernel(const bf16* __restrict__ cmp_o,
    const bf16* __restrict__ fine_o, const bf16* __restrict__ slide_o,
    const float* __restrict__ graw, const float* __restrict__ bg,
    unsigned short* __restrict__ ocombT){
  int n = blockIdx.x, tid = threadIdx.x;
  #pragma unroll
  for (int i = 0; i < 8; ++i){
    int c = tid + i*256;
    int hq = c >> 7;
    float g0 = 1.f/(1.f + expf(-(graw[(size_t)n*48 + hq*3 + 0] + bg[hq*3 + 0])));
    float g1 = 1.f/(1.f + expf(-(graw[(size_t)n*48 + hq*3 + 1] + bg[hq*3 + 1])));
    float g2 = 1.f/(1.f + expf(-(graw[(size_t)n*48 + hq*3 + 2] + bg[hq*3 + 2])));
    size_t idx = (size_t)n*DIM + c;
    float v = b2f(cmp_o[idx])*g0 + b2f(fine_o[idx])*g1 + b2f(slide_o[idx])*g2;
    int sl = c >> 5, kk = c & 31;
    ocombT[(size_t)sl*(N_TOK*32) + (size_t)n*32 + kk] = f2bf(v);
  }
}

extern "C" void kernel_launch(void* const* d_in, const int* in_sizes, int n_in,
                              void* d_out, int out_size, void* d_ws, size_t ws_size,
                              hipStream_t stream)
{
  const float* x      = (const float*)d_in[0];
  const float* g_norm = (const float*)d_in[1];
  const float* W_qkv  = (const float*)d_in[2];
  const float* k_pos  = (const float*)d_in[3];
  const float* v_pos  = (const float*)d_in[4];
  const float* mem_kv = (const float*)d_in[5];
  const float* Wk1    = (const float*)d_in[6];
  const float* bk1    = (const float*)d_in[7];
  const float* Wk2    = (const float*)d_in[8];
  const float* bk2    = (const float*)d_in[9];
  const float* Wv1    = (const float*)d_in[10];
  const float* bv1    = (const float*)d_in[11];
  const float* Wv2    = (const float*)d_in[12];
  const float* bv2    = (const float*)d_in[13];
  const float* Wg     = (const float*)d_in[14];
  const float* bg     = (const float*)d_in[15];
  const float* W_out  = (const float*)d_in[16];
  float* out = (float*)d_out;
  (void)ws_size; (void)in_sizes; (void)n_in; (void)out_size;

  // ---- Workspace layout (bytes), peak ~54.5 MB ----
  char* base = (char*)d_ws;
  float* q     = (float*)(base + 0);                 // 8 MB [n][2048] fp32, live -> cmp_attn
  float* xn    = (float*)(base + 8388608);           // 8 MB fp32
  bf16*  qr    = (bf16*) (base + 8388608);           // 4 MB (over xn, after xn dead)
  bf16*  kr    = (bf16*) (base + 12582912);          // 0.5 MB
  unsigned short* ocombT = (unsigned short*)(base + 8388608);  // 4 MB (over qr, after slide) slab-tiled
  float* kv    = (float*)(base + 16777216);          // 2 MB [n][512] fp32 (direct-stored by qkv GEMM)
  float* hbuf2 = (float*)(base + 18874368);          // 4 MB: [2][128][4096] fp32 (k, v halves)
  bf16*  cmp_o = (bf16*) (base + 18874368);          // 4 MB (over hbuf2, after MLP2s)
  float* ckb   = (float*)(base + 23068672);          // 64 KB (raw)
  float* cvb   = (float*)(base + 23134208);          // 64 KB (raw)
  float* ck    = (float*)(base + 23199744);          // 65 KB
  float* cv    = (float*)(base + 23266304);          // 65 KB
  float* gates = (float*)(base + 23332864);          // 192 KB (raw, sigmoid folded in combine)
  int*   sel   = (int*)  (base + 23529472);          // 64 KB
  bf16*  fine_o  = (bf16*)(base + 0);                // 4 MB (over q, after cmp_attn)
  bf16*  slide_o = (bf16*)(base + 4194304);          // 4 MB (over q upper half)
  // Pre-split operands (xnh/xnl and ocombT are SLAB-TILED [s][row][32])
  unsigned short* xnh  = (unsigned short*)(base + 25165824);  // 4 MB bf16 hi(xn)
  unsigned short* xnl  = (unsigned short*)(base + 29360128);  // 4 MB bf16 lo(xn)
  unsigned short* WqhT = (unsigned short*)(base + 33554432);  // 10.49 MB: full W_qkv hi, [s][2560][32]
  unsigned short* WqlT = (unsigned short*)(base + 44040192);  // 10.49 MB: lo     (ends 54,525,952)
  unsigned short* WohT = WqhT;   // W_out split reuses first 8 MB of each region (after qkv GEMM)
  unsigned short* WolT = WqlT;
  unsigned short* fh   = (unsigned short*)(base + 41943040);  // 2 MB, tail of WqhT region (Wq dead)
  unsigned short* fl   = (unsigned short*)(base + 52428800);  // 2 MB, tail of WqlT region

  // Zero split-K accumulation targets (stream-ordered; graph-capture legal)
  hipMemsetAsync(gates, 0, (size_t)N_TOK*48*4,   stream);
  hipMemsetAsync(ckb,   0, (size_t)KVH*NWIN*DH*4, stream);
  hipMemsetAsync(cvb,   0, (size_t)KVH*NWIN*DH*4, stream);
  hipMemsetAsync(hbuf2, 0, (size_t)2*128*CDIM*4,  stream);

  // Full W_qkv (2560 cols) -> slab-tiled hi/lo bf16 split
  transpose_split_kernel<<<dim3(40, 32), 256, 0, stream>>>(W_qkv, 2560, 2560, WqhT, WqlT);
  rmsnorm_kernel<<<N_TOK, 256, 0, stream>>>(x, g_norm, xn, xnh, xnl);
  // gates_raw = xn @ Wg [1024 x 48] — z=16 (round-15, passing)
  gemm_splitk_kernel<<<dim3(1, 16, 16), 256, 0, stream>>>(xn, 0, nullptr, Wg, 48, gates, N_TOK, 48, DIM, 128);
  // q + kv in ONE LDS-free MFMA GEMM — wide 32x32 wave tile (round-23, passing)
  gemm_mfma_qkvT_kernel<<<dim3(20, 32), 256, 0, stream>>>(xnh, xnl, WqhT, WqlT, q, kv);
  // W_out -> slab-tiled hi/lo split (reuses first 8 MB of Wq regions; ordered after qkv GEMM)
  transpose_split_kernel<<<dim3(32, 32), 256, 0, stream>>>(W_out, 2048, 2048, WohT, WolT);
  // qr, kr (bf16) — xn dead after this point
  rope_kernel<<<N_TOK, 256, 0, stream>>>(q, kv, qr, kr);
  // compression MLP1s: staged MFMA, 4 m-frags + z=16 (round-24; bit-identical values)
  build_f_kernel<<<256, 256, 0, stream>>>(kv, k_pos, v_pos, fh, fl);
  gemm_mfma_mlp1_kernel<<<dim3(64, 2, 16), 256, 0, stream>>>(fh, fl, Wk1, Wv1, hbuf2);
  // MLP2s fused into one dispatch (round-14, passing)
  gemm_mlp2_fused_kernel<<<dim3(2, 2, 64), 256, 0, stream>>>(hbuf2, bk1, bv1, Wk2, Wv2, ckb, cvb);
  assemble_kernel<<<NCMP, 256, 0, stream>>>(ckb, cvb, mem_kv, bk2, bv2, ck, cv);
  // compressed attention + selection (-> cmp_o, over hbuf2 after MLP2s done)
  cmp_attn_kernel<<<KVH*N_TOK, 256, 0, stream>>>(q, ck, cv, cmp_o, sel);
  // fine attention (q dead -> fine_o over q region), round-20 named-scalar prefetch (passing)
  fine_attn_kernel<<<KVH*N_TOK, 256, 0, stream>>>(qr, kr, kv, sel, fine_o);
  // sliding attention (-> slide_o over q upper half)
  slide_attn_kernel<<<dim3(32, 16), 256, 0, stream>>>(qr, kr, kv, slide_o);
  // combine (qr dead -> ocombT over qr, slab-tiled); sigmoid(graw+bg) folded here
  combine_kernel<<<N_TOK, 256, 0, stream>>>(cmp_o, fine_o, slide_o, gates, bg, ocombT);
  // out = ocomb @ W_out — wide 32x32 wave tile (round-23, passing)
  gemm_mfma_outT_kernel<<<dim3(16, 32), 256, 0, stream>>>(ocombT, WohT, WolT, out);
}

// Round 25
// 692.606 us; speedup vs baseline: 1.0898x; 1.0066x over previous
//
#include <hip/hip_runtime.h>
#include <hip/hip_bf16.h>
#include <math.h>

typedef __hip_bfloat16 bf16;
typedef __attribute__((ext_vector_type(8))) short bf16x8;
typedef __attribute__((ext_vector_type(4))) float f32x4;

#define N_TOK 1024
#define DIM 2048
#define NHEADS 16
#define KVH 2
#define DH 128
#define GQ 8
#define NWIN 64
#define CMP_BLK 32
#define NCMP 65        // MEM_KV + NWIN
#define NFINE 16
#define SEL_BLK 64
#define T_TOT 320
#define CDIM 4096      // CMP_BLK*DH
#define SCALE 0.08838834764831845f

static __device__ __forceinline__ float b2f(bf16 v){ return __bfloat162float(v); }
static __device__ __forceinline__ float bfbits2f(unsigned int u){
  union { unsigned int i; float f; } x; x.i = u << 16; return x.f;
}
// RNE float->bf16 bits (matches __float2bfloat16 for normal values)
static __device__ __forceinline__ unsigned short f2bf(float f){
  union { float f; unsigned u; } x; x.f = f;
  unsigned r = x.u + 0x7fffu + ((x.u >> 16) & 1u);
  return (unsigned short)(r >> 16);
}

// ---------------- RMSNorm: x fp32 [N,DIM] -> xn fp32 + xnh/xnl bf16 hi/lo SLAB-TILED ----------------
__global__ __launch_bounds__(256) void rmsnorm_kernel(const float* __restrict__ x,
                                                      const float* __restrict__ g,
                                                      float* __restrict__ xn,
                                                      unsigned short* __restrict__ xnh,
                                                      unsigned short* __restrict__ xnl){
  int n = blockIdx.x, tid = threadIdx.x;
  __shared__ float red[256];
  const float* row = x + (size_t)n*DIM;
  float vals[8];
  float s = 0.f;
  #pragma unroll
  for (int i = 0; i < 8; ++i){ float v = row[tid + i*256]; vals[i] = v; s += v*v; }
  red[tid] = s; __syncthreads();
  for (int st = 128; st > 0; st >>= 1){ if (tid < st) red[tid] += red[tid+st]; __syncthreads(); }
  float scale = 1.0f / sqrtf(red[0]/(float)DIM + 1e-6f);
  #pragma unroll
  for (int i = 0; i < 8; ++i){
    int c = tid + i*256;
    float v = vals[i]*scale*g[c];
    xn[(size_t)n*DIM + c] = v;
    unsigned short h = f2bf(v);
    int sl = c >> 5, kk = c & 31;
    size_t o = (size_t)sl*(N_TOK*32) + (size_t)n*32 + kk;
    xnh[o] = h;
    xnl[o] = f2bf(v - bfbits2f(h));
  }
}

// ---------------- Transpose + hi/lo split into SLAB-TILED layout --------------------------------
__global__ __launch_bounds__(256) void transpose_split_kernel(const float* __restrict__ W, int ldw,
                                                              int ncols,
                                                              unsigned short* __restrict__ Th,
                                                              unsigned short* __restrict__ Tl){
  __shared__ float t[64][65];
  int bx = blockIdx.x;   // n tile
  int by = blockIdx.y;   // k tile
  int tid = threadIdx.x;
  #pragma unroll
  for (int i = 0; i < 16; ++i){
    int idx = tid + i*256;
    int r = idx >> 6, c = idx & 63;            // r=k_local, c=n_local (coalesced read)
    t[r][c] = W[(size_t)(by*64 + r)*ldw + bx*64 + c];
  }
  __syncthreads();
  #pragma unroll
  for (int i = 0; i < 16; ++i){
    int idx = tid + i*256;
    int nl = idx >> 6, kl = idx & 63;          // kl consecutive -> kk contiguous (coalesced)
    float v = t[kl][nl];
    unsigned short h = f2bf(v);
    unsigned short l = f2bf(v - bfbits2f(h));
    int s = by*2 + (kl >> 5), kk = kl & 31;
    size_t o = (size_t)s*((size_t)ncols*32) + (size_t)(bx*64 + nl)*32 + kk;
    Th[o] = h;
    Tl[o] = l;
  }
}

// ---------------- Split-K GEMM (64x64 tile) — kept for gates -----------------------------------
__global__ __launch_bounds__(256) void gemm_splitk_kernel(const void* __restrict__ Av, int a_is_bf16,
                                                          const float* __restrict__ afold,
                                                          const float* __restrict__ B, int ldb,
                                                          float* __restrict__ C,
                                                          int M, int N, int K, int kchunk){
  __shared__ __align__(16) float As[16*68];
  __shared__ __align__(16) float Bs[16*68];
  int tid = threadIdx.x;
  int tx = tid & 15, ty = tid >> 4;
  int m0 = blockIdx.y * 64, n0 = blockIdx.x * 64;
  int kz = blockIdx.z * kchunk;
  const float* Af = (const float*)Av;
  const bf16*  Ab = (const bf16*)Av;
  float c[4][4] = {};
  for (int k0 = kz; k0 < kz + kchunk; k0 += 16){
    #pragma unroll
    for (int i = 0; i < 4; ++i){
      int idx = tid + i*256;
      int kk = idx & 15, m = idx >> 4;
      size_t aidx = (size_t)(m0+m)*K + k0 + kk;
      float av = a_is_bf16 ? b2f(Ab[aidx]) : Af[aidx];
      if (afold) av = fmaxf(av + afold[k0+kk], 0.f);
      As[kk*68 + m] = av;
    }
    #pragma unroll
    for (int i = 0; i < 4; ++i){
      int idx = tid + i*256;
      int nn = idx & 63, kk = idx >> 6;
      int col = n0 + nn;
      Bs[kk*68 + nn] = (col < N) ? B[(size_t)(k0+kk)*ldb + col] : 0.f;
    }
    __syncthreads();
    #pragma unroll
    for (int kk = 0; kk < 16; ++kk){
      float a[4], b[4];
      *(float4*)a = *(const float4*)&As[kk*68 + ty*4];
      *(float4*)b = *(const float4*)&Bs[kk*68 + tx*4];
      #pragma unroll
      for (int i = 0; i < 4; ++i)
        #pragma unroll
        for (int j = 0; j < 4; ++j)
          c[i][j] += a[i]*b[j];
    }
    __syncthreads();
  }
  #pragma unroll
  for (int i = 0; i < 4; ++i){
    int row = m0 + ty*4 + i;
    #pragma unroll
    for (int j = 0; j < 4; ++j){
      int col = n0 + tx*4 + j;
      if (col < N) atomicAdd(&C[(size_t)row*N + col], c[i][j]);
    }
  }
}

// ---------------- MLP2 GEMM, k/v FUSED into one dispatch (round-14, passing) ------------------------
__global__ __launch_bounds__(256) void gemm_mlp2_fused_kernel(const float* __restrict__ hbuf2,
    const float* __restrict__ bk1, const float* __restrict__ bv1,
    const float* __restrict__ Wk2, const float* __restrict__ Wv2,
    float* __restrict__ ckb, float* __restrict__ cvb){
  const int kvsel = blockIdx.z >> 5;
  const int kz = (blockIdx.z & 31) * 128;
  const float* Af    = hbuf2 + (size_t)kvsel*128*CDIM;
  const float* afold = kvsel ? bv1 : bk1;
  const float* B     = kvsel ? Wv2 : Wk2;
  float* C           = kvsel ? cvb : ckb;
  __shared__ __align__(16) float As[16*68];
  __shared__ __align__(16) float Bs[16*68];
  int tid = threadIdx.x;
  int tx = tid & 15, ty = tid >> 4;
  int m0 = blockIdx.y * 64, n0 = blockIdx.x * 64;
  float c[4][4] = {};
  for (int k0 = kz; k0 < kz + 128; k0 += 16){
    #pragma unroll
    for (int i = 0; i < 4; ++i){
      int idx = tid + i*256;
      int kk = idx & 15, m = idx >> 4;
      float av = Af[(size_t)(m0+m)*CDIM + k0 + kk];
      av = fmaxf(av + afold[k0+kk], 0.f);
      As[kk*68 + m] = av;
    }
    #pragma unroll
    for (int i = 0; i < 4; ++i){
      int idx = tid + i*256;
      int nn = idx & 63, kk = idx >> 6;
      Bs[kk*68 + nn] = B[(size_t)(k0+kk)*DH + n0 + nn];
    }
    __syncthreads();
    #pragma unroll
    for (int kk = 0; kk < 16; ++kk){
      float a[4], b[4];
      *(float4*)a = *(const float4*)&As[kk*68 + ty*4];
      *(float4*)b = *(const float4*)&Bs[kk*68 + tx*4];
      #pragma unroll
      for (int i = 0; i < 4; ++i)
        #pragma unroll
        for (int j = 0; j < 4; ++j)
          c[i][j] += a[i]*b[j];
    }
    __syncthreads();
  }
  #pragma unroll
  for (int i = 0; i < 4; ++i){
    int row = m0 + ty*4 + i;
    #pragma unroll
    for (int j = 0; j < 4; ++j){
      int col = n0 + tx*4 + j;
      atomicAdd(&C[(size_t)row*DH + col], c[i][j]);
    }
  }
}

// ---------------- MLP1 GEMM via MFMA — round-24 PASSING: 4 m-frags + z=16 ---------------------------
__global__ __launch_bounds__(256) void gemm_mfma_mlp1_kernel(const unsigned short* __restrict__ fh,
                                                             const unsigned short* __restrict__ fl,
                                                             const float* __restrict__ Wk1,
                                                             const float* __restrict__ Wv1,
                                                             float* __restrict__ hbuf2){
  const int kvsel = blockIdx.z >> 3;
  const int slab0 = (blockIdx.z & 7) * 16;     // 16 slabs = 512 k
  const int kz = slab0 * 32;
  const unsigned short* Ah = fh + (size_t)kvsel*524288 + (size_t)slab0*4096;
  const unsigned short* Al = fl + (size_t)kvsel*524288 + (size_t)slab0*4096;
  const float* B = kvsel ? Wv1 : Wk1;
  float* C = hbuf2 + (size_t)kvsel*524288;
  const int n0 = blockIdx.x * 64;
  const int m0 = blockIdx.y * 64;              // 4 m-frags = 64 rows/block
  const int tid = threadIdx.x;
  const int wid = tid >> 6, lane = tid & 63;
  const int l15 = lane & 15, lg = lane >> 4;
  const int colL = wid*16 + l15;
  __shared__ __align__(16) float Bs[2][32][68];   // 17.4 KB

  f32x4 acc[4];
  #pragma unroll
  for (int m = 0; m < 4; ++m) acc[m] = (f32x4){0.f,0.f,0.f,0.f};

  const unsigned short* ahp[4];
  const unsigned short* alp[4];
  #pragma unroll
  for (int m = 0; m < 4; ++m){
    size_t ro = (size_t)(m0 + m*16 + l15)*32 + lg*8;
    ahp[m] = Ah + ro;
    alp[m] = Al + ro;
  }
  const int sr = tid >> 3, sc = (tid & 7) * 8;   // stage: row sr (of 32), 8 cols from sc

  float4 rb0, rb1;
  int4 rah[4], ral[4];
  {
    const float* bp = B + (size_t)(kz + sr)*CDIM + n0 + sc;
    rb0 = *(const float4*)(bp);
    rb1 = *(const float4*)(bp + 4);
    #pragma unroll
    for (int m = 0; m < 4; ++m){
      rah[m] = *(const int4*)(ahp[m]);
      ral[m] = *(const int4*)(alp[m]);
    }
  }

  #pragma unroll 1
  for (int s = 0; s < 16; ++s){
    const int buf = s & 1;                        // runtime index OK: LDS, not registers
    *(float4*)&Bs[buf][sr][sc]     = rb0;
    *(float4*)&Bs[buf][sr][sc + 4] = rb1;
    int4 cah[4], cal[4];
    #pragma unroll
    for (int m = 0; m < 4; ++m){ cah[m] = rah[m]; cal[m] = ral[m]; }
    __syncthreads();
    if (s + 1 < 16){
      const int kr = kz + (s+1)*32;
      const float* bp = B + (size_t)(kr + sr)*CDIM + n0 + sc;
      rb0 = *(const float4*)(bp);
      rb1 = *(const float4*)(bp + 4);
      #pragma unroll
      for (int m = 0; m < 4; ++m){
        rah[m] = *(const int4*)(ahp[m] + (size_t)(s+1)*4096);
        ral[m] = *(const int4*)(alp[m] + (size_t)(s+1)*4096);
      }
    }
    float bv[8];
    #pragma unroll
    for (int j = 0; j < 8; ++j) bv[j] = Bs[buf][lg*8 + j][colL];
    bf16x8 bh, bl;
    #pragma unroll
    for (int j = 0; j < 8; ++j){
      unsigned short h = f2bf(bv[j]);
      bh[j] = (short)h;
      bl[j] = (short)f2bf(bv[j] - bfbits2f(h));
    }
    #pragma unroll
    for (int m = 0; m < 4; ++m){
      union { int4 i; bf16x8 v; } uah, ual;
      uah.i = cah[m]; ual.i = cal[m];
      acc[m] = __builtin_amdgcn_mfma_f32_16x16x32_bf16(uah.v, bh, acc[m], 0, 0, 0);
      acc[m] = __builtin_amdgcn_mfma_f32_16x16x32_bf16(ual.v, bh, acc[m], 0, 0, 0);
      acc[m] = __builtin_amdgcn_mfma_f32_16x16x32_bf16(uah.v, bl, acc[m], 0, 0, 0);
    }
  }
  const int col = n0 + colL;
  #pragma unroll
  for (int m = 0; m < 4; ++m)
    #pragma unroll
    for (int r = 0; r < 4; ++r){
      const int row = m0 + m*16 + lg*4 + r;
      atomicAdd(&C[(size_t)row*CDIM + col], acc[m][r]);
    }
}

// ---------------- q+kv GEMM — round-23 PASSING: WIDE WAVE TILE 32x32, depth-2 rings -----------------
#define QKV_MFMA1(ACC, AH, AL, BH, BL) do{ \
    union { int4 i; bf16x8 v; } ubh_, ubl_; \
    ubh_.i = BH; ubl_.i = BL; \
    _Pragma("unroll") \
    for (int m_ = 0; m_ < 2; ++m_){ \
      union { int4 i; bf16x8 v; } uah_, ual_; \
      uah_.i = AH[m_]; ual_.i = AL[m_]; \
      ACC[m_] = __builtin_amdgcn_mfma_f32_16x16x32_bf16(uah_.v, ubh_.v, ACC[m_], 0, 0, 0); \
      ACC[m_] = __builtin_amdgcn_mfma_f32_16x16x32_bf16(ual_.v, ubh_.v, ACC[m_], 0, 0, 0); \
      ACC[m_] = __builtin_amdgcn_mfma_f32_16x16x32_bf16(uah_.v, ubl_.v, ACC[m_], 0, 0, 0); \
    } \
  }while(0)
#define QKV_FILL(AH, AL, BH0, BL0, BH1, BL1, S) do{ \
    _Pragma("unroll") \
    for (int m_ = 0; m_ < 2; ++m_){ \
      AH[m_] = *(const int4*)(aph[m_] + (size_t)(S)*ASTR); \
      AL[m_] = *(const int4*)(apl[m_] + (size_t)(S)*ASTR); \
    } \
    BH0 = *(const int4*)(bph0 + (size_t)(S)*BSTR); \
    BL0 = *(const int4*)(bpl0 + (size_t)(S)*BSTR); \
    BH1 = *(const int4*)(bph1 + (size_t)(S)*BSTR); \
    BL1 = *(const int4*)(bpl1 + (size_t)(S)*BSTR); \
  }while(0)

__global__ __launch_bounds__(256) void gemm_mfma_qkvT_kernel(const unsigned short* __restrict__ Ah,
                                                             const unsigned short* __restrict__ Al,
                                                             const unsigned short* __restrict__ BhT,
                                                             const unsigned short* __restrict__ BlT,
                                                             float* __restrict__ Cq,
                                                             float* __restrict__ Ckv){
  const int n0 = blockIdx.x * 128;
  const int m0 = blockIdx.y * 32;
  const int tid = threadIdx.x;
  const int wid = tid >> 6, lane = tid & 63;
  const int l15 = lane & 15, lg = lane >> 4;
  const int col0 = n0 + wid*32 + l15;
  const int col1 = col0 + 16;
  const size_t ASTR = (size_t)N_TOK*32;     // 32768
  const size_t BSTR = (size_t)2560*32;      // 81920

  f32x4 acc0[2], acc1[2];
  #pragma unroll
  for (int m = 0; m < 2; ++m){ acc0[m] = (f32x4){0.f,0.f,0.f,0.f}; acc1[m] = (f32x4){0.f,0.f,0.f,0.f}; }

  const unsigned short* aph[2];
  const unsigned short* apl[2];
  #pragma unroll
  for (int m = 0; m < 2; ++m){
    size_t ro = (size_t)(m0 + m*16 + l15)*32 + lg*8;
    aph[m] = Ah + ro;
    apl[m] = Al + ro;
  }
  const unsigned short* bph0 = BhT + (size_t)col0*32 + lg*8;
  const unsigned short* bpl0 = BlT + (size_t)col0*32 + lg*8;
  const unsigned short* bph1 = BhT + (size_t)col1*32 + lg*8;
  const unsigned short* bpl1 = BlT + (size_t)col1*32 + lg*8;

  int4 r0ah[2], r0al[2], r1ah[2], r1al[2];
  int4 r0bh0, r0bl0, r0bh1, r0bl1, r1bh0, r1bl0, r1bh1, r1bl1;
  QKV_FILL(r0ah, r0al, r0bh0, r0bl0, r0bh1, r0bl1, 0);
  QKV_FILL(r1ah, r1al, r1bh0, r1bl0, r1bh1, r1bl1, 1);

  #pragma unroll 1
  for (int s = 0; s < 64; s += 2){
    QKV_MFMA1(acc0, r0ah, r0al, r0bh0, r0bl0);
    QKV_MFMA1(acc1, r0ah, r0al, r0bh1, r0bl1);
    if (s + 2 < 64) QKV_FILL(r0ah, r0al, r0bh0, r0bl0, r0bh1, r0bl1, s+2);
    QKV_MFMA1(acc0, r1ah, r1al, r1bh0, r1bl0);
    QKV_MFMA1(acc1, r1ah, r1al, r1bh1, r1bl1);
    if (s + 3 < 64) QKV_FILL(r1ah, r1al, r1bh0, r1bl0, r1bh1, r1bl1, s+3);
  }
  #pragma unroll
  for (int m = 0; m < 2; ++m)
    #pragma unroll
    for (int r = 0; r < 4; ++r){
      const int row = m0 + m*16 + lg*4 + r;
      if (col0 < 2048) Cq[(size_t)row*DIM + col0] = acc0[m][r];
      else             Ckv[(size_t)row*512 + (col0 - 2048)] = acc0[m][r];
      if (col1 < 2048) Cq[(size_t)row*DIM + col1] = acc1[m][r];
      else             Ckv[(size_t)row*512 + (col1 - 2048)] = acc1[m][r];
    }
}

// ---------------- out-GEMM — round-23 PASSING: WIDE WAVE TILE 32x32, depth-2 rings, 2-term ----------
#define OUT_MFMA1(ACC, AA, BH, BL) do{ \
    union { int4 i; bf16x8 v; } ubh_, ubl_; \
    ubh_.i = BH; ubl_.i = BL; \
    _Pragma("unroll") \
    for (int m_ = 0; m_ < 2; ++m_){ \
      union { int4 i; bf16x8 v; } ua_; ua_.i = AA[m_]; \
      ACC[m_] = __builtin_amdgcn_mfma_f32_16x16x32_bf16(ua_.v, ubh_.v, ACC[m_], 0, 0, 0); \
      ACC[m_] = __builtin_amdgcn_mfma_f32_16x16x32_bf16(ua_.v, ubl_.v, ACC[m_], 0, 0, 0); \
    } \
  }while(0)
#define OUT_FILL(AA, BH0, BL0, BH1, BL1, S) do{ \
    _Pragma("unroll") \
    for (int m_ = 0; m_ < 2; ++m_) \
      AA[m_] = *(const int4*)(ap[m_] + (size_t)(S)*ASTR); \
    BH0 = *(const int4*)(bph0 + (size_t)(S)*BSTR); \
    BL0 = *(const int4*)(bpl0 + (size_t)(S)*BSTR); \
    BH1 = *(const int4*)(bph1 + (size_t)(S)*BSTR); \
    BL1 = *(const int4*)(bpl1 + (size_t)(S)*BSTR); \
  }while(0)

__global__ __launch_bounds__(256) void gemm_mfma_outT_kernel(const unsigned short* __restrict__ AT,
                                                             const unsigned short* __restrict__ BhT,
                                                             const unsigned short* __restrict__ BlT,
                                                             float* __restrict__ C){
  const int n0 = blockIdx.x * 128;
  const int m0 = blockIdx.y * 32;
  const int tid = threadIdx.x;
  const int wid = tid >> 6, lane = tid & 63;
  const int l15 = lane & 15, lg = lane >> 4;
  const int col0 = n0 + wid*32 + l15;
  const int col1 = col0 + 16;
  const size_t ASTR = (size_t)N_TOK*32;     // 32768
  const size_t BSTR = (size_t)2048*32;      // 65536

  f32x4 acc0[2], acc1[2];
  #pragma unroll
  for (int m = 0; m < 2; ++m){ acc0[m] = (f32x4){0.f,0.f,0.f,0.f}; acc1[m] = (f32x4){0.f,0.f,0.f,0.f}; }

  const unsigned short* ap[2];
  #pragma unroll
  for (int m = 0; m < 2; ++m)
    ap[m] = AT + (size_t)(m0 + m*16 + l15)*32 + lg*8;
  const unsigned short* bph0 = BhT + (size_t)col0*32 + lg*8;
  const unsigned short* bpl0 = BlT + (size_t)col0*32 + lg*8;
  const unsigned short* bph1 = BhT + (size_t)col1*32 + lg*8;
  const unsigned short* bpl1 = BlT + (size_t)col1*32 + lg*8;

  int4 r0a[2], r1a[2];
  int4 r0bh0, r0bl0, r0bh1, r0bl1, r1bh0, r1bl0, r1bh1, r1bl1;
  OUT_FILL(r0a, r0bh0, r0bl0, r0bh1, r0bl1, 0);
  OUT_FILL(r1a, r1bh0, r1bl0, r1bh1, r1bl1, 1);

  #pragma unroll 1
  for (int s = 0; s < 64; s += 2){
    OUT_MFMA1(acc0, r0a, r0bh0, r0bl0);
    OUT_MFMA1(acc1, r0a, r0bh1, r0bl1);
    if (s + 2 < 64) OUT_FILL(r0a, r0bh0, r0bl0, r0bh1, r0bl1, s+2);
    OUT_MFMA1(acc0, r1a, r1bh0, r1bl0);
    OUT_MFMA1(acc1, r1a, r1bh1, r1bl1);
    if (s + 3 < 64) OUT_FILL(r1a, r1bh0, r1bl0, r1bh1, r1bl1, s+3);
  }
  #pragma unroll
  for (int m = 0; m < 2; ++m)
    #pragma unroll
    for (int r = 0; r < 4; ++r){
      const int row = m0 + m*16 + lg*4 + r;
      C[(size_t)row*DIM + col0] = acc0[m][r];
      C[(size_t)row*DIM + col1] = acc1[m][r];
    }
}

// ---------------- RoPE: q fp32 [n][2048], kv fp32 [n][512] -> qr bf16 [n][2048], kr bf16 [n][256] ----
__global__ __launch_bounds__(256) void rope_kernel(const float* __restrict__ q,
    const float* __restrict__ kv, bf16* __restrict__ qr, bf16* __restrict__ kr){
  int n = blockIdx.x, tid = threadIdx.x;
  const float* qrow = q + (size_t)n*DIM;
  bf16* qrrow = qr + (size_t)n*DIM;
  #pragma unroll
  for (int i = 0; i < 4; ++i){
    int p = tid + i*256;
    int hd = p >> 6, ii = p & 63;
    float inv = powf(10000.f, -(float)ii/64.f);
    float ang = (float)n * inv;
    float cs = cosf(ang), sn = sinf(ang);
    float x1 = qrow[hd*DH + 2*ii], x2 = qrow[hd*DH + 2*ii + 1];
    qrrow[hd*DH + 2*ii]     = __float2bfloat16(x1*cs - x2*sn);
    qrrow[hd*DH + 2*ii + 1] = __float2bfloat16(x1*sn + x2*cs);
  }
  if (tid < 128){
    int h = tid >> 6, ii = tid & 63;
    float inv = powf(10000.f, -(float)ii/64.f);
    float ang = (float)n * inv;
    float cs = cosf(ang), sn = sinf(ang);
    const float* kvrow = kv + (size_t)n*512;
    float x1 = kvrow[h*DH + 2*ii], x2 = kvrow[h*DH + 2*ii + 1];
    bf16* krrow = kr + (size_t)n*256;
    krrow[h*DH + 2*ii]     = __float2bfloat16(x1*cs - x2*sn);
    krrow[h*DH + 2*ii + 1] = __float2bfloat16(x1*sn + x2*cs);
  }
}

// ---------------- Build compression-MLP input, k/v fused, SLAB-TILED bf16 hi/lo ---------------------
// fh/fl layout: [kv][128 slabs][128 rows][32] (slab = k/32 within CDIM).
__global__ __launch_bounds__(256) void build_f_kernel(const float* __restrict__ kv,
    const float* __restrict__ k_pos, const float* __restrict__ v_pos,
    unsigned short* __restrict__ fh, unsigned short* __restrict__ fl){
  int bw2 = blockIdx.x;          // 0..255: kvsel*128 + h*NWIN + w
  int kvsel = bw2 >> 7, bw = bw2 & 127;
  int voff = kvsel * 256;
  const float* pos = kvsel ? v_pos : k_pos;
  int h = bw >> 6, w = bw & 63;
  int tid = threadIdx.x;
  for (int idx = tid; idx < CMP_BLK*DH; idx += 256){
    int j = idx >> 7, d = idx & 127;
    int t = w*16 + j - 16;       // padded window index
    float kvv = (t >= 0) ? kv[(size_t)t*512 + voff + h*DH + d] : 0.f;
    float v = kvv + pos[(h*CMP_BLK + j)*DH + d];
    unsigned short hh = f2bf(v);
    int sl = idx >> 5, kk = idx & 31;
    size_t o = (size_t)kvsel*524288 + (size_t)sl*4096 + (size_t)bw*32 + kk;
    fh[o] = hh;
    fl[o] = f2bf(v - bfbits2f(hh));
  }
}

// ---------------- Assemble ck/cv [KVH][NCMP][DH]; MLP second bias folded here ----------------
__global__ __launch_bounds__(256) void assemble_kernel(const float* __restrict__ ckb,
    const float* __restrict__ cvb, const float* __restrict__ mem_kv,
    const float* __restrict__ bk2, const float* __restrict__ bv2,
    float* __restrict__ ck, float* __restrict__ cv){
  int j = blockIdx.x;            // 0..64
  int tid = threadIdx.x;         // 256 = KVH*DH
  int h = tid >> 7, d = tid & 127;
  float kvx, vvx;
  if (j == 0){
    kvx = mem_kv[(0*KVH + h)*DH + d];
    vvx = mem_kv[(1*KVH + h)*DH + d];
  } else {
    kvx = ckb[((size_t)h*NWIN + (j-1))*DH + d] + bk2[d];
    vvx = cvb[((size_t)h*NWIN + (j-1))*DH + d] + bv2[d];
  }
  ck[((size_t)h*NCMP + j)*DH + d] = kvx;
  cv[((size_t)h*NCMP + j)*DH + d] = vvx;
}

// ---------------- Compressed attention — ROUND-25: shfl-butterfly softmax reductions ---------------
// The 32-lane strided LDS-tree reduces are replaced by __shfl_xor butterflies with DESCENDING
// offsets 16,8,4,2,1 — identical set-partition tree, commutative swaps only -> BIT-IDENTICAL.
// Removes red[] and ~12 barriers. Cross-wave barriers (sims fill, output) kept.
__global__ __launch_bounds__(256) void cmp_attn_kernel(const float* __restrict__ q,
    const float* __restrict__ ck, const float* __restrict__ cv,
    bf16* __restrict__ cmp_o, int* __restrict__ sel){
  int bx = blockIdx.x;
  int h = bx >> 10, n = bx & 1023;
  int tid = threadIdx.x;
  __shared__ float cks[NCMP*129];
  __shared__ float qs[GQ*DH];
  __shared__ float sims[GQ*66];
  __shared__ float impb[NFINE];
  for (int idx = tid; idx < NCMP*DH; idx += 256){
    int j = idx >> 7, d = idx & 127;
    cks[j*129 + d] = ck[((size_t)h*NCMP + j)*DH + d];
  }
  for (int idx = tid; idx < GQ*DH; idx += 256)
    qs[idx] = q[(size_t)n*DIM + h*(GQ*DH) + idx];
  __syncthreads();
  for (int p = tid; p < GQ*NCMP; p += 256){
    int g = p / NCMP, j = p % NCMP;
    float acc = 0.f;
    const float* qp = &qs[g*DH];
    const float* kp = &cks[j*129];
    #pragma unroll 4
    for (int d = 0; d < DH; ++d) acc += qp[d]*kp[d];
    sims[g*66 + j] = acc * SCALE;
  }
  __syncthreads();
  if (tid < NFINE){
    float s = 0.f;
    for (int g = 0; g < GQ; ++g)
      #pragma unroll
      for (int c = 0; c < 4; ++c)
        s += sims[g*66 + 1 + tid*4 + c];
    impb[tid] = s;
  }
  __syncthreads();
  if (tid == 0){
    int own = n >> 6;
    impb[own] = -1e30f;
    int selbuf[5];
    #pragma unroll
    for (int r = 0; r < 4; ++r){
      float best = -1e38f; int bi = 0;
      for (int f = 0; f < NFINE; ++f)
        if (impb[f] > best){ best = impb[f]; bi = f; }   // strict > : lowest index on ties
      selbuf[r] = bi; impb[bi] = -1e38f;
    }
    selbuf[4] = own;
    for (int r = 0; r < 5; ++r) sel[(size_t)(h*N_TOK + n)*8 + r] = selbuf[r];
  }
  int g = tid >> 5, lane = tid & 31;
  float m = -1e38f;
  for (int j = lane; j < NCMP; j += 32) m = fmaxf(m, sims[g*66 + j]);
  #pragma unroll
  for (int off = 16; off > 0; off >>= 1) m = fmaxf(m, __shfl_xor(m, off));
  float ps = 0.f;
  for (int j = lane; j < NCMP; j += 32){ float e = expf(sims[g*66+j] - m); sims[g*66+j] = e; ps += e; }
  #pragma unroll
  for (int off = 16; off > 0; off >>= 1) ps += __shfl_xor(ps, off);
  float inv = 1.f / ps;
  for (int j = lane; j < NCMP; j += 32) sims[g*66+j] *= inv;
  __syncthreads();
  for (int p = tid; p < GQ*DH; p += 256){
    int gg = p >> 7, d = p & 127;
    float acc = 0.f;
    const float* cvp = cv + (size_t)h*NCMP*DH + d;
    for (int j = 0; j < NCMP; ++j) acc += sims[gg*66 + j] * cvp[j*DH];
    cmp_o[(size_t)n*DIM + (h*GQ + gg)*DH + d] = __float2bfloat16(acc);
  }
}

// ---------------- Fine attention — ROUND-25: shfl-butterfly softmax (bit-identical) -----------------
// Row qi is wave-local (lanes qi*32..+31 in one 32-half of a wave). Descending-offset shfl_xor
// butterfly = same reduction tree as the LDS strided tree -> bit-identical. Removes red[] and
// ~12 barriers. Staging barriers (kvbuf shared cross-wave) kept.
#define FA_LOADK(blk) do{ \
    const bf16* p_ = kr + (size_t)((blk)*SEL_BLK + tK)*256 + h*DH; \
    k0 = *(const int4*)(p_ + dK);      \
    k1 = *(const int4*)(p_ + dK + 32); \
    k2 = *(const int4*)(p_ + dK + 64); \
    k3 = *(const int4*)(p_ + dK + 96); \
  }while(0)
#define FA_STOREK1(reg, db) do{ \
    unsigned w0_=(unsigned)(reg).x, w1_=(unsigned)(reg).y, w2_=(unsigned)(reg).z, w3_=(unsigned)(reg).w; \
    float* d_ = &kvbuf[(size_t)(db)*66 + tK]; \
    d_[0]   = bfbits2f(w0_ & 0xffffu); d_[66]  = bfbits2f(w0_ >> 16); \
    d_[132] = bfbits2f(w1_ & 0xffffu); d_[198] = bfbits2f(w1_ >> 16); \
    d_[264] = bfbits2f(w2_ & 0xffffu); d_[330] = bfbits2f(w2_ >> 16); \
    d_[396] = bfbits2f(w3_ & 0xffffu); d_[462] = bfbits2f(w3_ >> 16); \
  }while(0)
#define FA_STOREK do{ FA_STOREK1(k0,(dK)); FA_STOREK1(k1,(dK+32)); FA_STOREK1(k2,(dK+64)); FA_STOREK1(k3,(dK+96)); }while(0)
#define FA_QK(tile) do{ \
    float acc0_ = 0.f, acc1_ = 0.f; \
    const float* qp_ = &qs[qi*DH]; \
    const float* kp_ = &kvbuf[2*tx]; \
    _Pragma("unroll") \
    for (int d_ = 0; d_ < DH; d_ += 4){ \
      float4 a_ = *(const float4*)(qp_ + d_); \
      float2 b0_ = *(const float2*)(kp_ + (size_t)(d_  )*66); \
      float2 b1_ = *(const float2*)(kp_ + (size_t)(d_+1)*66); \
      float2 b2_ = *(const float2*)(kp_ + (size_t)(d_+2)*66); \
      float2 b3_ = *(const float2*)(kp_ + (size_t)(d_+3)*66); \
      acc0_ += a_.x*b0_.x; acc1_ += a_.x*b0_.y; \
      acc0_ += a_.y*b1_.x; acc1_ += a_.y*b1_.y; \
      acc0_ += a_.z*b2_.x; acc1_ += a_.z*b2_.y; \
      acc0_ += a_.w*b3_.x; acc1_ += a_.w*b3_.y; \
    } \
    *(float2*)&sims[(size_t)qi*322 + (tile)*SEL_BLK + 2*tx] = make_float2(acc0_*SCALE, acc1_*SCALE); \
  }while(0)
#define FA_LOADV(blk) do{ \
    const float* p_ = kv + (size_t)((blk)*SEL_BLK + tV)*512 + 256 + h*DH; \
    v0 = *(const float4*)(p_ + dV);         \
    v1 = *(const float4*)(p_ + 4096 + dV);  \
    v2 = *(const float4*)(p_ + 8192 + dV);  \
    v3 = *(const float4*)(p_ + 12288 + dV); \
    v4 = *(const float4*)(p_ + 16384 + dV); \
    v5 = *(const float4*)(p_ + 20480 + dV); \
    v6 = *(const float4*)(p_ + 24576 + dV); \
    v7 = *(const float4*)(p_ + 28672 + dV); \
  }while(0)
#define FA_STOREV do{ \
    float* d_ = &kvbuf[(size_t)tV*132 + dV]; \
    *(float4*)(d_)        = v0; \
    *(float4*)(d_ + 1056) = v1; \
    *(float4*)(d_ + 2112) = v2; \
    *(float4*)(d_ + 3168) = v3; \
    *(float4*)(d_ + 4224) = v4; \
    *(float4*)(d_ + 5280) = v5; \
    *(float4*)(d_ + 6336) = v6; \
    *(float4*)(d_ + 7392) = v7; \
  }while(0)
#define FA_PV(tile) do{ \
    const float* sp_ = &sims[(size_t)qi*322 + (tile)*SEL_BLK]; \
    const float* vp_ = &kvbuf[tx << 2]; \
    _Pragma("unroll 8") \
    for (int t_ = 0; t_ < SEL_BLK; ++t_){ \
      float p_ = sp_[t_]; \
      float4 vv_ = *(const float4*)(vp_ + (size_t)t_*132); \
      av0 += p_*vv_.x; av1 += p_*vv_.y; av2 += p_*vv_.z; av3 += p_*vv_.w; \
    } \
  }while(0)

__global__ __launch_bounds__(256) void fine_attn_kernel(const bf16* __restrict__ qr,
    const bf16* __restrict__ kr, const float* __restrict__ kv,
    const int* __restrict__ sel, bf16* __restrict__ fine_o){
  int bx = blockIdx.x;
  int h = bx >> 10, n = bx & 1023;
  int tid = threadIdx.x;
  __shared__ __align__(16) float kvbuf[8448];   // kT[128][66] (QK) | V[64][132] (PV)
  __shared__ __align__(16) float qs[GQ*DH];     // natural [qi][d]
  __shared__ float sims[GQ*322];
  const int qi = tid >> 5, tx = tid & 31;

  int s0_, s1_, s2_, s3_, s4_;
  {
    const int* sp = sel + (size_t)(h*N_TOK + n)*8;
    int b0 = sp[0], b1 = sp[1], b2 = sp[2], b3 = sp[3], b4 = sp[4];
    s0_ = (b0 < 0) ? 0 : (b0 > 15 ? 15 : b0);
    s1_ = (b1 < 0) ? 0 : (b1 > 15 ? 15 : b1);
    s2_ = (b2 < 0) ? 0 : (b2 > 15 ? 15 : b2);
    s3_ = (b3 < 0) ? 0 : (b3 > 15 ? 15 : b3);
    s4_ = (b4 < 0) ? 0 : (b4 > 15 ? 15 : b4);
  }
  for (int idx = tid; idx < GQ*DH; idx += 256)
    qs[idx] = b2f(qr[(size_t)n*DIM + h*(GQ*DH) + idx]);

  // ---- QK phase: per-thread coords. (tid+i*256)&63 == tid&63; d0_i = dK + 32*i.
  const int tK = tid & 63;
  const int dK = (tid >> 6) << 3;
  int4 k0, k1, k2, k3;
  FA_LOADK(s0_);
  __syncthreads(); FA_STOREK; __syncthreads(); FA_LOADK(s1_); FA_QK(0);
  __syncthreads(); FA_STOREK; __syncthreads(); FA_LOADK(s2_); FA_QK(1);
  __syncthreads(); FA_STOREK; __syncthreads(); FA_LOADK(s3_); FA_QK(2);
  __syncthreads(); FA_STOREK; __syncthreads(); FA_LOADK(s4_); FA_QK(3);
  __syncthreads(); FA_STOREK; __syncthreads();                FA_QK(4);

  // ---- prefetch V tile 0 (overlaps the softmax below)
  const int tV = tid >> 5;
  const int dV = (tid & 31) << 2;
  float4 v0, v1, v2, v3, v4, v5, v6, v7;
  FA_LOADV(s0_);

  // ---- softmax over 320: wave-local rows, shfl-butterfly (bit-identical to LDS tree)
  {
    float m = -1e38f;
    for (int t = tx; t < T_TOT; t += 32) m = fmaxf(m, sims[(size_t)qi*322 + t]);
    #pragma unroll
    for (int off = 16; off > 0; off >>= 1) m = fmaxf(m, __shfl_xor(m, off));
    float ps = 0.f;
    for (int t = tx; t < T_TOT; t += 32){ float e = expf(sims[(size_t)qi*322+t] - m); sims[(size_t)qi*322+t] = e; ps += e; }
    #pragma unroll
    for (int off = 16; off > 0; off >>= 1) ps += __shfl_xor(ps, off);
    float inv = 1.f / ps;
    for (int t = tx; t < T_TOT; t += 32) sims[(size_t)qi*322+t] *= inv;
  }

  // ---- PV phase with prefetch (first barrier guards kvbuf reuse after QK reads)
  float av0 = 0.f, av1 = 0.f, av2 = 0.f, av3 = 0.f;
  __syncthreads(); FA_STOREV; __syncthreads(); FA_LOADV(s1_); FA_PV(0);
  __syncthreads(); FA_STOREV; __syncthreads(); FA_LOADV(s2_); FA_PV(1);
  __syncthreads(); FA_STOREV; __syncthreads(); FA_LOADV(s3_); FA_PV(2);
  __syncthreads(); FA_STOREV; __syncthreads(); FA_LOADV(s4_); FA_PV(3);
  __syncthreads(); FA_STOREV; __syncthreads();                FA_PV(4);
  {
    bf16 o[4];
    o[0] = __float2bfloat16(av0);
    o[1] = __float2bfloat16(av1);
    o[2] = __float2bfloat16(av2);
    o[3] = __float2bfloat16(av3);
    *(ushort4*)(fine_o + (size_t)n*DIM + (h*GQ + qi)*DH + (tx << 2)) = *(const ushort4*)o;
  }
}

// ---------------- Sliding-window attention, flash-style online softmax --------------------------
__global__ __launch_bounds__(256) void slide_attn_kernel(const bf16* __restrict__ qr,
    const bf16* __restrict__ kr, const float* __restrict__ kv,
    bf16* __restrict__ slide_o){
  int hq = blockIdx.y;          // 16 heads
  int qt = blockIdx.x;          // 32 query tiles of 32
  int h = hq >> 3;
  int n0 = qt * 32;
  int tid = threadIdx.x;
  __shared__ float qT[128*36];   // [d][qi], pad 36
  __shared__ float kvb[128*68];  // K^T [d][t] pad 68 (QK) | V [t][128] (PV)
  __shared__ float stT[64*36];   // [t][qi] exp'd probs, pad 36

  const int ty  = tid >> 5;
  const int tx  = tid & 31;
  const int qi0 = ty << 2;

  for (int c = tid; c < 512; c += 256){
    int qi = c & 31, d0 = (c >> 5) << 3;
    int4 w = *(const int4*)(qr + (size_t)(n0+qi)*DIM + hq*DH + d0);
    float* dst = &qT[(size_t)d0*36 + qi];
    unsigned int wv[4] = {(unsigned)w.x,(unsigned)w.y,(unsigned)w.z,(unsigned)w.w};
    #pragma unroll
    for (int m = 0; m < 4; ++m){
      dst[(2*m  )*36] = bfbits2f(wv[m] & 0xffffu);
      dst[(2*m+1)*36] = bfbits2f(wv[m] >> 16);
    }
  }

  float acc[4][4] = {};
  float mrow[4] = {-1e30f,-1e30f,-1e30f,-1e30f};
  float lrow[4] = {0.f,0.f,0.f,0.f};
  float arow[4];
  const int kstart = n0 - 128;

  for (int tile = 0; tile < 5; ++tile){
    const int kbase = kstart + tile*64;
    __syncthreads();
    for (int c = tid; c < 1024; c += 256){
      int t = c & 63, d0 = (c >> 6) << 3;
      int kg = kbase + t;
      int kgc = min(max(kg, 0), N_TOK-1);
      int4 w = *(const int4*)(kr + (size_t)kgc*256 + h*DH + d0);
      float* dst = &kvb[(size_t)d0*68 + t];
      unsigned int wv[4] = {(unsigned)w.x,(unsigned)w.y,(unsigned)w.z,(unsigned)w.w};
      #pragma unroll
      for (int m = 0; m < 4; ++m){
        dst[(2*m  )*68] = bfbits2f(wv[m] & 0xffffu);
        dst[(2*m+1)*68] = bfbits2f(wv[m] >> 16);
      }
    }
    __syncthreads();
    float c0[8] = {};
    {
      const float* aP = qT + qi0;
      const float* bP = kvb + (tx << 1);
      #pragma unroll 4
      for (int d = 0; d < 128; ++d){
        float4 a = *(const float4*)(aP + d*36);
        float2 b = *(const float2*)(bP + d*68);
        c0[0] += a.x*b.x; c0[1] += a.x*b.y;
        c0[2] += a.y*b.x; c0[3] += a.y*b.y;
        c0[4] += a.z*b.x; c0[5] += a.z*b.y;
        c0[6] += a.w*b.x; c0[7] += a.w*b.y;
      }
    }
    const int kg0 = kbase + (tx << 1);
    #pragma unroll
    for (int i = 0; i < 4; ++i){
      int qg = n0 + qi0 + i;
      int d0 = qg - kg0, d1 = d0 - 1;
      bool v0 = (kg0   >= 0) && (kg0   < N_TOK) && (d0 <= 128) && (d0 >= -128);
      bool v1 = (kg0+1 >= 0) && (kg0+1 < N_TOK) && (d1 <= 128) && (d1 >= -128);
      float s0 = v0 ? c0[i*2  ]*SCALE : -1e30f;
      float s1 = v1 ? c0[i*2+1]*SCALE : -1e30f;
      float mi = fmaxf(s0, s1);
      #pragma unroll
      for (int off = 1; off < 32; off <<= 1) mi = fmaxf(mi, __shfl_xor(mi, off));
      float mold = mrow[i];
      float mnew = fmaxf(fmaxf(mold, mi), -1e20f);
      arow[i] = expf(mold - mnew);
      mrow[i] = mnew;
      float e0 = expf(s0 - mnew);
      float e1 = expf(s1 - mnew);
      float ps = e0 + e1;
      #pragma unroll
      for (int off = 1; off < 32; off <<= 1) ps += __shfl_xor(ps, off);
      lrow[i] = lrow[i]*arow[i] + ps;
      stT[(size_t)(2*tx  )*36 + qi0 + i] = e0;
      stT[(size_t)(2*tx+1)*36 + qi0 + i] = e1;
    }
    __syncthreads();
    for (int c = tid; c < 2048; c += 256){
      int t = c >> 5, d0 = (c & 31) << 2;
      int kg = kbase + t;
      int kgc = min(max(kg, 0), N_TOK-1);
      float4 v = *(const float4*)(kv + (size_t)kgc*512 + 256 + h*DH + d0);
      *(float4*)&kvb[(size_t)t*128 + d0] = v;
    }
    __syncthreads();
    #pragma unroll
    for (int i = 0; i < 4; ++i){
      float ar = arow[i];
      acc[i][0] *= ar; acc[i][1] *= ar; acc[i][2] *= ar; acc[i][3] *= ar;
    }
    {
      const float* pP = stT + qi0;
      const float* vP = kvb + (tx << 2);
      #pragma unroll 4
      for (int t = 0; t < 64; ++t){
        float4 p = *(const float4*)(pP + t*36);
        float4 v = *(const float4*)(vP + t*128);
        acc[0][0] += p.x*v.x; acc[0][1] += p.x*v.y; acc[0][2] += p.x*v.z; acc[0][3] += p.x*v.w;
        acc[1][0] += p.y*v.x; acc[1][1] += p.y*v.y; acc[1][2] += p.y*v.z; acc[1][3] += p.y*v.w;
        acc[2][0] += p.z*v.x; acc[2][1] += p.z*v.y; acc[2][2] += p.z*v.z; acc[2][3] += p.z*v.w;
        acc[3][0] += p.w*v.x; acc[3][1] += p.w*v.y; acc[3][2] += p.w*v.z; acc[3][3] += p.w*v.w;
      }
    }
  }
  #pragma unroll
  for (int i = 0; i < 4; ++i){
    int row = n0 + qi0 + i;
    float inv = 1.f / lrow[i];
    bf16 o[4];
    o[0] = __float2bfloat16(acc[i][0]*inv);
    o[1] = __float2bfloat16(acc[i][1]*inv);
    o[2] = __float2bfloat16(acc[i][2]*inv);
    o[3] = __float2bfloat16(acc[i][3]*inv);
    *(ushort4*)(slide_o + (size_t)row*DIM + hq*DH + (tx << 2)) = *(const ushort4*)o;
  }
}

// ---------------- Gated combine -> ocombT bf16 SLAB-TILED [s][row][kk] ------------------------------
__global__ __launch_bounds__(256) void combine_kernel(const bf16* __restrict__ cmp_o,
    const bf16* __restrict__ fine_o, const bf16* __restrict__ slide_o,
    const float* __restrict__ graw, const float* __restrict__ bg,
    unsigned short* __restrict__ ocombT){
  int n = blockIdx.x, tid = threadIdx.x;
  #pragma unroll
  for (int i = 0; i < 8; ++i){
    int c = tid + i*256;
    int hq = c >> 7;
    float g0 = 1.f/(1.f + expf(-(graw[(size_t)n*48 + hq*3 + 0] + bg[hq*3 + 0])));
    float g1 = 1.f/(1.f + expf(-(graw[(size_t)n*48 + hq*3 + 1] + bg[hq*3 + 1])));
    float g2 = 1.f/(1.f + expf(-(graw[(size_t)n*48 + hq*3 + 2] + bg[hq*3 + 2])));
    size_t idx = (size_t)n*DIM + c;
    float v = b2f(cmp_o[idx])*g0 + b2f(fine_o[idx])*g1 + b2f(slide_o[idx])*g2;
    int sl = c >> 5, kk = c & 31;
    ocombT[(size_t)sl*(N_TOK*32) + (size_t)n*32 + kk] = f2bf(v);
  }
}

extern "C" void kernel_launch(void* const* d_in, const int* in_sizes, int n_in,
                              void* d_out, int out_size, void* d_ws, size_t ws_size,
                              hipStream_t stream)
{
  const float* x      = (const float*)d_in[0];
  const float* g_norm = (const float*)d_in[1];
  const float* W_qkv  = (const float*)d_in[2];
  const float* k_pos  = (const float*)d_in[3];
  const float* v_pos  = (const float*)d_in[4];
  const float* mem_kv = (const float*)d_in[5];
  const float* Wk1    = (const float*)d_in[6];
  const float* bk1    = (const float*)d_in[7];
  const float* Wk2    = (const float*)d_in[8];
  const float* bk2    = (const float*)d_in[9];
  const float* Wv1    = (const float*)d_in[10];
  const float* bv1    = (const float*)d_in[11];
  const float* Wv2    = (const float*)d_in[12];
  const float* bv2    = (const float*)d_in[13];
  const float* Wg     = (const float*)d_in[14];
  const float* bg     = (const float*)d_in[15];
  const float* W_out  = (const float*)d_in[16];
  float* out = (float*)d_out;
  (void)ws_size; (void)in_sizes; (void)n_in; (void)out_size;

  // ---- Workspace layout (bytes), peak ~54.5 MB ----
  char* base = (char*)d_ws;
  float* q     = (float*)(base + 0);                 // 8 MB [n][2048] fp32, live -> cmp_attn
  float* xn    = (float*)(base + 8388608);           // 8 MB fp32
  bf16*  qr    = (bf16*) (base + 8388608);           // 4 MB (over xn, after xn dead)
  bf16*  kr    = (bf16*) (base + 12582912);          // 0.5 MB
  unsigned short* ocombT = (unsigned short*)(base + 8388608);  // 4 MB (over qr, after slide) slab-tiled
  float* kv    = (float*)(base + 16777216);          // 2 MB [n][512] fp32 (direct-stored by qkv GEMM)
  float* hbuf2 = (float*)(base + 18874368);          // 4 MB: [2][128][4096] fp32 (k, v halves)
  bf16*  cmp_o = (bf16*) (base + 18874368);          // 4 MB (over hbuf2, after MLP2s)
  float* ckb   = (float*)(base + 23068672);          // 64 KB (raw)
  float* cvb   = (float*)(base + 23134208);          // 64 KB (raw)
  float* ck    = (float*)(base + 23199744);          // 65 KB
  float* cv    = (float*)(base + 23266304);          // 65 KB
  float* gates = (float*)(base + 23332864);          // 192 KB (raw, sigmoid folded in combine)
  int*   sel   = (int*)  (base + 23529472);          // 64 KB
  bf16*  fine_o  = (bf16*)(base + 0);                // 4 MB (over q, after cmp_attn)
  bf16*  slide_o = (bf16*)(base + 4194304);          // 4 MB (over q upper half)
  // Pre-split operands (xnh/xnl and ocombT are SLAB-TILED [s][row][32])
  unsigned short* xnh  = (unsigned short*)(base + 25165824);  // 4 MB bf16 hi(xn)
  unsigned short* xnl  = (unsigned short*)(base + 29360128);  // 4 MB bf16 lo(xn)
  unsigned short* WqhT = (unsigned short*)(base + 33554432);  // 10.49 MB: full W_qkv hi, [s][2560][32]
  unsigned short* WqlT = (unsigned short*)(base + 44040192);  // 10.49 MB: lo     (ends 54,525,952)
  unsigned short* WohT = WqhT;   // W_out split reuses first 8 MB of each region (after qkv GEMM)
  unsigned short* WolT = WqlT;
  unsigned short* fh   = (unsigned short*)(base + 41943040);  // 2 MB, tail of WqhT region (Wq dead)
  unsigned short* fl   = (unsigned short*)(base + 52428800);  // 2 MB, tail of WqlT region

  // Zero split-K accumulation targets (stream-ordered; graph-capture legal)
  hipMemsetAsync(gates, 0, (size_t)N_TOK*48*4,   stream);
  hipMemsetAsync(ckb,   0, (size_t)KVH*NWIN*DH*4, stream);
  hipMemsetAsync(cvb,   0, (size_t)KVH*NWIN*DH*4, stream);
  hipMemsetAsync(hbuf2, 0, (size_t)2*128*CDIM*4,  stream);

  // Full W_qkv (2560 cols) -> slab-tiled hi/lo bf16 split
  transpose_split_kernel<<<dim3(40, 32), 256, 0, stream>>>(W_qkv, 2560, 2560, WqhT, WqlT);
  rmsnorm_kernel<<<N_TOK, 256, 0, stream>>>(x, g_norm, xn, xnh, xnl);
  // gates_raw = xn @ Wg [1024 x 48] — z=16 (round-15, passing)
  gemm_splitk_kernel<<<dim3(1, 16, 16), 256, 0, stream>>>(xn, 0, nullptr, Wg, 48, gates, N_TOK, 48, DIM, 128);
  // q + kv in ONE LDS-free MFMA GEMM — wide 32x32 wave tile (round-23, passing)
  gemm_mfma_qkvT_kernel<<<dim3(20, 32), 256, 0, stream>>>(xnh, xnl, WqhT, WqlT, q, kv);
  // W_out -> slab-tiled hi/lo split (reuses first 8 MB of Wq regions; ordered after qkv GEMM)
  transpose_split_kernel<<<dim3(32, 32), 256, 0, stream>>>(W_out, 2048, 2048, WohT, WolT);
  // qr, kr (bf16) — xn dead after this point
  rope_kernel<<<N_TOK, 256, 0, stream>>>(q, kv, qr, kr);
  // compression MLP1s: staged MFMA, 4 m-frags + z=16 (round-24, passing)
  build_f_kernel<<<256, 256, 0, stream>>>(kv, k_pos, v_pos, fh, fl);
  gemm_mfma_mlp1_kernel<<<dim3(64, 2, 16), 256, 0, stream>>>(fh, fl, Wk1, Wv1, hbuf2);
  // MLP2s fused into one dispatch (round-14, passing)
  gemm_mlp2_fused_kernel<<<dim3(2, 2, 64), 256, 0, stream>>>(hbuf2, bk1, bv1, Wk2, Wv2, ckb, cvb);
  assemble_kernel<<<NCMP, 256, 0, stream>>>(ckb, cvb, mem_kv, bk2, bv2, ck, cv);
  // compressed attention + selection (-> cmp_o), shfl-butterfly softmax (bit-identical)
  cmp_attn_kernel<<<KVH*N_TOK, 256, 0, stream>>>(q, ck, cv, cmp_o, sel);
  // fine attention (q dead -> fine_o over q region), shfl-butterfly softmax (bit-identical)
  fine_attn_kernel<<<KVH*N_TOK, 256, 0, stream>>>(qr, kr, kv, sel, fine_o);
  // sliding attention (-> slide_o over q upper half)
  slide_attn_kernel<<<dim3(32, 16), 256, 0, stream>>>(qr, kr, kv, slide_o);
  // combine (qr dead -> ocombT over qr, slab-tiled); sigmoid(graw+bg) folded here
  combine_kernel<<<N_TOK, 256, 0, stream>>>(cmp_o, fine_o, slide_o, gates, bg, ocombT);
  // out = ocomb @ W_out — wide 32x32 wave tile (round-23, passing)
  gemm_mfma_outT_kernel<<<dim3(16, 32), 256, 0, stream>>>(ocombT, WohT, WolT, out);
}